// Round 1
// baseline (2452.890 us; speedup 1.0000x reference)
//
#include <hip/hip_runtime.h>
#include <hip/hip_bf16.h>
#include <math.h>

// Problem constants (b=2, l=1024 fixed by harness)
#define BATCH 2
#define SEQ 1024
#define DMODEL 1024
#define DSTATE 128
#define HEADDIM 64
#define NHEADS 32
#define DINNER 2048
#define NUMANG 32
#define DPROJ 4480
// proj row offsets
#define OFF_Z 0
#define OFF_X 2048
#define OFF_B 4096
#define OFF_C 4224
#define OFF_DT 4352
#define OFF_A 4384
#define OFF_TRAP 4416
#define OFF_ANG 4448

// ---------------- GEMM: C[M][N] = A[M][K] @ B[N][K]^T (fp32) ----------------
__global__ __launch_bounds__(256) void gemm_nt(const float* __restrict__ A,
                                               const float* __restrict__ B,
                                               float* __restrict__ C,
                                               int M, int N, int K) {
  __shared__ float As[64][36];
  __shared__ float Bs[64][36];
  const int tid = threadIdx.x;
  const int bm = blockIdx.y * 64;
  const int bn = blockIdx.x * 64;
  const int tx = tid & 15, ty = tid >> 4;
  const int lrow = tid >> 2;        // 0..63
  const int lk   = (tid & 3) * 8;   // 0,8,16,24
  float acc[4][4] = {};
  for (int k0 = 0; k0 < K; k0 += 32) {
    const float* ap = A + (size_t)(bm + lrow) * K + k0 + lk;
    float4 a0 = *(const float4*)(ap);
    float4 a1 = *(const float4*)(ap + 4);
    const float* bp = B + (size_t)(bn + lrow) * K + k0 + lk;
    float4 b0 = *(const float4*)(bp);
    float4 b1 = *(const float4*)(bp + 4);
    *(float4*)&As[lrow][lk]     = a0;
    *(float4*)&As[lrow][lk + 4] = a1;
    *(float4*)&Bs[lrow][lk]     = b0;
    *(float4*)&Bs[lrow][lk + 4] = b1;
    __syncthreads();
#pragma unroll
    for (int kk = 0; kk < 32; ++kk) {
      float a[4], b[4];
#pragma unroll
      for (int i = 0; i < 4; ++i) a[i] = As[ty * 4 + i][kk];
#pragma unroll
      for (int j = 0; j < 4; ++j) b[j] = Bs[tx * 4 + j][kk];
#pragma unroll
      for (int i = 0; i < 4; ++i)
#pragma unroll
        for (int j = 0; j < 4; ++j)
          acc[i][j] = fmaf(a[i], b[j], acc[i][j]);
    }
    __syncthreads();
  }
#pragma unroll
  for (int i = 0; i < 4; ++i) {
    float4 v = {acc[i][0], acc[i][1], acc[i][2], acc[i][3]};
    *(float4*)&C[(size_t)(bm + ty * 4 + i) * N + bn + tx * 4] = v;
  }
}

// ---------------- per-(b,l,h) scalars: dt, g=exp(a*dt), lam ----------------
__device__ __forceinline__ float softplusf(float x) {
  return fmaxf(x, 0.f) + log1pf(expf(-fabsf(x)));
}

__global__ __launch_bounds__(256) void scalars_kernel(const float* __restrict__ proj,
                                                      const float* __restrict__ dt_bias,
                                                      float4* __restrict__ sc4) {
  int idx = blockIdx.x * 256 + threadIdx.x;  // 2*1024*32 = 65536 total
  int b = idx >> 15;
  int rem = idx & 32767;
  int l = rem >> 5, h = rem & 31;
  size_t row = (size_t)(b * SEQ + l) * DPROJ;
  float ddt = proj[row + OFF_DT + h];
  float dda = proj[row + OFF_A + h];
  float trp = proj[row + OFF_TRAP + h];
  float a = fminf(-softplusf(dda), -1e-4f);
  float dt = softplusf(ddt + dt_bias[h]);
  float g = expf(a * dt);
  float lam = 1.0f / (1.0f + expf(-trp));
  sc4[((size_t)(b * NHEADS + h)) * SEQ + l] = make_float4(dt, g, lam, 0.f);
}

// ---------------- theta = cumsum_l(angles * dt), per (b,h) ----------------
__global__ __launch_bounds__(1024) void theta_kernel(const float* __restrict__ proj,
                                                     const float4* __restrict__ sc4,
                                                     float4* __restrict__ theta4) {
  __shared__ float4 buf[1024];
  const int bh = blockIdx.x;  // b*32+h
  const int b = bh >> 5, h = bh & 31;
  const int l = threadIdx.x;
  const float dtv = sc4[(size_t)bh * SEQ + l].x;
  const size_t row = (size_t)(b * SEQ + l) * DPROJ + OFF_ANG;
#pragma unroll
  for (int kc = 0; kc < 8; ++kc) {
    float4 v = *(const float4*)(proj + row + kc * 4);
    v.x *= dtv; v.y *= dtv; v.z *= dtv; v.w *= dtv;
    buf[l] = v;
    __syncthreads();
    for (int off = 1; off < 1024; off <<= 1) {
      float4 t;
      bool act = (l >= off);
      if (act) t = buf[l - off];
      __syncthreads();
      if (act) {
        float4 u = buf[l];
        u.x += t.x; u.y += t.y; u.z += t.z; u.w += t.w;
        buf[l] = u;
      }
      __syncthreads();
    }
    float4 r = buf[l];  // own slot: safe
    theta4[((size_t)(b * SEQ + l) * NHEADS + h) * 8 + kc] = r;
  }
}

// ---------------- RMSNorm + bias + RoPE -> Bh, Ch (b,l,h,128) ----------------
__global__ __launch_bounds__(128) void rope_kernel(const float* __restrict__ proj,
                                                   const float* __restrict__ theta,
                                                   const float* __restrict__ B_bias,
                                                   const float* __restrict__ C_bias,
                                                   const float* __restrict__ Bnw,
                                                   const float* __restrict__ Cnw,
                                                   float* __restrict__ Bh,
                                                   float* __restrict__ Ch) {
  const int bl = blockIdx.x;   // b*1024 + l
  const int n = threadIdx.x;   // 0..127
  __shared__ float sB[128], sC[128], red[4];
  const size_t row = (size_t)bl * DPROJ;
  float bv = proj[row + OFF_B + n];
  float cv = proj[row + OFF_C + n];
  float sb = bv * bv, sc = cv * cv;
  for (int m = 32; m; m >>= 1) { sb += __shfl_xor(sb, m); sc += __shfl_xor(sc, m); }
  const int wave = n >> 6;
  if ((n & 63) == 0) { red[wave * 2] = sb; red[wave * 2 + 1] = sc; }
  __syncthreads();
  float rb = rsqrtf((red[0] + red[2]) / 128.0f + 1e-5f);
  float rc = rsqrtf((red[1] + red[3]) / 128.0f + 1e-5f);
  sB[n] = bv * rb * Bnw[n];
  sC[n] = cv * rc * Cnw[n];
  __syncthreads();
  for (int h = 0; h < 32; ++h) {
    float ob, oc;
    const size_t thbase = ((size_t)bl * NHEADS + h) * NUMANG;
    if (n < 64) {
      int k = n & 31;
      float th = theta[thbase + k];
      float cth = cosf(th), sth = sinf(th);
      float b1 = sB[k]      + B_bias[h * 128 + k];
      float b2 = sB[k + 32] + B_bias[h * 128 + k + 32];
      float c1 = sC[k]      + C_bias[h * 128 + k];
      float c2 = sC[k + 32] + C_bias[h * 128 + k + 32];
      if (n < 32) { ob = b1 * cth - b2 * sth; oc = c1 * cth - c2 * sth; }
      else        { ob = b1 * sth + b2 * cth; oc = c1 * sth + c2 * cth; }
    } else {
      ob = sB[n] + B_bias[h * 128 + n];
      oc = sC[n] + C_bias[h * 128 + n];
    }
    size_t o = ((size_t)bl * NHEADS + h) * DSTATE + n;
    Bh[o] = ob;
    Ch[o] = oc;
  }
}

// ---------------- sequential scan per (b,h); gate + D*x fused ----------------
__global__ __launch_bounds__(512) void scan_kernel(const float* __restrict__ proj,
                                                   const float4* __restrict__ sc4,
                                                   const float* __restrict__ Bh,
                                                   const float* __restrict__ Ch,
                                                   const float* __restrict__ Dp,
                                                   float* __restrict__ Y) {
  const int bh = blockIdx.x;
  const int b = bh >> 5, h = bh & 31;
  const int tid = threadIdx.x;
  const int p = tid >> 3, c = tid & 7;   // p: head dim 0..63, c: state chunk
  const int nb = c * 16;
  float hreg[16] = {}, bxp[16] = {};
  const float Dv = Dp[h];

  float4 Bc[4], Cc[4], Bn2[4], Cn2[4], scur, snxt;
  float xc, zc, xn, zn;

  auto load_t = [&](int l, float4* Bv, float4* Cv, float* xv, float* zv, float4* s) {
    size_t r = ((size_t)(b * SEQ + l) * NHEADS + h) * DSTATE + nb;
    const float4* bp = (const float4*)(Bh + r);
    const float4* cp = (const float4*)(Ch + r);
    Bv[0] = bp[0]; Bv[1] = bp[1]; Bv[2] = bp[2]; Bv[3] = bp[3];
    Cv[0] = cp[0]; Cv[1] = cp[1]; Cv[2] = cp[2]; Cv[3] = cp[3];
    size_t pr = (size_t)(b * SEQ + l) * DPROJ;
    *xv = proj[pr + OFF_X + h * HEADDIM + p];
    *zv = proj[pr + OFF_Z + h * HEADDIM + p];
    *s = sc4[(size_t)bh * SEQ + l];
  };

  load_t(0, Bc, Cc, &xc, &zc, &scur);
  for (int l = 0; l < SEQ; ++l) {
    int ln = (l + 1 < SEQ) ? l + 1 : l;
    load_t(ln, Bn2, Cn2, &xn, &zn, &snxt);  // prefetch next step
    float dt = scur.x, g = scur.y, lam = scur.z;
    float dtl = dt * lam;
    float dtog = dt * (1.0f - lam) * g;
    float acc = 0.0f;
#pragma unroll
    for (int q = 0; q < 4; ++q) {
      const float* Bq = (const float*)&Bc[q];
      const float* Cq = (const float*)&Cc[q];
#pragma unroll
      for (int i = 0; i < 4; ++i) {
        int j = q * 4 + i;
        float bx = xc * Bq[i];
        float hv = g * hreg[j] + dtl * bx + dtog * bxp[j];
        hreg[j] = hv;
        bxp[j] = bx;
        acc = fmaf(hv, Cq[i], acc);
      }
    }
    acc += __shfl_down(acc, 4, 8);
    acc += __shfl_down(acc, 2, 8);
    acc += __shfl_down(acc, 1, 8);
    if (c == 0) {
      float y = acc + Dv * xc;
      float sg = 1.0f / (1.0f + expf(-zc));
      Y[(size_t)(b * SEQ + l) * DINNER + h * HEADDIM + p] = y * (zc * sg);
    }
#pragma unroll
    for (int q = 0; q < 4; ++q) { Bc[q] = Bn2[q]; Cc[q] = Cn2[q]; }
    xc = xn; zc = zn; scur = snxt;
  }
}

extern "C" void kernel_launch(void* const* d_in, const int* in_sizes, int n_in,
                              void* d_out, int out_size, void* d_ws, size_t ws_size,
                              hipStream_t stream) {
  const float* u       = (const float*)d_in[0];
  const float* W_in    = (const float*)d_in[1];
  const float* W_out   = (const float*)d_in[2];
  const float* dt_bias = (const float*)d_in[3];
  const float* B_bias  = (const float*)d_in[4];
  const float* C_bias  = (const float*)d_in[5];
  const float* Bnw     = (const float*)d_in[6];
  const float* Cnw     = (const float*)d_in[7];
  const float* Dp      = (const float*)d_in[8];
  float* out = (float*)d_out;

  char* ws = (char*)d_ws;
  float*  proj  = (float*)(ws);                    // 2*1024*4480*4  = 36,700,160
  float4* sc4   = (float4*)(ws + 36700160);        // 2*32*1024*16   =  1,048,576
  float*  theta = (float*)(ws + 37748736);         // 2*1024*32*32*4 =  8,388,608
  float*  Bh    = (float*)(ws + 46137344);         // 33,554,432
  float*  Ch    = (float*)(ws + 79691776);         // 33,554,432
  float*  Y     = (float*)(ws + 113246208);        // 16,777,216  (total ~124 MB)

  // 1) proj = u @ W_in^T   (2048 x 4480, K=1024)
  gemm_nt<<<dim3(DPROJ / 64, (BATCH * SEQ) / 64), 256, 0, stream>>>(
      u, W_in, proj, BATCH * SEQ, DPROJ, DMODEL);
  // 2) dt/g/lam per (b,l,h)
  scalars_kernel<<<(BATCH * SEQ * NHEADS) / 256, 256, 0, stream>>>(proj, dt_bias, sc4);
  // 3) theta cumsum per (b,h)
  theta_kernel<<<BATCH * NHEADS, 1024, 0, stream>>>(proj, sc4, (float4*)theta);
  // 4) rmsnorm + bias + rope -> Bh, Ch
  rope_kernel<<<BATCH * SEQ, 128, 0, stream>>>(proj, theta, B_bias, C_bias, Bnw, Cnw, Bh, Ch);
  // 5) sequential scan + D*x + silu(z) gating -> Y (2048 x 2048)
  scan_kernel<<<BATCH * NHEADS, 512, 0, stream>>>(proj, sc4, Bh, Ch, Dp, Y);
  // 6) out = Y @ W_out^T   (2048 x 1024, K=2048)
  gemm_nt<<<dim3(DMODEL / 64, (BATCH * SEQ) / 64), 256, 0, stream>>>(
      Y, W_out, out, BATCH * SEQ, DMODEL, DINNER);
}

// Round 2
// 941.257 us; speedup vs baseline: 2.6060x; 2.6060x over previous
//
#include <hip/hip_runtime.h>
#include <hip/hip_bf16.h>
#include <math.h>

#define BATCH 2
#define SEQ 1024
#define DMODEL 1024
#define DSTATE 128
#define HEADDIM 64
#define NHEADS 32
#define DINNER 2048
#define NUMANG 32
#define DPROJ 4480
#define DPROJ4 1120
// proj row offsets (floats)
#define OFF_Z 0
#define OFF_X 2048
#define OFF_B 4096
#define OFF_C 4224
#define OFF_DT 4352
#define OFF_A 4384
#define OFF_TRAP 4416
#define OFF_ANG 4448

// ---------------- GEMM: C[M][N] = A[M][K] @ B[N][K]^T (fp32) ----------------
// LDS tiles stored K-major so inner loop = 2x ds_read_b128 + 16 FMA.
__global__ __launch_bounds__(256) void gemm_nt(const float* __restrict__ A,
                                               const float* __restrict__ B,
                                               float* __restrict__ C,
                                               int M, int N, int K) {
  __shared__ float As[32][68];   // [k][m], pad 68 keeps b128 alignment
  __shared__ float Bs[32][68];   // [k][n]
  const int tid = threadIdx.x;
  const int bm = blockIdx.y * 64;
  const int bn = blockIdx.x * 64;
  const int tx = tid & 15, ty = tid >> 4;
  const int lrow = tid >> 2;        // 0..63
  const int lk   = (tid & 3) * 8;   // 0,8,16,24
  float acc[4][4] = {};
  const float* Arow = A + (size_t)(bm + lrow) * K + lk;
  const float* Brow = B + (size_t)(bn + lrow) * K + lk;
  for (int k0 = 0; k0 < K; k0 += 32) {
    float4 a0 = *(const float4*)(Arow + k0);
    float4 a1 = *(const float4*)(Arow + k0 + 4);
    float4 b0 = *(const float4*)(Brow + k0);
    float4 b1 = *(const float4*)(Brow + k0 + 4);
    __syncthreads();
    // transposed scalar stores (k-major)
    As[lk + 0][lrow] = a0.x; As[lk + 1][lrow] = a0.y;
    As[lk + 2][lrow] = a0.z; As[lk + 3][lrow] = a0.w;
    As[lk + 4][lrow] = a1.x; As[lk + 5][lrow] = a1.y;
    As[lk + 6][lrow] = a1.z; As[lk + 7][lrow] = a1.w;
    Bs[lk + 0][lrow] = b0.x; Bs[lk + 1][lrow] = b0.y;
    Bs[lk + 2][lrow] = b0.z; Bs[lk + 3][lrow] = b0.w;
    Bs[lk + 4][lrow] = b1.x; Bs[lk + 5][lrow] = b1.y;
    Bs[lk + 6][lrow] = b1.z; Bs[lk + 7][lrow] = b1.w;
    __syncthreads();
#pragma unroll
    for (int kk = 0; kk < 32; ++kk) {
      float4 av = *(const float4*)&As[kk][ty * 4];
      float4 bv = *(const float4*)&Bs[kk][tx * 4];
      const float* ap = (const float*)&av;
      const float* bp = (const float*)&bv;
#pragma unroll
      for (int i = 0; i < 4; ++i)
#pragma unroll
        for (int j = 0; j < 4; ++j)
          acc[i][j] = fmaf(ap[i], bp[j], acc[i][j]);
    }
  }
#pragma unroll
  for (int i = 0; i < 4; ++i) {
    float4 v = {acc[i][0], acc[i][1], acc[i][2], acc[i][3]};
    *(float4*)&C[(size_t)(bm + ty * 4 + i) * N + bn + tx * 4] = v;
  }
}

// ---------------- per-(b,l,h) scalars: dt, g=exp(a*dt), lam ----------------
__device__ __forceinline__ float softplusf(float x) {
  return fmaxf(x, 0.f) + log1pf(expf(-fabsf(x)));
}

__global__ __launch_bounds__(256) void scalars_kernel(const float* __restrict__ proj,
                                                      const float* __restrict__ dt_bias,
                                                      float4* __restrict__ sc4) {
  int idx = blockIdx.x * 256 + threadIdx.x;  // 65536 total
  int b = idx >> 15;
  int rem = idx & 32767;
  int l = rem >> 5, h = rem & 31;
  size_t row = (size_t)(b * SEQ + l) * DPROJ;
  float ddt = proj[row + OFF_DT + h];
  float dda = proj[row + OFF_A + h];
  float trp = proj[row + OFF_TRAP + h];
  float a = fminf(-softplusf(dda), -1e-4f);
  float dt = softplusf(ddt + dt_bias[h]);
  float g = expf(a * dt);
  float lam = 1.0f / (1.0f + expf(-trp));
  sc4[((size_t)(b * NHEADS + h)) * SEQ + l] = make_float4(dt, g, lam, 0.f);
}

// ---------------- theta = cumsum_l(angles * dt), per (b,h): shuffle scan ----
__global__ __launch_bounds__(1024) void theta_kernel(const float* __restrict__ proj,
                                                     const float4* __restrict__ sc4,
                                                     float4* __restrict__ theta4) {
  __shared__ float4 part[16];
  __shared__ float4 part2[16];
  const int bh = blockIdx.x;
  const int b = bh >> 5, h = bh & 31;
  const int l = threadIdx.x;
  const int lane = l & 63, w = l >> 6;
  const float dtv = sc4[(size_t)bh * SEQ + l].x;
  const size_t row = (size_t)(b * SEQ + l) * DPROJ4 + (OFF_ANG / 4);
#pragma unroll
  for (int kc = 0; kc < 8; ++kc) {
    float4 v = ((const float4*)proj)[row + kc];
    v.x *= dtv; v.y *= dtv; v.z *= dtv; v.w *= dtv;
    // inclusive scan within wave (64)
#pragma unroll
    for (int off = 1; off < 64; off <<= 1) {
      float tx = __shfl_up(v.x, off, 64);
      float ty = __shfl_up(v.y, off, 64);
      float tz = __shfl_up(v.z, off, 64);
      float tw = __shfl_up(v.w, off, 64);
      if (lane >= off) { v.x += tx; v.y += ty; v.z += tz; v.w += tw; }
    }
    if (lane == 63) part[w] = v;
    __syncthreads();
    if (l < 16) {
      float4 p = part[l];
#pragma unroll
      for (int off = 1; off < 16; off <<= 1) {
        float tx = __shfl_up(p.x, off, 16);
        float ty = __shfl_up(p.y, off, 16);
        float tz = __shfl_up(p.z, off, 16);
        float tw = __shfl_up(p.w, off, 16);
        if (l >= off) { p.x += tx; p.y += ty; p.z += tz; p.w += tw; }
      }
      part2[l] = p;
    }
    __syncthreads();
    if (w > 0) {
      float4 o = part2[w - 1];
      v.x += o.x; v.y += o.y; v.z += o.z; v.w += o.w;
    }
    theta4[((size_t)(b * SEQ + l) * NHEADS + h) * 8 + kc] = v;
  }
}

// ---------------- RMSNorm + bias + RoPE -> Bh, Ch in [b][h][l][128] --------
__global__ __launch_bounds__(128) void rope_kernel(const float* __restrict__ proj,
                                                   const float* __restrict__ theta,
                                                   const float* __restrict__ B_bias,
                                                   const float* __restrict__ C_bias,
                                                   const float* __restrict__ Bnw,
                                                   const float* __restrict__ Cnw,
                                                   float* __restrict__ Bh,
                                                   float* __restrict__ Ch) {
  const int bl = blockIdx.x;   // b*1024 + l
  const int b = bl >> 10, l = bl & 1023;
  const int n = threadIdx.x;   // 0..127
  __shared__ float sB[128], sC[128], red[4];
  const size_t row = (size_t)bl * DPROJ;
  float bv = proj[row + OFF_B + n];
  float cv = proj[row + OFF_C + n];
  float sb = bv * bv, sc = cv * cv;
  for (int m = 32; m; m >>= 1) { sb += __shfl_xor(sb, m); sc += __shfl_xor(sc, m); }
  const int wave = n >> 6;
  if ((n & 63) == 0) { red[wave * 2] = sb; red[wave * 2 + 1] = sc; }
  __syncthreads();
  float rb = rsqrtf((red[0] + red[2]) / 128.0f + 1e-5f);
  float rc = rsqrtf((red[1] + red[3]) / 128.0f + 1e-5f);
  sB[n] = bv * rb * Bnw[n];
  sC[n] = cv * rc * Cnw[n];
  __syncthreads();
  for (int h = 0; h < 32; ++h) {
    float ob, oc;
    const size_t thbase = ((size_t)bl * NHEADS + h) * NUMANG;
    if (n < 64) {
      int k = n & 31;
      float th = theta[thbase + k];
      float cth = cosf(th), sth = sinf(th);
      float b1 = sB[k]      + B_bias[h * 128 + k];
      float b2 = sB[k + 32] + B_bias[h * 128 + k + 32];
      float c1 = sC[k]      + C_bias[h * 128 + k];
      float c2 = sC[k + 32] + C_bias[h * 128 + k + 32];
      if (n < 32) { ob = b1 * cth - b2 * sth; oc = c1 * cth - c2 * sth; }
      else        { ob = b1 * sth + b2 * cth; oc = c1 * sth + c2 * cth; }
    } else {
      ob = sB[n] + B_bias[h * 128 + n];
      oc = sC[n] + C_bias[h * 128 + n];
    }
    size_t o = (((size_t)(b * NHEADS + h)) * SEQ + l) * DSTATE + n;
    Bh[o] = ob;
    Ch[o] = oc;
  }
}

// ---------------- scan: 256 blocks (bh x 4 pgroups), LDS ring prefetch -----
// Per step LDS record: B 32 f4, C 32 f4, x 4 f4, z 4 f4, sc 1 f4 = 73 f4.
#define REC 73
#define PHS 8
#define FILL (REC * PHS)   // 584 f4 per phase

__global__ __launch_bounds__(256) void scan_kernel(const float* __restrict__ proj,
                                                   const float4* __restrict__ sc4,
                                                   const float4* __restrict__ Bh4,
                                                   const float4* __restrict__ Ch4,
                                                   const float* __restrict__ Dp,
                                                   float* __restrict__ Y) {
  __shared__ float4 sB[2][PHS][32];
  __shared__ float4 sC[2][PHS][32];
  __shared__ float  sx[2][PHS][16];
  __shared__ float  sz[2][PHS][16];
  __shared__ float4 ssc[2][PHS];

  const int blk = blockIdx.x;
  const int bh = blk >> 2, pg = blk & 3;
  const int b = bh >> 5, h = bh & 31;
  const int p0 = pg * 16;
  const int tid = threadIdx.x;
  const int pp = tid >> 4, c = tid & 15;
  const float Dv = Dp[h];

  // fill indices (fixed per thread)
  const int i0 = tid, i1 = tid + 256, i2 = tid + 512;
  const int st0 = i0 / REC, r0i = i0 - st0 * REC;
  const int st1 = i1 / REC, r1i = i1 - st1 * REC;
  const int st2 = i2 / REC, r2i = i2 - st2 * REC;
  const bool has2 = (i2 < FILL);

  auto fload = [&](int st, int r, int l0) -> float4 {
    int l = l0 + st; if (l > SEQ - 1) l = SEQ - 1;
    if (r < 32)      return Bh4[((size_t)bh * SEQ + l) * 32 + r];
    else if (r < 64) return Ch4[((size_t)bh * SEQ + l) * 32 + (r - 32)];
    else if (r < 68) return ((const float4*)proj)[(size_t)(b * SEQ + l) * DPROJ4 + (OFF_X / 4) + h * 16 + pg * 4 + (r - 64)];
    else if (r < 72) return ((const float4*)proj)[(size_t)(b * SEQ + l) * DPROJ4 + (OFF_Z / 4) + h * 16 + pg * 4 + (r - 68)];
    else             return sc4[(size_t)bh * SEQ + l];
  };
  auto fstore = [&](int st, int r, int bufb, float4 v) {
    if (r < 32)      sB[bufb][st][r] = v;
    else if (r < 64) sC[bufb][st][r - 32] = v;
    else if (r < 68) *(float4*)&sx[bufb][st][(r - 64) * 4] = v;
    else if (r < 72) *(float4*)&sz[bufb][st][(r - 68) * 4] = v;
    else             ssc[bufb][st] = v;
  };

  float4 v0 = fload(st0, r0i, 0);
  float4 v1 = fload(st1, r1i, 0);
  float4 v2 = has2 ? fload(st2, r2i, 0) : make_float4(0, 0, 0, 0);
  fstore(st0, r0i, 0, v0);
  fstore(st1, r1i, 0, v1);
  if (has2) fstore(st2, r2i, 0, v2);
  __syncthreads();

  float hr[8] = {}, bxp[8] = {};
  int buf = 0;
  for (int ph = 0; ph < SEQ / PHS; ++ph) {
    const int nl0 = (ph + 1) * PHS;
    v0 = fload(st0, r0i, nl0);
    v1 = fload(st1, r1i, nl0);
    if (has2) v2 = fload(st2, r2i, nl0);
#pragma unroll
    for (int s = 0; s < PHS; ++s) {
      float4 scv = ssc[buf][s];
      float dt = scv.x, g = scv.y, lam = scv.z;
      float dtl = dt * lam;
      float dtog = dt * (1.0f - lam) * g;
      float xv = sx[buf][s][pp];
      float4 B0 = sB[buf][s][c];
      float4 B1 = sB[buf][s][16 + c];
      float4 C0 = sC[buf][s][c];
      float4 C1 = sC[buf][s][16 + c];
      float acc = 0.0f;
      const float* Bp0 = (const float*)&B0;
      const float* Cp0 = (const float*)&C0;
      const float* Bp1 = (const float*)&B1;
      const float* Cp1 = (const float*)&C1;
#pragma unroll
      for (int i = 0; i < 4; ++i) {
        float bx = xv * Bp0[i];
        float hv = fmaf(g, hr[i], fmaf(dtl, bx, dtog * bxp[i]));
        hr[i] = hv; bxp[i] = bx;
        acc = fmaf(hv, Cp0[i], acc);
      }
#pragma unroll
      for (int i = 0; i < 4; ++i) {
        float bx = xv * Bp1[i];
        float hv = fmaf(g, hr[4 + i], fmaf(dtl, bx, dtog * bxp[4 + i]));
        hr[4 + i] = hv; bxp[4 + i] = bx;
        acc = fmaf(hv, Cp1[i], acc);
      }
      acc += __shfl_xor(acc, 8, 16);
      acc += __shfl_xor(acc, 4, 16);
      acc += __shfl_xor(acc, 2, 16);
      acc += __shfl_xor(acc, 1, 16);
      if (c == 0) {
        int l = ph * PHS + s;
        float zv = sz[buf][s][pp];
        float y = acc + Dv * xv;
        float sg = 1.0f / (1.0f + expf(-zv));
        Y[(size_t)(b * SEQ + l) * DINNER + h * HEADDIM + p0 + pp] = y * zv * sg;
      }
    }
    fstore(st0, r0i, buf ^ 1, v0);
    fstore(st1, r1i, buf ^ 1, v1);
    if (has2) fstore(st2, r2i, buf ^ 1, v2);
    __syncthreads();
    buf ^= 1;
  }
}

extern "C" void kernel_launch(void* const* d_in, const int* in_sizes, int n_in,
                              void* d_out, int out_size, void* d_ws, size_t ws_size,
                              hipStream_t stream) {
  const float* u       = (const float*)d_in[0];
  const float* W_in    = (const float*)d_in[1];
  const float* W_out   = (const float*)d_in[2];
  const float* dt_bias = (const float*)d_in[3];
  const float* B_bias  = (const float*)d_in[4];
  const float* C_bias  = (const float*)d_in[5];
  const float* Bnw     = (const float*)d_in[6];
  const float* Cnw     = (const float*)d_in[7];
  const float* Dp      = (const float*)d_in[8];
  float* out = (float*)d_out;

  char* ws = (char*)d_ws;
  float*  proj  = (float*)(ws);                    // 36,700,160 B
  float4* sc4   = (float4*)(ws + 36700160);        //  1,048,576 B
  float*  theta = (float*)(ws + 37748736);         //  8,388,608 B
  float*  Bh    = (float*)(ws + 46137344);         // 33,554,432 B
  float*  Ch    = (float*)(ws + 79691776);         // 33,554,432 B
  float*  Y     = (float*)(ws + 113246208);        // 16,777,216 B

  gemm_nt<<<dim3(DPROJ / 64, (BATCH * SEQ) / 64), 256, 0, stream>>>(
      u, W_in, proj, BATCH * SEQ, DPROJ, DMODEL);
  scalars_kernel<<<(BATCH * SEQ * NHEADS) / 256, 256, 0, stream>>>(proj, dt_bias, sc4);
  theta_kernel<<<BATCH * NHEADS, 1024, 0, stream>>>(proj, sc4, (float4*)theta);
  rope_kernel<<<BATCH * SEQ, 128, 0, stream>>>(proj, theta, B_bias, C_bias, Bnw, Cnw, Bh, Ch);
  scan_kernel<<<BATCH * NHEADS * 4, 256, 0, stream>>>(
      proj, sc4, (const float4*)Bh, (const float4*)Ch, Dp, Y);
  gemm_nt<<<dim3(DMODEL / 64, (BATCH * SEQ) / 64), 256, 0, stream>>>(
      Y, W_out, out, BATCH * SEQ, DMODEL, DINNER);
}

// Round 4
// 672.186 us; speedup vs baseline: 3.6491x; 1.4003x over previous
//
#include <hip/hip_runtime.h>
#include <hip/hip_bf16.h>
#include <math.h>

#define BATCH 2
#define SEQ 1024
#define DMODEL 1024
#define DSTATE 128
#define HEADDIM 64
#define NHEADS 32
#define DINNER 2048
#define NUMANG 32
#define DPROJ 4480
#define DPROJ4 1120
#define CH 64
#define NCH 16
// proj row offsets (floats)
#define OFF_Z 0
#define OFF_X 2048
#define OFF_B 4096
#define OFF_C 4224
#define OFF_DT 4352
#define OFF_A 4384
#define OFF_TRAP 4416
#define OFF_ANG 4448

// ---------------- GEMM: C[M][N] = A[M][K] @ B[N][K]^T (fp32) ----------------
__global__ __launch_bounds__(256) void gemm_nt(const float* __restrict__ A,
                                               const float* __restrict__ B,
                                               float* __restrict__ C,
                                               int M, int N, int K) {
  __shared__ float As[32][68];
  __shared__ float Bs[32][68];
  const int tid = threadIdx.x;
  const int bm = blockIdx.y * 64;
  const int bn = blockIdx.x * 64;
  const int tx = tid & 15, ty = tid >> 4;
  const int lrow = tid >> 2;
  const int lk   = (tid & 3) * 8;
  float acc[4][4] = {};
  const float* Arow = A + (size_t)(bm + lrow) * K + lk;
  const float* Brow = B + (size_t)(bn + lrow) * K + lk;
  for (int k0 = 0; k0 < K; k0 += 32) {
    float4 a0 = *(const float4*)(Arow + k0);
    float4 a1 = *(const float4*)(Arow + k0 + 4);
    float4 b0 = *(const float4*)(Brow + k0);
    float4 b1 = *(const float4*)(Brow + k0 + 4);
    __syncthreads();
    As[lk + 0][lrow] = a0.x; As[lk + 1][lrow] = a0.y;
    As[lk + 2][lrow] = a0.z; As[lk + 3][lrow] = a0.w;
    As[lk + 4][lrow] = a1.x; As[lk + 5][lrow] = a1.y;
    As[lk + 6][lrow] = a1.z; As[lk + 7][lrow] = a1.w;
    Bs[lk + 0][lrow] = b0.x; Bs[lk + 1][lrow] = b0.y;
    Bs[lk + 2][lrow] = b0.z; Bs[lk + 3][lrow] = b0.w;
    Bs[lk + 4][lrow] = b1.x; Bs[lk + 5][lrow] = b1.y;
    Bs[lk + 6][lrow] = b1.z; Bs[lk + 7][lrow] = b1.w;
    __syncthreads();
#pragma unroll
    for (int kk = 0; kk < 32; ++kk) {
      float4 av = *(const float4*)&As[kk][ty * 4];
      float4 bv = *(const float4*)&Bs[kk][tx * 4];
      const float* ap = (const float*)&av;
      const float* bp = (const float*)&bv;
#pragma unroll
      for (int i = 0; i < 4; ++i)
#pragma unroll
        for (int j = 0; j < 4; ++j)
          acc[i][j] = fmaf(ap[i], bp[j], acc[i][j]);
    }
  }
#pragma unroll
  for (int i = 0; i < 4; ++i) {
    float4 v = {acc[i][0], acc[i][1], acc[i][2], acc[i][3]};
    *(float4*)&C[(size_t)(bm + ty * 4 + i) * N + bn + tx * 4] = v;
  }
}

// ---------------- per-(b,l,h) scalars: dt, g, lam, adt ----------------
__device__ __forceinline__ float softplusf(float x) {
  return fmaxf(x, 0.f) + log1pf(expf(-fabsf(x)));
}

__global__ __launch_bounds__(256) void scalars_kernel(const float* __restrict__ proj,
                                                      const float* __restrict__ dt_bias,
                                                      float4* __restrict__ sc4) {
  int idx = blockIdx.x * 256 + threadIdx.x;
  int b = idx >> 15;
  int rem = idx & 32767;
  int l = rem >> 5, h = rem & 31;
  size_t row = (size_t)(b * SEQ + l) * DPROJ;
  float ddt = proj[row + OFF_DT + h];
  float dda = proj[row + OFF_A + h];
  float trp = proj[row + OFF_TRAP + h];
  float a = fminf(-softplusf(dda), -1e-4f);
  float dt = softplusf(ddt + dt_bias[h]);
  float adt = a * dt;
  float lam = 1.0f / (1.0f + expf(-trp));
  sc4[((size_t)(b * NHEADS + h)) * SEQ + l] = make_float4(dt, expf(adt), lam, adt);
}

// ---------------- theta = cumsum_l(angles * dt), per (b,h) ----------------
__global__ __launch_bounds__(1024) void theta_kernel(const float* __restrict__ proj,
                                                     const float4* __restrict__ sc4,
                                                     float4* __restrict__ theta4) {
  __shared__ float4 part[16];
  __shared__ float4 part2[16];
  const int bh = blockIdx.x;
  const int b = bh >> 5, h = bh & 31;
  const int l = threadIdx.x;
  const int lane = l & 63, w = l >> 6;
  const float dtv = sc4[(size_t)bh * SEQ + l].x;
  const size_t row = (size_t)(b * SEQ + l) * DPROJ4 + (OFF_ANG / 4);
#pragma unroll
  for (int kc = 0; kc < 8; ++kc) {
    float4 v = ((const float4*)proj)[row + kc];
    v.x *= dtv; v.y *= dtv; v.z *= dtv; v.w *= dtv;
#pragma unroll
    for (int off = 1; off < 64; off <<= 1) {
      float tx = __shfl_up(v.x, off, 64);
      float ty = __shfl_up(v.y, off, 64);
      float tz = __shfl_up(v.z, off, 64);
      float tw = __shfl_up(v.w, off, 64);
      if (lane >= off) { v.x += tx; v.y += ty; v.z += tz; v.w += tw; }
    }
    if (lane == 63) part[w] = v;
    __syncthreads();
    if (l < 16) {
      float4 p = part[l];
#pragma unroll
      for (int off = 1; off < 16; off <<= 1) {
        float tx = __shfl_up(p.x, off, 16);
        float ty = __shfl_up(p.y, off, 16);
        float tz = __shfl_up(p.z, off, 16);
        float tw = __shfl_up(p.w, off, 16);
        if (l >= off) { p.x += tx; p.y += ty; p.z += tz; p.w += tw; }
      }
      part2[l] = p;
    }
    __syncthreads();
    if (w > 0) {
      float4 o = part2[w - 1];
      v.x += o.x; v.y += o.y; v.z += o.z; v.w += o.w;
    }
    theta4[((size_t)(b * SEQ + l) * NHEADS + h) * 8 + kc] = v;
  }
}

// ---------------- RMSNorm + bias + RoPE -> Bh, Ch in [bh][l][128] ----------
__global__ __launch_bounds__(128) void rope_kernel(const float* __restrict__ proj,
                                                   const float* __restrict__ theta,
                                                   const float* __restrict__ B_bias,
                                                   const float* __restrict__ C_bias,
                                                   const float* __restrict__ Bnw,
                                                   const float* __restrict__ Cnw,
                                                   float* __restrict__ Bh,
                                                   float* __restrict__ Ch) {
  const int bl = blockIdx.x;
  const int b = bl >> 10, l = bl & 1023;
  const int n = threadIdx.x;
  __shared__ float sB[128], sC[128], red[4];
  const size_t row = (size_t)bl * DPROJ;
  float bv = proj[row + OFF_B + n];
  float cv = proj[row + OFF_C + n];
  float sb = bv * bv, sc = cv * cv;
  for (int m = 32; m; m >>= 1) { sb += __shfl_xor(sb, m); sc += __shfl_xor(sc, m); }
  const int wave = n >> 6;
  if ((n & 63) == 0) { red[wave * 2] = sb; red[wave * 2 + 1] = sc; }
  __syncthreads();
  float rb = rsqrtf((red[0] + red[2]) / 128.0f + 1e-5f);
  float rc = rsqrtf((red[1] + red[3]) / 128.0f + 1e-5f);
  sB[n] = bv * rb * Bnw[n];
  sC[n] = cv * rc * Cnw[n];
  __syncthreads();
  for (int h = 0; h < 32; ++h) {
    float ob, oc;
    const size_t thbase = ((size_t)bl * NHEADS + h) * NUMANG;
    if (n < 64) {
      int k = n & 31;
      float th = theta[thbase + k];
      float cth = cosf(th), sth = sinf(th);
      float b1 = sB[k]      + B_bias[h * 128 + k];
      float b2 = sB[k + 32] + B_bias[h * 128 + k + 32];
      float c1 = sC[k]      + C_bias[h * 128 + k];
      float c2 = sC[k + 32] + C_bias[h * 128 + k + 32];
      if (n < 32) { ob = b1 * cth - b2 * sth; oc = c1 * cth - c2 * sth; }
      else        { ob = b1 * sth + b2 * cth; oc = c1 * sth + c2 * cth; }
    } else {
      ob = sB[n] + B_bias[h * 128 + n];
      oc = sC[n] + C_bias[h * 128 + n];
    }
    size_t o = (((size_t)(b * NHEADS + h)) * SEQ + l) * DSTATE + n;
    Bh[o] = ob;
    Ch[o] = oc;
  }
}

// ============ chunked scan, phase A: per-chunk parallel GEMMs ==============
__global__ __launch_bounds__(256) void chunk_kernel(
    const float* __restrict__ proj,
    const float4* __restrict__ sc4,
    const float* __restrict__ Bh,
    const float* __restrict__ Chh,
    float* __restrict__ Yacc,
    float* __restrict__ dHT,
    float* __restrict__ Gv_g,
    float2* __restrict__ de_g) {
  __shared__ float sC[64][132];
  __shared__ float sBt[128][68];
  __shared__ float sX[64][68];
  __shared__ float sS[64][68];
  __shared__ float sA[64], sW[64], sCV[64], sDL[64];

  const int blk = blockIdx.x;
  const int bh = blk >> 4, ch = blk & 15;
  const int b = bh >> 5, h = bh & 31;
  const int t0 = ch * CH;
  const int tid = threadIdx.x;

  {
    const int row = tid >> 5;
    const int c4 = tid & 31;
#pragma unroll
    for (int pass = 0; pass < 8; ++pass) {
      int l = t0 + pass * 8 + row;
      float4 cv = *(const float4*)&Chh[((size_t)bh * SEQ + l) * DSTATE + c4 * 4];
      float4 bv = *(const float4*)&Bh[((size_t)bh * SEQ + l) * DSTATE + c4 * 4];
      *(float4*)&sC[pass * 8 + row][c4 * 4] = cv;
      sBt[c4 * 4 + 0][pass * 8 + row] = bv.x;
      sBt[c4 * 4 + 1][pass * 8 + row] = bv.y;
      sBt[c4 * 4 + 2][pass * 8 + row] = bv.z;
      sBt[c4 * 4 + 3][pass * 8 + row] = bv.w;
    }
    // X: 64 rows x 64 floats; 4 threads/row, each loads 4 float4 (16 floats)
    const int xr = tid >> 2, xc = tid & 3;
    int l = t0 + xr;
    const float* xrow = &proj[(size_t)(b * SEQ + l) * DPROJ + OFF_X + h * 64];
#pragma unroll
    for (int j = 0; j < 4; ++j) {
      float4 xv = *(const float4*)(xrow + xc * 16 + j * 4);
      *(float4*)&sX[xr][xc * 16 + j * 4] = xv;
    }
  }
  if (tid < 64) {
    float4 s = sc4[(size_t)bh * SEQ + t0 + tid];
    float dt = s.x, lam = s.z, adt = s.w;
    float A = adt;
#pragma unroll
    for (int off = 1; off < 64; off <<= 1) {
      float t = __shfl_up(A, off, 64);
      if (tid >= off) A += t;
    }
    float dtn = __shfl_down(dt, 1, 64);
    float lamn = __shfl_down(lam, 1, 64);
    float dl = dt * lam;
    float w = dl + dtn * (1.0f - lamn);
    if (tid == 63) w = 0.0f;
    float A63 = __shfl(A, 63, 64);
    float cv = (tid < 63) ? expf(A63 - A) * w : dl;
    sA[tid] = A; sW[tid] = w; sCV[tid] = cv; sDL[tid] = dl;
    Gv_g[((size_t)bh * NCH + ch) * 64 + tid] = expf(A);
    if (tid == 0) de_g[(size_t)bh * NCH + ch] = make_float2(expf(A63), dt * (1.0f - lam));
  }
  __syncthreads();

  const int ty = tid >> 4, tx = tid & 15;
  // ---- S = C @ B^T, scale by decay weights, store sS ----
  {
    float acc[4][4] = {};
    for (int n = 0; n < 128; n += 4) {
      float4 ctv[4], btv[4];
#pragma unroll
      for (int i = 0; i < 4; ++i) ctv[i] = *(const float4*)&sC[ty * 4 + i][n];
#pragma unroll
      for (int k = 0; k < 4; ++k) btv[k] = *(const float4*)&sBt[n + k][tx * 4];
#pragma unroll
      for (int k = 0; k < 4; ++k) {
        const float* bp = (const float*)&btv[k];
#pragma unroll
        for (int i = 0; i < 4; ++i) {
          float cva = ((const float*)&ctv[i])[k];
#pragma unroll
          for (int j = 0; j < 4; ++j)
            acc[i][j] = fmaf(cva, bp[j], acc[i][j]);
        }
      }
    }
#pragma unroll
    for (int i = 0; i < 4; ++i) {
      int t = ty * 4 + i;
      float At = sA[t], dlt = sDL[t];
      float4 o;
      float* op = (float*)&o;
#pragma unroll
      for (int j = 0; j < 4; ++j) {
        int s = tx * 4 + j;
        float f = (s < t) ? expf(At - sA[s]) * sW[s] : ((s == t) ? dlt : 0.0f);
        op[j] = acc[i][j] * f;
      }
      *(float4*)&sS[t][tx * 4] = o;
    }
  }
  __syncthreads();
  // ---- Y1 = sS @ X -> Yacc global ----
  {
    float acc[4][4] = {};
    for (int s = 0; s < 64; s += 4) {
      float4 sv[4], xv[4];
#pragma unroll
      for (int i = 0; i < 4; ++i) sv[i] = *(const float4*)&sS[ty * 4 + i][s];
#pragma unroll
      for (int k = 0; k < 4; ++k) xv[k] = *(const float4*)&sX[s + k][tx * 4];
#pragma unroll
      for (int k = 0; k < 4; ++k) {
        const float* xp = (const float*)&xv[k];
#pragma unroll
        for (int i = 0; i < 4; ++i) {
          float sva = ((const float*)&sv[i])[k];
#pragma unroll
          for (int j = 0; j < 4; ++j)
            acc[i][j] = fmaf(sva, xp[j], acc[i][j]);
        }
      }
    }
#pragma unroll
    for (int i = 0; i < 4; ++i) {
      float4 v = {acc[i][0], acc[i][1], acc[i][2], acc[i][3]};
      *(float4*)&Yacc[(size_t)(b * SEQ + t0 + ty * 4 + i) * DINNER + h * 64 + tx * 4] = v;
    }
  }
  __syncthreads();
  // ---- scale X rows by cv[s] ----
  {
    const int s = tid >> 2, p0 = (tid & 3) * 16;
    float c = sCV[s];
#pragma unroll
    for (int j4 = 0; j4 < 4; ++j4) {
      float4 v = *(const float4*)&sX[s][p0 + j4 * 4];
      v.x *= c; v.y *= c; v.z *= c; v.w *= c;
      *(float4*)&sX[s][p0 + j4 * 4] = v;
    }
  }
  __syncthreads();
  // ---- dHT[n][p] = sum_s Bt[n][s] * Xs[s][p] ----
  {
    float acc[8][4] = {};
    for (int s = 0; s < 64; s += 4) {
      float4 bv[8], xv[4];
#pragma unroll
      for (int r = 0; r < 8; ++r) bv[r] = *(const float4*)&sBt[ty * 8 + r][s];
#pragma unroll
      for (int k = 0; k < 4; ++k) xv[k] = *(const float4*)&sX[s + k][tx * 4];
#pragma unroll
      for (int k = 0; k < 4; ++k) {
        const float* xp = (const float*)&xv[k];
#pragma unroll
        for (int r = 0; r < 8; ++r) {
          float bva = ((const float*)&bv[r])[k];
#pragma unroll
          for (int j = 0; j < 4; ++j)
            acc[r][j] = fmaf(bva, xp[j], acc[r][j]);
        }
      }
    }
#pragma unroll
    for (int r = 0; r < 8; ++r) {
      float4 v = {acc[r][0], acc[r][1], acc[r][2], acc[r][3]};
      *(float4*)&dHT[(((size_t)bh * NCH + ch) * 128 + ty * 8 + r) * 64 + tx * 4] = v;
    }
  }
}

// ============ phase B: sequential 16-chunk state carry (64 blocks) ==========
__global__ __launch_bounds__(512) void carry_kernel(
    const float* __restrict__ proj,
    const float* __restrict__ Bh,
    const float* __restrict__ dHT,
    const float2* __restrict__ de_g,
    float* __restrict__ Heff) {
  const int bh = blockIdx.x;
  const int b = bh >> 5, h = bh & 31;
  const int tid = threadIdx.x;
  const int n = tid >> 2;
  const int p0 = (tid & 3) * 16;
  float hreg[16] = {};
  for (int c = 0; c < NCH; ++c) {
    float2 de = de_g[bh * NCH + c];
    float heff[16];
    if (c == 0) {
#pragma unroll
      for (int j = 0; j < 16; ++j) heff[j] = 0.0f;
    } else {
      int lprev = c * CH - 1;
      float Bp = Bh[((size_t)bh * SEQ + lprev) * DSTATE + n];
      const float4* xp4 = (const float4*)&proj[(size_t)(b * SEQ + lprev) * DPROJ + OFF_X + h * 64 + p0];
      float eB = de.y * Bp;
#pragma unroll
      for (int j4 = 0; j4 < 4; ++j4) {
        float4 xv = xp4[j4];
        heff[j4 * 4 + 0] = hreg[j4 * 4 + 0] + eB * xv.x;
        heff[j4 * 4 + 1] = hreg[j4 * 4 + 1] + eB * xv.y;
        heff[j4 * 4 + 2] = hreg[j4 * 4 + 2] + eB * xv.z;
        heff[j4 * 4 + 3] = hreg[j4 * 4 + 3] + eB * xv.w;
      }
    }
    size_t base = (((size_t)bh * NCH + c) * 128 + n) * 64 + p0;
#pragma unroll
    for (int j4 = 0; j4 < 4; ++j4)
      *(float4*)&Heff[base + j4 * 4] = *(const float4*)&heff[j4 * 4];
#pragma unroll
    for (int j4 = 0; j4 < 4; ++j4) {
      float4 dh = *(const float4*)&dHT[base + j4 * 4];
      hreg[j4 * 4 + 0] = de.x * heff[j4 * 4 + 0] + dh.x;
      hreg[j4 * 4 + 1] = de.x * heff[j4 * 4 + 1] + dh.y;
      hreg[j4 * 4 + 2] = de.x * heff[j4 * 4 + 2] + dh.z;
      hreg[j4 * 4 + 3] = de.x * heff[j4 * 4 + 3] + dh.w;
    }
  }
}

// ============ phase C: Y2 = G*(C @ Heff) + Y1 + D*x, gate, -> Y =============
__global__ __launch_bounds__(256) void inter_kernel(
    const float* __restrict__ proj,
    const float* __restrict__ Chh,
    const float* __restrict__ Heff,
    const float* __restrict__ Gv_g,
    const float* __restrict__ Dp,
    float* __restrict__ Yacc) {
  __shared__ float sC[64][132];
  __shared__ float sH[128][68];
  __shared__ float sGv[64];
  const int blk = blockIdx.x;
  const int bh = blk >> 4, ch = blk & 15;
  const int b = bh >> 5, h = bh & 31;
  const int t0 = ch * CH;
  const int tid = threadIdx.x;
  {
    const int row = tid >> 5, c4 = tid & 31;
#pragma unroll
    for (int pass = 0; pass < 8; ++pass) {
      int l = t0 + pass * 8 + row;
      float4 cv = *(const float4*)&Chh[((size_t)bh * SEQ + l) * DSTATE + c4 * 4];
      *(float4*)&sC[pass * 8 + row][c4 * 4] = cv;
    }
    const int hr = tid >> 4, hc = tid & 15;
#pragma unroll
    for (int pass = 0; pass < 8; ++pass) {
      int n = pass * 16 + hr;
      float4 hv = *(const float4*)&Heff[(((size_t)bh * NCH + ch) * 128 + n) * 64 + hc * 4];
      *(float4*)&sH[n][hc * 4] = hv;
    }
    if (tid < 64) sGv[tid] = Gv_g[((size_t)bh * NCH + ch) * 64 + tid];
  }
  __syncthreads();
  const int ty = tid >> 4, tx = tid & 15;
  float acc[4][4] = {};
  for (int n = 0; n < 128; n += 4) {
    float4 cv[4], hv[4];
#pragma unroll
    for (int i = 0; i < 4; ++i) cv[i] = *(const float4*)&sC[ty * 4 + i][n];
#pragma unroll
    for (int k = 0; k < 4; ++k) hv[k] = *(const float4*)&sH[n + k][tx * 4];
#pragma unroll
    for (int k = 0; k < 4; ++k) {
      const float* hp = (const float*)&hv[k];
#pragma unroll
      for (int i = 0; i < 4; ++i) {
        float cva = ((const float*)&cv[i])[k];
#pragma unroll
        for (int j = 0; j < 4; ++j)
          acc[i][j] = fmaf(cva, hp[j], acc[i][j]);
      }
    }
  }
  const float Dv = Dp[h];
#pragma unroll
  for (int i = 0; i < 4; ++i) {
    int l = t0 + ty * 4 + i;
    float gt = sGv[ty * 4 + i];
    size_t rowp = (size_t)(b * SEQ + l) * DPROJ;
    float4 xv = *(const float4*)&proj[rowp + OFF_X + h * 64 + tx * 4];
    float4 zv = *(const float4*)&proj[rowp + OFF_Z + h * 64 + tx * 4];
    size_t yo = (size_t)(b * SEQ + l) * DINNER + h * 64 + tx * 4;
    float4 y1 = *(const float4*)&Yacc[yo];
    float y[4];
    y[0] = y1.x + gt * acc[i][0] + Dv * xv.x;
    y[1] = y1.y + gt * acc[i][1] + Dv * xv.y;
    y[2] = y1.z + gt * acc[i][2] + Dv * xv.z;
    y[3] = y1.w + gt * acc[i][3] + Dv * xv.w;
    const float* zp = (const float*)&zv;
    float4 o;
    float* op = (float*)&o;
#pragma unroll
    for (int j = 0; j < 4; ++j) {
      float z = zp[j];
      float sg = 1.0f / (1.0f + expf(-z));
      op[j] = y[j] * z * sg;
    }
    *(float4*)&Yacc[yo] = o;
  }
}

extern "C" void kernel_launch(void* const* d_in, const int* in_sizes, int n_in,
                              void* d_out, int out_size, void* d_ws, size_t ws_size,
                              hipStream_t stream) {
  const float* u       = (const float*)d_in[0];
  const float* W_in    = (const float*)d_in[1];
  const float* W_out   = (const float*)d_in[2];
  const float* dt_bias = (const float*)d_in[3];
  const float* B_bias  = (const float*)d_in[4];
  const float* C_bias  = (const float*)d_in[5];
  const float* Bnw     = (const float*)d_in[6];
  const float* Cnw     = (const float*)d_in[7];
  const float* Dp      = (const float*)d_in[8];
  float* out = (float*)d_out;

  char* ws = (char*)d_ws;
  float*  proj  = (float*)(ws);                    // 36,700,160
  float4* sc4   = (float4*)(ws + 36700160);        //  1,048,576
  float*  theta = (float*)(ws + 37748736);         //  8,388,608
  float*  Bh    = (float*)(ws + 46137344);         // 33,554,432
  float*  Ch    = (float*)(ws + 79691776);         // 33,554,432
  float*  Y     = (float*)(ws + 113246208);        // 16,777,216
  float*  dHT   = (float*)(ws + 130023424);        // 33,554,432
  float*  Heff  = (float*)(ws + 163577856);        // 33,554,432
  float*  Gv    = (float*)(ws + 197132288);        //    262,144
  float2* deg   = (float2*)(ws + 197394432);       //      8,192

  gemm_nt<<<dim3(DPROJ / 64, (BATCH * SEQ) / 64), 256, 0, stream>>>(
      u, W_in, proj, BATCH * SEQ, DPROJ, DMODEL);
  scalars_kernel<<<(BATCH * SEQ * NHEADS) / 256, 256, 0, stream>>>(proj, dt_bias, sc4);
  theta_kernel<<<BATCH * NHEADS, 1024, 0, stream>>>(proj, sc4, (float4*)theta);
  rope_kernel<<<BATCH * SEQ, 128, 0, stream>>>(proj, theta, B_bias, C_bias, Bnw, Cnw, Bh, Ch);
  chunk_kernel<<<BATCH * NHEADS * NCH, 256, 0, stream>>>(
      proj, sc4, Bh, Ch, Y, dHT, Gv, deg);
  carry_kernel<<<BATCH * NHEADS, 512, 0, stream>>>(proj, Bh, dHT, deg, Heff);
  inter_kernel<<<BATCH * NHEADS * NCH, 256, 0, stream>>>(
      proj, Ch, Heff, Gv, Dp, Y);
  gemm_nt<<<dim3(DMODEL / 64, (BATCH * SEQ) / 64), 256, 0, stream>>>(
      Y, W_out, out, BATCH * SEQ, DMODEL, DINNER);
}

// Round 5
// 391.026 us; speedup vs baseline: 6.2730x; 1.7190x over previous
//
#include <hip/hip_runtime.h>
#include <hip/hip_bf16.h>
#include <math.h>

#define BATCH 2
#define SEQ 1024
#define DMODEL 1024
#define DSTATE 128
#define HEADDIM 64
#define NHEADS 32
#define DINNER 2048
#define NUMANG 32
#define DPROJ 4480
#define DPROJ4 1120
#define CH 64
#define NCH 16
// proj row offsets (floats)
#define OFF_Z 0
#define OFF_X 2048
#define OFF_B 4096
#define OFF_C 4224
#define OFF_DT 4352
#define OFF_A 4384
#define OFF_TRAP 4416
#define OFF_ANG 4448

typedef __attribute__((ext_vector_type(8))) short bf16x8;
typedef __attribute__((ext_vector_type(4))) float f32x4;
typedef unsigned short u16;

// ---------------- fp32 -> bf16 (RNE) ----------------
__device__ __forceinline__ u16 f2bf(float f) {
  unsigned int u = __float_as_uint(f);
  u += 0x7FFFu + ((u >> 16) & 1u);
  return (u16)(u >> 16);
}

__global__ __launch_bounds__(256) void cvt_bf16(const float* __restrict__ in,
                                                u16* __restrict__ out, int n4) {
  int i = blockIdx.x * 256 + threadIdx.x;
  if (i >= n4) return;
  float4 v = ((const float4*)in)[i];
  ushort4 o;
  o.x = f2bf(v.x); o.y = f2bf(v.y); o.z = f2bf(v.z); o.w = f2bf(v.w);
  ((ushort4*)out)[i] = o;
}

// ---------------- bf16 MFMA GEMM: C[M][N] = A[M][K] @ B[N][K]^T ------------
// 128x128 tile, BK=64, 4 waves, global_load_lds w16, XOR-swizzled LDS chunks.
__device__ __forceinline__ void gload_lds16(const void* g, void* l) {
  __builtin_amdgcn_global_load_lds(
      (const __attribute__((address_space(1))) unsigned int*)g,
      (__attribute__((address_space(3))) unsigned int*)l, 16, 0, 0);
}

__global__ __launch_bounds__(256) void gemm_bf16(const u16* __restrict__ A,
                                                 const u16* __restrict__ B,
                                                 float* __restrict__ C,
                                                 int M, int N, int K) {
  __shared__ u16 As[128 * 64];
  __shared__ u16 Bs[128 * 64];
  const int tid = threadIdx.x;
  const int lane = tid & 63, wave = tid >> 6;
  const int bm = blockIdx.y * 128, bn = blockIdx.x * 128;
  const int wm = (wave >> 1) * 64, wn = (wave & 1) * 64;

  // staging: row = it*32 + wave*8 + (lane>>3); global k-chunk = (lane&7)^(row&7)
  const int srow = wave * 8 + (lane >> 3);
  const int scol = (((lane & 7) ^ ((lane >> 3) & 7)) * 8);
  const u16* Ab = A + (size_t)(bm + srow) * K + scol;
  const u16* Bb = B + (size_t)(bn + srow) * K + scol;
  u16* Asw = As + wave * 512;
  u16* Bsw = Bs + wave * 512;

  f32x4 acc[4][4];
#pragma unroll
  for (int i = 0; i < 4; ++i)
#pragma unroll
    for (int j = 0; j < 4; ++j)
      acc[i][j] = (f32x4){0.f, 0.f, 0.f, 0.f};

  const int fr = lane & 15;   // m/n within 16x16
  const int fq = lane >> 4;   // quad -> k-chunk within 32
  const int sw = fr & 7;      // row-dependent swizzle

  for (int k0 = 0; k0 < K; k0 += 64) {
    __syncthreads();
#pragma unroll
    for (int it = 0; it < 4; ++it) {
      gload_lds16(Ab + (size_t)(it * 32) * K + k0, Asw + it * 2048);
      gload_lds16(Bb + (size_t)(it * 32) * K + k0, Bsw + it * 2048);
    }
    __syncthreads();
#pragma unroll
    for (int kh = 0; kh < 2; ++kh) {
      bf16x8 af[4], bfv[4];
#pragma unroll
      for (int i = 0; i < 4; ++i) {
        int row = wm + i * 16 + fr;
        af[i] = *(const bf16x8*)(As + row * 64 + (((kh * 4 + fq) ^ sw) * 8));
      }
#pragma unroll
      for (int j = 0; j < 4; ++j) {
        int row = wn + j * 16 + fr;
        bfv[j] = *(const bf16x8*)(Bs + row * 64 + (((kh * 4 + fq) ^ sw) * 8));
      }
#pragma unroll
      for (int i = 0; i < 4; ++i)
#pragma unroll
        for (int j = 0; j < 4; ++j)
          acc[i][j] = __builtin_amdgcn_mfma_f32_16x16x32_bf16(af[i], bfv[j], acc[i][j], 0, 0, 0);
    }
  }
  const int orow = bm + wm + fq * 4;
  const int ocol = bn + wn + fr;
#pragma unroll
  for (int i = 0; i < 4; ++i)
#pragma unroll
    for (int j = 0; j < 4; ++j)
#pragma unroll
      for (int r = 0; r < 4; ++r)
        C[(size_t)(orow + i * 16 + r) * N + ocol + j * 16] = acc[i][j][r];
}

// ---------------- per-(b,l,h) scalars: dt, g, lam, adt ----------------
__device__ __forceinline__ float softplusf(float x) {
  return fmaxf(x, 0.f) + log1pf(expf(-fabsf(x)));
}

__global__ __launch_bounds__(256) void scalars_kernel(const float* __restrict__ proj,
                                                      const float* __restrict__ dt_bias,
                                                      float4* __restrict__ sc4) {
  int idx = blockIdx.x * 256 + threadIdx.x;
  int b = idx >> 15;
  int rem = idx & 32767;
  int l = rem >> 5, h = rem & 31;
  size_t row = (size_t)(b * SEQ + l) * DPROJ;
  float ddt = proj[row + OFF_DT + h];
  float dda = proj[row + OFF_A + h];
  float trp = proj[row + OFF_TRAP + h];
  float a = fminf(-softplusf(dda), -1e-4f);
  float dt = softplusf(ddt + dt_bias[h]);
  float adt = a * dt;
  float lam = 1.0f / (1.0f + expf(-trp));
  sc4[((size_t)(b * NHEADS + h)) * SEQ + l] = make_float4(dt, expf(adt), lam, adt);
}

// ---------------- theta = cumsum_l(angles * dt), per (b,h) ----------------
__global__ __launch_bounds__(1024) void theta_kernel(const float* __restrict__ proj,
                                                     const float4* __restrict__ sc4,
                                                     float4* __restrict__ theta4) {
  __shared__ float4 part[16];
  __shared__ float4 part2[16];
  const int bh = blockIdx.x;
  const int b = bh >> 5, h = bh & 31;
  const int l = threadIdx.x;
  const int lane = l & 63, w = l >> 6;
  const float dtv = sc4[(size_t)bh * SEQ + l].x;
  const size_t row = (size_t)(b * SEQ + l) * DPROJ4 + (OFF_ANG / 4);
#pragma unroll
  for (int kc = 0; kc < 8; ++kc) {
    float4 v = ((const float4*)proj)[row + kc];
    v.x *= dtv; v.y *= dtv; v.z *= dtv; v.w *= dtv;
#pragma unroll
    for (int off = 1; off < 64; off <<= 1) {
      float tx = __shfl_up(v.x, off, 64);
      float ty = __shfl_up(v.y, off, 64);
      float tz = __shfl_up(v.z, off, 64);
      float tw = __shfl_up(v.w, off, 64);
      if (lane >= off) { v.x += tx; v.y += ty; v.z += tz; v.w += tw; }
    }
    if (lane == 63) part[w] = v;
    __syncthreads();
    if (l < 16) {
      float4 p = part[l];
#pragma unroll
      for (int off = 1; off < 16; off <<= 1) {
        float tx = __shfl_up(p.x, off, 16);
        float ty = __shfl_up(p.y, off, 16);
        float tz = __shfl_up(p.z, off, 16);
        float tw = __shfl_up(p.w, off, 16);
        if (l >= off) { p.x += tx; p.y += ty; p.z += tz; p.w += tw; }
      }
      part2[l] = p;
    }
    __syncthreads();
    if (w > 0) {
      float4 o = part2[w - 1];
      v.x += o.x; v.y += o.y; v.z += o.z; v.w += o.w;
    }
    theta4[((size_t)(b * SEQ + l) * NHEADS + h) * 8 + kc] = v;
  }
}

// ---------------- RMSNorm + bias + RoPE -> Bh, Ch in [bh][l][128] ----------
__global__ __launch_bounds__(128) void rope_kernel(const float* __restrict__ proj,
                                                   const float* __restrict__ theta,
                                                   const float* __restrict__ B_bias,
                                                   const float* __restrict__ C_bias,
                                                   const float* __restrict__ Bnw,
                                                   const float* __restrict__ Cnw,
                                                   float* __restrict__ Bh,
                                                   float* __restrict__ Ch) {
  const int bl = blockIdx.x;
  const int b = bl >> 10, l = bl & 1023;
  const int n = threadIdx.x;
  __shared__ float sB[128], sC[128], red[4];
  const size_t row = (size_t)bl * DPROJ;
  float bv = proj[row + OFF_B + n];
  float cv = proj[row + OFF_C + n];
  float sb = bv * bv, sc = cv * cv;
  for (int m = 32; m; m >>= 1) { sb += __shfl_xor(sb, m); sc += __shfl_xor(sc, m); }
  const int wave = n >> 6;
  if ((n & 63) == 0) { red[wave * 2] = sb; red[wave * 2 + 1] = sc; }
  __syncthreads();
  float rb = rsqrtf((red[0] + red[2]) / 128.0f + 1e-5f);
  float rc = rsqrtf((red[1] + red[3]) / 128.0f + 1e-5f);
  sB[n] = bv * rb * Bnw[n];
  sC[n] = cv * rc * Cnw[n];
  __syncthreads();
  for (int h = 0; h < 32; ++h) {
    float ob, oc;
    const size_t thbase = ((size_t)bl * NHEADS + h) * NUMANG;
    if (n < 64) {
      int k = n & 31;
      float th = theta[thbase + k];
      float cth = cosf(th), sth = sinf(th);
      float b1 = sB[k]      + B_bias[h * 128 + k];
      float b2 = sB[k + 32] + B_bias[h * 128 + k + 32];
      float c1 = sC[k]      + C_bias[h * 128 + k];
      float c2 = sC[k + 32] + C_bias[h * 128 + k + 32];
      if (n < 32) { ob = b1 * cth - b2 * sth; oc = c1 * cth - c2 * sth; }
      else        { ob = b1 * sth + b2 * cth; oc = c1 * sth + c2 * cth; }
    } else {
      ob = sB[n] + B_bias[h * 128 + n];
      oc = sC[n] + C_bias[h * 128 + n];
    }
    size_t o = (((size_t)(b * NHEADS + h)) * SEQ + l) * DSTATE + n;
    Bh[o] = ob;
    Ch[o] = oc;
  }
}

// ============ chunked scan, phase A: per-chunk parallel GEMMs ==============
__global__ __launch_bounds__(256) void chunk_kernel(
    const float* __restrict__ proj,
    const float4* __restrict__ sc4,
    const float* __restrict__ Bh,
    const float* __restrict__ Chh,
    float* __restrict__ Yacc,
    float* __restrict__ dHT,
    float* __restrict__ Gv_g,
    float2* __restrict__ de_g) {
  __shared__ float sC[64][132];
  __shared__ float sBt[128][68];
  __shared__ float sX[64][68];
  __shared__ float sS[64][68];
  __shared__ float sA[64], sW[64], sCV[64], sDL[64];

  const int blk = blockIdx.x;
  const int bh = blk >> 4, ch = blk & 15;
  const int b = bh >> 5, h = bh & 31;
  const int t0 = ch * CH;
  const int tid = threadIdx.x;

  {
    const int row = tid >> 5;
    const int c4 = tid & 31;
#pragma unroll
    for (int pass = 0; pass < 8; ++pass) {
      int l = t0 + pass * 8 + row;
      float4 cv = *(const float4*)&Chh[((size_t)bh * SEQ + l) * DSTATE + c4 * 4];
      float4 bv = *(const float4*)&Bh[((size_t)bh * SEQ + l) * DSTATE + c4 * 4];
      *(float4*)&sC[pass * 8 + row][c4 * 4] = cv;
      sBt[c4 * 4 + 0][pass * 8 + row] = bv.x;
      sBt[c4 * 4 + 1][pass * 8 + row] = bv.y;
      sBt[c4 * 4 + 2][pass * 8 + row] = bv.z;
      sBt[c4 * 4 + 3][pass * 8 + row] = bv.w;
    }
    const int xr = tid >> 2, xc = tid & 3;
    int l = t0 + xr;
    const float* xrow = &proj[(size_t)(b * SEQ + l) * DPROJ + OFF_X + h * 64];
#pragma unroll
    for (int j = 0; j < 4; ++j) {
      float4 xv = *(const float4*)(xrow + xc * 16 + j * 4);
      *(float4*)&sX[xr][xc * 16 + j * 4] = xv;
    }
  }
  if (tid < 64) {
    float4 s = sc4[(size_t)bh * SEQ + t0 + tid];
    float dt = s.x, lam = s.z, adt = s.w;
    float A = adt;
#pragma unroll
    for (int off = 1; off < 64; off <<= 1) {
      float t = __shfl_up(A, off, 64);
      if (tid >= off) A += t;
    }
    float dtn = __shfl_down(dt, 1, 64);
    float lamn = __shfl_down(lam, 1, 64);
    float dl = dt * lam;
    float w = dl + dtn * (1.0f - lamn);
    if (tid == 63) w = 0.0f;
    float A63 = __shfl(A, 63, 64);
    float cv = (tid < 63) ? expf(A63 - A) * w : dl;
    sA[tid] = A; sW[tid] = w; sCV[tid] = cv; sDL[tid] = dl;
    Gv_g[((size_t)bh * NCH + ch) * 64 + tid] = expf(A);
    if (tid == 0) de_g[(size_t)bh * NCH + ch] = make_float2(expf(A63), dt * (1.0f - lam));
  }
  __syncthreads();

  const int ty = tid >> 4, tx = tid & 15;
  {
    float acc[4][4] = {};
    for (int n = 0; n < 128; n += 4) {
      float4 ctv[4], btv[4];
#pragma unroll
      for (int i = 0; i < 4; ++i) ctv[i] = *(const float4*)&sC[ty * 4 + i][n];
#pragma unroll
      for (int k = 0; k < 4; ++k) btv[k] = *(const float4*)&sBt[n + k][tx * 4];
#pragma unroll
      for (int k = 0; k < 4; ++k) {
        const float* bp = (const float*)&btv[k];
#pragma unroll
        for (int i = 0; i < 4; ++i) {
          float cva = ((const float*)&ctv[i])[k];
#pragma unroll
          for (int j = 0; j < 4; ++j)
            acc[i][j] = fmaf(cva, bp[j], acc[i][j]);
        }
      }
    }
#pragma unroll
    for (int i = 0; i < 4; ++i) {
      int t = ty * 4 + i;
      float At = sA[t], dlt = sDL[t];
      float4 o;
      float* op = (float*)&o;
#pragma unroll
      for (int j = 0; j < 4; ++j) {
        int s = tx * 4 + j;
        float f = (s < t) ? expf(At - sA[s]) * sW[s] : ((s == t) ? dlt : 0.0f);
        op[j] = acc[i][j] * f;
      }
      *(float4*)&sS[t][tx * 4] = o;
    }
  }
  __syncthreads();
  {
    float acc[4][4] = {};
    for (int s = 0; s < 64; s += 4) {
      float4 sv[4], xv[4];
#pragma unroll
      for (int i = 0; i < 4; ++i) sv[i] = *(const float4*)&sS[ty * 4 + i][s];
#pragma unroll
      for (int k = 0; k < 4; ++k) xv[k] = *(const float4*)&sX[s + k][tx * 4];
#pragma unroll
      for (int k = 0; k < 4; ++k) {
        const float* xp = (const float*)&xv[k];
#pragma unroll
        for (int i = 0; i < 4; ++i) {
          float sva = ((const float*)&sv[i])[k];
#pragma unroll
          for (int j = 0; j < 4; ++j)
            acc[i][j] = fmaf(sva, xp[j], acc[i][j]);
        }
      }
    }
#pragma unroll
    for (int i = 0; i < 4; ++i) {
      float4 v = {acc[i][0], acc[i][1], acc[i][2], acc[i][3]};
      *(float4*)&Yacc[(size_t)(b * SEQ + t0 + ty * 4 + i) * DINNER + h * 64 + tx * 4] = v;
    }
  }
  __syncthreads();
  {
    const int s = tid >> 2, p0 = (tid & 3) * 16;
    float c = sCV[s];
#pragma unroll
    for (int j4 = 0; j4 < 4; ++j4) {
      float4 v = *(const float4*)&sX[s][p0 + j4 * 4];
      v.x *= c; v.y *= c; v.z *= c; v.w *= c;
      *(float4*)&sX[s][p0 + j4 * 4] = v;
    }
  }
  __syncthreads();
  {
    float acc[8][4] = {};
    for (int s = 0; s < 64; s += 4) {
      float4 bv[8], xv[4];
#pragma unroll
      for (int r = 0; r < 8; ++r) bv[r] = *(const float4*)&sBt[ty * 8 + r][s];
#pragma unroll
      for (int k = 0; k < 4; ++k) xv[k] = *(const float4*)&sX[s + k][tx * 4];
#pragma unroll
      for (int k = 0; k < 4; ++k) {
        const float* xp = (const float*)&xv[k];
#pragma unroll
        for (int r = 0; r < 8; ++r) {
          float bva = ((const float*)&bv[r])[k];
#pragma unroll
          for (int j = 0; j < 4; ++j)
            acc[r][j] = fmaf(bva, xp[j], acc[r][j]);
        }
      }
    }
#pragma unroll
    for (int r = 0; r < 8; ++r) {
      float4 v = {acc[r][0], acc[r][1], acc[r][2], acc[r][3]};
      *(float4*)&dHT[(((size_t)bh * NCH + ch) * 128 + ty * 8 + r) * 64 + tx * 4] = v;
    }
  }
}

// ============ phase B: sequential 16-chunk state carry (64 blocks) ==========
__global__ __launch_bounds__(512) void carry_kernel(
    const float* __restrict__ proj,
    const float* __restrict__ Bh,
    const float* __restrict__ dHT,
    const float2* __restrict__ de_g,
    float* __restrict__ Heff) {
  const int bh = blockIdx.x;
  const int b = bh >> 5, h = bh & 31;
  const int tid = threadIdx.x;
  const int n = tid >> 2;
  const int p0 = (tid & 3) * 16;
  float hreg[16] = {};
  for (int c = 0; c < NCH; ++c) {
    float2 de = de_g[bh * NCH + c];
    float heff[16];
    if (c == 0) {
#pragma unroll
      for (int j = 0; j < 16; ++j) heff[j] = 0.0f;
    } else {
      int lprev = c * CH - 1;
      float Bp = Bh[((size_t)bh * SEQ + lprev) * DSTATE + n];
      const float4* xp4 = (const float4*)&proj[(size_t)(b * SEQ + lprev) * DPROJ + OFF_X + h * 64 + p0];
      float eB = de.y * Bp;
#pragma unroll
      for (int j4 = 0; j4 < 4; ++j4) {
        float4 xv = xp4[j4];
        heff[j4 * 4 + 0] = hreg[j4 * 4 + 0] + eB * xv.x;
        heff[j4 * 4 + 1] = hreg[j4 * 4 + 1] + eB * xv.y;
        heff[j4 * 4 + 2] = hreg[j4 * 4 + 2] + eB * xv.z;
        heff[j4 * 4 + 3] = hreg[j4 * 4 + 3] + eB * xv.w;
      }
    }
    size_t base = (((size_t)bh * NCH + c) * 128 + n) * 64 + p0;
#pragma unroll
    for (int j4 = 0; j4 < 4; ++j4)
      *(float4*)&Heff[base + j4 * 4] = *(const float4*)&heff[j4 * 4];
#pragma unroll
    for (int j4 = 0; j4 < 4; ++j4) {
      float4 dh = *(const float4*)&dHT[base + j4 * 4];
      hreg[j4 * 4 + 0] = de.x * heff[j4 * 4 + 0] + dh.x;
      hreg[j4 * 4 + 1] = de.x * heff[j4 * 4 + 1] + dh.y;
      hreg[j4 * 4 + 2] = de.x * heff[j4 * 4 + 2] + dh.z;
      hreg[j4 * 4 + 3] = de.x * heff[j4 * 4 + 3] + dh.w;
    }
  }
}

// ============ phase C: Y2 = G*(C @ Heff) + Y1 + D*x, gate, -> Y =============
__global__ __launch_bounds__(256) void inter_kernel(
    const float* __restrict__ proj,
    const float* __restrict__ Chh,
    const float* __restrict__ Heff,
    const float* __restrict__ Gv_g,
    const float* __restrict__ Dp,
    float* __restrict__ Yacc) {
  __shared__ float sC[64][132];
  __shared__ float sH[128][68];
  __shared__ float sGv[64];
  const int blk = blockIdx.x;
  const int bh = blk >> 4, ch = blk & 15;
  const int b = bh >> 5, h = bh & 31;
  const int t0 = ch * CH;
  const int tid = threadIdx.x;
  {
    const int row = tid >> 5, c4 = tid & 31;
#pragma unroll
    for (int pass = 0; pass < 8; ++pass) {
      int l = t0 + pass * 8 + row;
      float4 cv = *(const float4*)&Chh[((size_t)bh * SEQ + l) * DSTATE + c4 * 4];
      *(float4*)&sC[pass * 8 + row][c4 * 4] = cv;
    }
    const int hr = tid >> 4, hc = tid & 15;
#pragma unroll
    for (int pass = 0; pass < 8; ++pass) {
      int n = pass * 16 + hr;
      float4 hv = *(const float4*)&Heff[(((size_t)bh * NCH + ch) * 128 + n) * 64 + hc * 4];
      *(float4*)&sH[n][hc * 4] = hv;
    }
    if (tid < 64) sGv[tid] = Gv_g[((size_t)bh * NCH + ch) * 64 + tid];
  }
  __syncthreads();
  const int ty = tid >> 4, tx = tid & 15;
  float acc[4][4] = {};
  for (int n = 0; n < 128; n += 4) {
    float4 cv[4], hv[4];
#pragma unroll
    for (int i = 0; i < 4; ++i) cv[i] = *(const float4*)&sC[ty * 4 + i][n];
#pragma unroll
    for (int k = 0; k < 4; ++k) hv[k] = *(const float4*)&sH[n + k][tx * 4];
#pragma unroll
    for (int k = 0; k < 4; ++k) {
      const float* hp = (const float*)&hv[k];
#pragma unroll
      for (int i = 0; i < 4; ++i) {
        float cva = ((const float*)&cv[i])[k];
#pragma unroll
        for (int j = 0; j < 4; ++j)
          acc[i][j] = fmaf(cva, hp[j], acc[i][j]);
      }
    }
  }
  const float Dv = Dp[h];
#pragma unroll
  for (int i = 0; i < 4; ++i) {
    int l = t0 + ty * 4 + i;
    float gt = sGv[ty * 4 + i];
    size_t rowp = (size_t)(b * SEQ + l) * DPROJ;
    float4 xv = *(const float4*)&proj[rowp + OFF_X + h * 64 + tx * 4];
    float4 zv = *(const float4*)&proj[rowp + OFF_Z + h * 64 + tx * 4];
    size_t yo = (size_t)(b * SEQ + l) * DINNER + h * 64 + tx * 4;
    float4 y1 = *(const float4*)&Yacc[yo];
    float y[4];
    y[0] = y1.x + gt * acc[i][0] + Dv * xv.x;
    y[1] = y1.y + gt * acc[i][1] + Dv * xv.y;
    y[2] = y1.z + gt * acc[i][2] + Dv * xv.z;
    y[3] = y1.w + gt * acc[i][3] + Dv * xv.w;
    const float* zp = (const float*)&zv;
    float4 o;
    float* op = (float*)&o;
#pragma unroll
    for (int j = 0; j < 4; ++j) {
      float z = zp[j];
      float sg = 1.0f / (1.0f + expf(-z));
      op[j] = y[j] * z * sg;
    }
    *(float4*)&Yacc[yo] = o;
  }
}

extern "C" void kernel_launch(void* const* d_in, const int* in_sizes, int n_in,
                              void* d_out, int out_size, void* d_ws, size_t ws_size,
                              hipStream_t stream) {
  const float* u       = (const float*)d_in[0];
  const float* W_in    = (const float*)d_in[1];
  const float* W_out   = (const float*)d_in[2];
  const float* dt_bias = (const float*)d_in[3];
  const float* B_bias  = (const float*)d_in[4];
  const float* C_bias  = (const float*)d_in[5];
  const float* Bnw     = (const float*)d_in[6];
  const float* Cnw     = (const float*)d_in[7];
  const float* Dp      = (const float*)d_in[8];
  float* out = (float*)d_out;

  char* ws = (char*)d_ws;
  float*  proj  = (float*)(ws);                    // 36,700,160
  float4* sc4   = (float4*)(ws + 36700160);        //  1,048,576
  float*  theta = (float*)(ws + 37748736);         //  8,388,608
  float*  Bh    = (float*)(ws + 46137344);         // 33,554,432
  float*  Ch    = (float*)(ws + 79691776);         // 33,554,432
  float*  Y     = (float*)(ws + 113246208);        // 16,777,216
  float*  dHT   = (float*)(ws + 130023424);        // 33,554,432
  float*  Heff  = (float*)(ws + 163577856);        // 33,554,432
  float*  Gv    = (float*)(ws + 197132288);        //    262,144
  float2* deg   = (float2*)(ws + 197394432);       //      8,192
  // temporal overlays in the dHT region (dead outside chunk->carry window):
  u16* ub16 = (u16*)(ws + 130023424);              // 4,194,304  (before gemm1)
  u16* Wi16 = (u16*)(ws + 134217728);              // 9,175,040  (before gemm1)
  u16* Y16  = (u16*)(ws + 130023424);              // 8,388,608  (after inter)
  u16* Wo16 = (u16*)(ws + 138412032);              // 4,194,304  (after inter)

  // convert inputs to bf16
  cvt_bf16<<<2048, 256, 0, stream>>>(u, ub16, 524288);
  cvt_bf16<<<4480, 256, 0, stream>>>(W_in, Wi16, 1146880);
  // 1) proj = u @ W_in^T  (MFMA bf16)
  gemm_bf16<<<dim3(DPROJ / 128, (BATCH * SEQ) / 128), 256, 0, stream>>>(
      ub16, Wi16, proj, BATCH * SEQ, DPROJ, DMODEL);
  scalars_kernel<<<(BATCH * SEQ * NHEADS) / 256, 256, 0, stream>>>(proj, dt_bias, sc4);
  theta_kernel<<<BATCH * NHEADS, 1024, 0, stream>>>(proj, sc4, (float4*)theta);
  rope_kernel<<<BATCH * SEQ, 128, 0, stream>>>(proj, theta, B_bias, C_bias, Bnw, Cnw, Bh, Ch);
  chunk_kernel<<<BATCH * NHEADS * NCH, 256, 0, stream>>>(
      proj, sc4, Bh, Ch, Y, dHT, Gv, deg);
  carry_kernel<<<BATCH * NHEADS, 512, 0, stream>>>(proj, Bh, dHT, deg, Heff);
  inter_kernel<<<BATCH * NHEADS * NCH, 256, 0, stream>>>(
      proj, Ch, Heff, Gv, Dp, Y);
  // convert Y and W_out to bf16 (dHT region is dead now)
  cvt_bf16<<<4096, 256, 0, stream>>>(Y, Y16, 1048576);
  cvt_bf16<<<2048, 256, 0, stream>>>(W_out, Wo16, 524288);
  // 2) out = Y @ W_out^T  (MFMA bf16)
  gemm_bf16<<<dim3(DMODEL / 128, (BATCH * SEQ) / 128), 256, 0, stream>>>(
      Y16, Wo16, out, BATCH * SEQ, DMODEL, DINNER);
}

// Round 6
// 333.661 us; speedup vs baseline: 7.3514x; 1.1719x over previous
//
#include <hip/hip_runtime.h>
#include <hip/hip_bf16.h>
#include <math.h>

#define BATCH 2
#define SEQ 1024
#define DMODEL 1024
#define DSTATE 128
#define HEADDIM 64
#define NHEADS 32
#define DINNER 2048
#define NUMANG 32
#define DPROJ 4480
#define DPROJ4 1120
#define CH 64
#define NCH 16
// proj row offsets (floats)
#define OFF_Z 0
#define OFF_X 2048
#define OFF_B 4096
#define OFF_C 4224
#define OFF_DT 4352
#define OFF_A 4384
#define OFF_TRAP 4416
#define OFF_ANG 4448

typedef __attribute__((ext_vector_type(8))) short bf16x8;
typedef __attribute__((ext_vector_type(4))) float f32x4;
typedef unsigned short u16;

__device__ __forceinline__ u16 f2bf(float f) {
  unsigned int u = __float_as_uint(f);
  u += 0x7FFFu + ((u >> 16) & 1u);
  return (u16)(u >> 16);
}
__device__ __forceinline__ float bf2f(u16 x) {
  return __uint_as_float(((unsigned int)x) << 16);
}

__global__ __launch_bounds__(256) void cvt_bf16(const float* __restrict__ in,
                                                u16* __restrict__ out, int n4) {
  int i = blockIdx.x * 256 + threadIdx.x;
  if (i >= n4) return;
  float4 v = ((const float4*)in)[i];
  ushort4 o;
  o.x = f2bf(v.x); o.y = f2bf(v.y); o.z = f2bf(v.z); o.w = f2bf(v.w);
  ((ushort4*)out)[i] = o;
}

// ---------------- bf16 MFMA GEMM: C[M][N] = A[M][K] @ B[N][K]^T ------------
__device__ __forceinline__ void gload_lds16(const void* g, void* l) {
  __builtin_amdgcn_global_load_lds(
      (const __attribute__((address_space(1))) unsigned int*)g,
      (__attribute__((address_space(3))) unsigned int*)l, 16, 0, 0);
}

__global__ __launch_bounds__(256) void gemm_bf16(const u16* __restrict__ A,
                                                 const u16* __restrict__ B,
                                                 float* __restrict__ C,
                                                 int M, int N, int K) {
  __shared__ u16 As[128 * 64];
  __shared__ u16 Bs[128 * 64];
  const int tid = threadIdx.x;
  const int lane = tid & 63, wave = tid >> 6;
  const int bm = blockIdx.y * 128, bn = blockIdx.x * 128;
  const int wm = (wave >> 1) * 64, wn = (wave & 1) * 64;

  const int srow = wave * 8 + (lane >> 3);
  const int scol = (((lane & 7) ^ ((lane >> 3) & 7)) * 8);
  const u16* Ab = A + (size_t)(bm + srow) * K + scol;
  const u16* Bb = B + (size_t)(bn + srow) * K + scol;
  u16* Asw = As + wave * 512;
  u16* Bsw = Bs + wave * 512;

  f32x4 acc[4][4];
#pragma unroll
  for (int i = 0; i < 4; ++i)
#pragma unroll
    for (int j = 0; j < 4; ++j)
      acc[i][j] = (f32x4){0.f, 0.f, 0.f, 0.f};

  const int fr = lane & 15;
  const int fq = lane >> 4;
  const int sw = fr & 7;

  for (int k0 = 0; k0 < K; k0 += 64) {
    __syncthreads();
#pragma unroll
    for (int it = 0; it < 4; ++it) {
      gload_lds16(Ab + (size_t)(it * 32) * K + k0, Asw + it * 2048);
      gload_lds16(Bb + (size_t)(it * 32) * K + k0, Bsw + it * 2048);
    }
    __syncthreads();
#pragma unroll
    for (int kh = 0; kh < 2; ++kh) {
      bf16x8 af[4], bfv[4];
#pragma unroll
      for (int i = 0; i < 4; ++i) {
        int row = wm + i * 16 + fr;
        af[i] = *(const bf16x8*)(As + row * 64 + (((kh * 4 + fq) ^ sw) * 8));
      }
#pragma unroll
      for (int j = 0; j < 4; ++j) {
        int row = wn + j * 16 + fr;
        bfv[j] = *(const bf16x8*)(Bs + row * 64 + (((kh * 4 + fq) ^ sw) * 8));
      }
#pragma unroll
      for (int i = 0; i < 4; ++i)
#pragma unroll
        for (int j = 0; j < 4; ++j)
          acc[i][j] = __builtin_amdgcn_mfma_f32_16x16x32_bf16(af[i], bfv[j], acc[i][j], 0, 0, 0);
    }
  }
  const int orow = bm + wm + fq * 4;
  const int ocol = bn + wn + fr;
#pragma unroll
  for (int i = 0; i < 4; ++i)
#pragma unroll
    for (int j = 0; j < 4; ++j)
#pragma unroll
      for (int r = 0; r < 4; ++r)
        C[(size_t)(orow + i * 16 + r) * N + ocol + j * 16] = acc[i][j][r];
}

// ---------------- per-(b,l,h) scalars ----------------
__device__ __forceinline__ float softplusf(float x) {
  return fmaxf(x, 0.f) + log1pf(expf(-fabsf(x)));
}

__global__ __launch_bounds__(256) void scalars_kernel(const float* __restrict__ proj,
                                                      const float* __restrict__ dt_bias,
                                                      float4* __restrict__ sc4) {
  int idx = blockIdx.x * 256 + threadIdx.x;
  int b = idx >> 15;
  int rem = idx & 32767;
  int l = rem >> 5, h = rem & 31;
  size_t row = (size_t)(b * SEQ + l) * DPROJ;
  float ddt = proj[row + OFF_DT + h];
  float dda = proj[row + OFF_A + h];
  float trp = proj[row + OFF_TRAP + h];
  float a = fminf(-softplusf(dda), -1e-4f);
  float dt = softplusf(ddt + dt_bias[h]);
  float adt = a * dt;
  float lam = 1.0f / (1.0f + expf(-trp));
  sc4[((size_t)(b * NHEADS + h)) * SEQ + l] = make_float4(dt, expf(adt), lam, adt);
}

// ---------------- theta = cumsum_l(angles * dt) ----------------
__global__ __launch_bounds__(1024) void theta_kernel(const float* __restrict__ proj,
                                                     const float4* __restrict__ sc4,
                                                     float4* __restrict__ theta4) {
  __shared__ float4 part[16];
  __shared__ float4 part2[16];
  const int bh = blockIdx.x;
  const int b = bh >> 5, h = bh & 31;
  const int l = threadIdx.x;
  const int lane = l & 63, w = l >> 6;
  const float dtv = sc4[(size_t)bh * SEQ + l].x;
  const size_t row = (size_t)(b * SEQ + l) * DPROJ4 + (OFF_ANG / 4);
#pragma unroll
  for (int kc = 0; kc < 8; ++kc) {
    float4 v = ((const float4*)proj)[row + kc];
    v.x *= dtv; v.y *= dtv; v.z *= dtv; v.w *= dtv;
#pragma unroll
    for (int off = 1; off < 64; off <<= 1) {
      float tx = __shfl_up(v.x, off, 64);
      float ty = __shfl_up(v.y, off, 64);
      float tz = __shfl_up(v.z, off, 64);
      float tw = __shfl_up(v.w, off, 64);
      if (lane >= off) { v.x += tx; v.y += ty; v.z += tz; v.w += tw; }
    }
    if (lane == 63) part[w] = v;
    __syncthreads();
    if (l < 16) {
      float4 p = part[l];
#pragma unroll
      for (int off = 1; off < 16; off <<= 1) {
        float tx = __shfl_up(p.x, off, 16);
        float ty = __shfl_up(p.y, off, 16);
        float tz = __shfl_up(p.z, off, 16);
        float tw = __shfl_up(p.w, off, 16);
        if (l >= off) { p.x += tx; p.y += ty; p.z += tz; p.w += tw; }
      }
      part2[l] = p;
    }
    __syncthreads();
    if (w > 0) {
      float4 o = part2[w - 1];
      v.x += o.x; v.y += o.y; v.z += o.z; v.w += o.w;
    }
    theta4[((size_t)(b * SEQ + l) * NHEADS + h) * 8 + kc] = v;
  }
}

// ---------------- RMSNorm + bias + RoPE -> Bh16, Ch16 (bf16) ----------
__global__ __launch_bounds__(128) void rope_kernel(const float* __restrict__ proj,
                                                   const float* __restrict__ theta,
                                                   const float* __restrict__ B_bias,
                                                   const float* __restrict__ C_bias,
                                                   const float* __restrict__ Bnw,
                                                   const float* __restrict__ Cnw,
                                                   u16* __restrict__ Bh,
                                                   u16* __restrict__ Ch) {
  const int bl = blockIdx.x;
  const int b = bl >> 10, l = bl & 1023;
  const int n = threadIdx.x;
  __shared__ float sB[128], sC[128], red[4];
  const size_t row = (size_t)bl * DPROJ;
  float bv = proj[row + OFF_B + n];
  float cv = proj[row + OFF_C + n];
  float sb = bv * bv, sc = cv * cv;
  for (int m = 32; m; m >>= 1) { sb += __shfl_xor(sb, m); sc += __shfl_xor(sc, m); }
  const int wave = n >> 6;
  if ((n & 63) == 0) { red[wave * 2] = sb; red[wave * 2 + 1] = sc; }
  __syncthreads();
  float rb = rsqrtf((red[0] + red[2]) / 128.0f + 1e-5f);
  float rc = rsqrtf((red[1] + red[3]) / 128.0f + 1e-5f);
  sB[n] = bv * rb * Bnw[n];
  sC[n] = cv * rc * Cnw[n];
  __syncthreads();
  for (int h = 0; h < 32; ++h) {
    float ob, oc;
    const size_t thbase = ((size_t)bl * NHEADS + h) * NUMANG;
    if (n < 64) {
      int k = n & 31;
      float th = theta[thbase + k];
      float cth = cosf(th), sth = sinf(th);
      float b1 = sB[k]      + B_bias[h * 128 + k];
      float b2 = sB[k + 32] + B_bias[h * 128 + k + 32];
      float c1 = sC[k]      + C_bias[h * 128 + k];
      float c2 = sC[k + 32] + C_bias[h * 128 + k + 32];
      if (n < 32) { ob = b1 * cth - b2 * sth; oc = c1 * cth - c2 * sth; }
      else        { ob = b1 * sth + b2 * cth; oc = c1 * sth + c2 * cth; }
    } else {
      ob = sB[n] + B_bias[h * 128 + n];
      oc = sC[n] + C_bias[h * 128 + n];
    }
    size_t o = (((size_t)(b * NHEADS + h)) * SEQ + l) * DSTATE + n;
    Bh[o] = f2bf(ob);
    Ch[o] = f2bf(oc);
  }
}

// ============ chunked scan, phase A: MFMA per-chunk GEMMs ==============
#define SWB 136  // 128+8 bf16 stride
#define SWS 72   // 64+8 bf16 stride

__global__ __launch_bounds__(256) void chunk_kernel(
    const float* __restrict__ proj,
    const float4* __restrict__ sc4,
    const u16* __restrict__ Bh16,
    const u16* __restrict__ Ch16,
    float* __restrict__ Yacc,
    float* __restrict__ dHT,
    float* __restrict__ Gv_g,
    float2* __restrict__ de_g) {
  __shared__ u16 sCb[64 * SWB];
  __shared__ u16 sBb[64 * SWB];
  __shared__ u16 sBt[128 * SWS];
  __shared__ u16 sXt[64 * SWS];
  __shared__ u16 sSw[64 * SWS];
  __shared__ float sA[64], sW[64], sDL[64], sCV[64];

  const int blk = blockIdx.x;
  const int bh = blk >> 4, ch = blk & 15;
  const int b = bh >> 5, h = bh & 31;
  const int t0 = ch * CH;
  const int tid = threadIdx.x;
  const int lane = tid & 63, wave = tid >> 6;

  // ---- staging: B/C bf16 rows + B^T + X^T ----
  {
    const int row = tid >> 5;
    const int c4 = tid & 31;
#pragma unroll
    for (int pass = 0; pass < 8; ++pass) {
      int ll = pass * 8 + row;
      int l = t0 + ll;
      ushort4 cv = *(const ushort4*)&Ch16[((size_t)bh * SEQ + l) * DSTATE + c4 * 4];
      ushort4 bv = *(const ushort4*)&Bh16[((size_t)bh * SEQ + l) * DSTATE + c4 * 4];
      *(ushort4*)&sCb[ll * SWB + c4 * 4] = cv;
      *(ushort4*)&sBb[ll * SWB + c4 * 4] = bv;
      sBt[(c4 * 4 + 0) * SWS + ll] = bv.x;
      sBt[(c4 * 4 + 1) * SWS + ll] = bv.y;
      sBt[(c4 * 4 + 2) * SWS + ll] = bv.z;
      sBt[(c4 * 4 + 3) * SWS + ll] = bv.w;
    }
    const int xr = tid >> 2, xc = tid & 3;
    const float* xrow = &proj[(size_t)(b * SEQ + t0 + xr) * DPROJ + OFF_X + h * 64];
#pragma unroll
    for (int j = 0; j < 4; ++j) {
      float4 xv = *(const float4*)(xrow + xc * 16 + j * 4);
      int p = xc * 16 + j * 4;
      sXt[(p + 0) * SWS + xr] = f2bf(xv.x);
      sXt[(p + 1) * SWS + xr] = f2bf(xv.y);
      sXt[(p + 2) * SWS + xr] = f2bf(xv.z);
      sXt[(p + 3) * SWS + xr] = f2bf(xv.w);
    }
  }
  if (tid < 64) {
    float4 s = sc4[(size_t)bh * SEQ + t0 + tid];
    float dt = s.x, lam = s.z, adt = s.w;
    float A = adt;
#pragma unroll
    for (int off = 1; off < 64; off <<= 1) {
      float t = __shfl_up(A, off, 64);
      if (tid >= off) A += t;
    }
    float dtn = __shfl_down(dt, 1, 64);
    float lamn = __shfl_down(lam, 1, 64);
    float dl = dt * lam;
    float w = dl + dtn * (1.0f - lamn);
    if (tid == 63) w = 0.0f;
    float A63 = __shfl(A, 63, 64);
    float cv = (tid < 63) ? expf(A63 - A) * w : dl;
    sA[tid] = A; sW[tid] = w; sCV[tid] = cv; sDL[tid] = dl;
    Gv_g[((size_t)bh * NCH + ch) * 64 + tid] = expf(A);
    if (tid == 0) de_g[(size_t)bh * NCH + ch] = make_float2(expf(A63), dt * (1.0f - lam));
  }
  __syncthreads();

  const int fr = lane & 15, fq = lane >> 4;

  // ---- S^T[s][t] = sum_n B[s][n]*C[t][n]; mask by decay; -> sSw[t][s] bf16
  {
    f32x4 acc[4];
#pragma unroll
    for (int j = 0; j < 4; ++j) acc[j] = (f32x4){0.f, 0.f, 0.f, 0.f};
#pragma unroll
    for (int kc = 0; kc < 4; ++kc) {
      bf16x8 af = *(const bf16x8*)&sBb[(wave * 16 + fr) * SWB + kc * 32 + fq * 8];
#pragma unroll
      for (int j = 0; j < 4; ++j) {
        bf16x8 bf = *(const bf16x8*)&sCb[(j * 16 + fr) * SWB + kc * 32 + fq * 8];
        acc[j] = __builtin_amdgcn_mfma_f32_16x16x32_bf16(af, bf, acc[j], 0, 0, 0);
      }
    }
    const int sbase = wave * 16 + fq * 4;
#pragma unroll
    for (int j = 0; j < 4; ++j) {
      int t = j * 16 + fr;
      float At = sA[t], dlt = sDL[t];
#pragma unroll
      for (int r = 0; r < 4; ++r) {
        int ss = sbase + r;
        float f = (ss < t) ? expf(At - sA[ss]) * sW[ss] : ((ss == t) ? dlt : 0.0f);
        sSw[t * SWS + ss] = f2bf(acc[j][r] * f);
      }
    }
  }
  __syncthreads();

  // ---- Y1[t][p] = sum_s Sw[t][s] * Xt[p][s] -> Yacc ----
  {
    f32x4 acc[4];
#pragma unroll
    for (int j = 0; j < 4; ++j) acc[j] = (f32x4){0.f, 0.f, 0.f, 0.f};
#pragma unroll
    for (int kc = 0; kc < 2; ++kc) {
      bf16x8 af = *(const bf16x8*)&sSw[(wave * 16 + fr) * SWS + kc * 32 + fq * 8];
#pragma unroll
      for (int j = 0; j < 4; ++j) {
        bf16x8 bf = *(const bf16x8*)&sXt[(j * 16 + fr) * SWS + kc * 32 + fq * 8];
        acc[j] = __builtin_amdgcn_mfma_f32_16x16x32_bf16(af, bf, acc[j], 0, 0, 0);
      }
    }
    const int tr = t0 + wave * 16 + fq * 4;
#pragma unroll
    for (int j = 0; j < 4; ++j) {
      int p = j * 16 + fr;
#pragma unroll
      for (int r = 0; r < 4; ++r)
        Yacc[(size_t)(b * SEQ + tr + r) * DINNER + h * 64 + p] = acc[j][r];
    }
  }
  __syncthreads();

  // ---- scale Xt columns by cv[s] in place ----
  {
    const int p = tid >> 2;
    const int s0 = (tid & 3) * 16;
#pragma unroll
    for (int k = 0; k < 16; ++k) {
      int s = s0 + k;
      sXt[p * SWS + s] = f2bf(bf2f(sXt[p * SWS + s]) * sCV[s]);
    }
  }
  __syncthreads();

  // ---- dHT[n][p] = sum_s Bt[n][s] * cvXt[p][s] ----
  {
#pragma unroll
    for (int mi = 0; mi < 2; ++mi) {
      f32x4 acc[4];
#pragma unroll
      for (int j = 0; j < 4; ++j) acc[j] = (f32x4){0.f, 0.f, 0.f, 0.f};
      const int nrow = wave * 32 + mi * 16;
#pragma unroll
      for (int kc = 0; kc < 2; ++kc) {
        bf16x8 af = *(const bf16x8*)&sBt[(nrow + fr) * SWS + kc * 32 + fq * 8];
#pragma unroll
        for (int j = 0; j < 4; ++j) {
          bf16x8 bf = *(const bf16x8*)&sXt[(j * 16 + fr) * SWS + kc * 32 + fq * 8];
          acc[j] = __builtin_amdgcn_mfma_f32_16x16x32_bf16(af, bf, acc[j], 0, 0, 0);
        }
      }
      const int nr = nrow + fq * 4;
#pragma unroll
      for (int j = 0; j < 4; ++j) {
        int p = j * 16 + fr;
#pragma unroll
        for (int r = 0; r < 4; ++r)
          dHT[(((size_t)bh * NCH + ch) * 128 + nr + r) * 64 + p] = acc[j][r];
      }
    }
  }
}

// ============ phase B: sequential 16-chunk state carry ==========
__global__ __launch_bounds__(512) void carry_kernel(
    const float* __restrict__ proj,
    const u16* __restrict__ Bh16,
    const float* __restrict__ dHT,
    const float2* __restrict__ de_g,
    float* __restrict__ Heff) {
  const int bh = blockIdx.x;
  const int b = bh >> 5, h = bh & 31;
  const int tid = threadIdx.x;
  const int n = tid >> 2;
  const int p0 = (tid & 3) * 16;
  float hreg[16] = {};
  for (int c = 0; c < NCH; ++c) {
    float2 de = de_g[bh * NCH + c];
    float heff[16];
    if (c == 0) {
#pragma unroll
      for (int j = 0; j < 16; ++j) heff[j] = 0.0f;
    } else {
      int lprev = c * CH - 1;
      float Bp = bf2f(Bh16[((size_t)bh * SEQ + lprev) * DSTATE + n]);
      const float4* xp4 = (const float4*)&proj[(size_t)(b * SEQ + lprev) * DPROJ + OFF_X + h * 64 + p0];
      float eB = de.y * Bp;
#pragma unroll
      for (int j4 = 0; j4 < 4; ++j4) {
        float4 xv = xp4[j4];
        heff[j4 * 4 + 0] = hreg[j4 * 4 + 0] + eB * xv.x;
        heff[j4 * 4 + 1] = hreg[j4 * 4 + 1] + eB * xv.y;
        heff[j4 * 4 + 2] = hreg[j4 * 4 + 2] + eB * xv.z;
        heff[j4 * 4 + 3] = hreg[j4 * 4 + 3] + eB * xv.w;
      }
    }
    size_t base = (((size_t)bh * NCH + c) * 128 + n) * 64 + p0;
#pragma unroll
    for (int j4 = 0; j4 < 4; ++j4)
      *(float4*)&Heff[base + j4 * 4] = *(const float4*)&heff[j4 * 4];
#pragma unroll
    for (int j4 = 0; j4 < 4; ++j4) {
      float4 dh = *(const float4*)&dHT[base + j4 * 4];
      hreg[j4 * 4 + 0] = de.x * heff[j4 * 4 + 0] + dh.x;
      hreg[j4 * 4 + 1] = de.x * heff[j4 * 4 + 1] + dh.y;
      hreg[j4 * 4 + 2] = de.x * heff[j4 * 4 + 2] + dh.z;
      hreg[j4 * 4 + 3] = de.x * heff[j4 * 4 + 3] + dh.w;
    }
  }
}

// ============ phase C: Y2 = G*(C @ Heff) + Y1 + D*x, gate ============
__global__ __launch_bounds__(256) void inter_kernel(
    const float* __restrict__ proj,
    const u16* __restrict__ Ch16,
    const float* __restrict__ Heff,
    const float* __restrict__ Gv_g,
    const float* __restrict__ Dp,
    float* __restrict__ Yacc) {
  __shared__ float sC[64][132];
  __shared__ float sH[128][68];
  __shared__ float sGv[64];
  const int blk = blockIdx.x;
  const int bh = blk >> 4, ch = blk & 15;
  const int b = bh >> 5, h = bh & 31;
  const int t0 = ch * CH;
  const int tid = threadIdx.x;
  {
    const int row = tid >> 5, c4 = tid & 31;
#pragma unroll
    for (int pass = 0; pass < 8; ++pass) {
      int l = t0 + pass * 8 + row;
      ushort4 cv = *(const ushort4*)&Ch16[((size_t)bh * SEQ + l) * DSTATE + c4 * 4];
      float4 cf = {bf2f(cv.x), bf2f(cv.y), bf2f(cv.z), bf2f(cv.w)};
      *(float4*)&sC[pass * 8 + row][c4 * 4] = cf;
    }
    const int hr = tid >> 4, hc = tid & 15;
#pragma unroll
    for (int pass = 0; pass < 8; ++pass) {
      int n = pass * 16 + hr;
      float4 hv = *(const float4*)&Heff[(((size_t)bh * NCH + ch) * 128 + n) * 64 + hc * 4];
      *(float4*)&sH[n][hc * 4] = hv;
    }
    if (tid < 64) sGv[tid] = Gv_g[((size_t)bh * NCH + ch) * 64 + tid];
  }
  __syncthreads();
  const int ty = tid >> 4, tx = tid & 15;
  float acc[4][4] = {};
  for (int n = 0; n < 128; n += 4) {
    float4 cv[4], hv[4];
#pragma unroll
    for (int i = 0; i < 4; ++i) cv[i] = *(const float4*)&sC[ty * 4 + i][n];
#pragma unroll
    for (int k = 0; k < 4; ++k) hv[k] = *(const float4*)&sH[n + k][tx * 4];
#pragma unroll
    for (int k = 0; k < 4; ++k) {
      const float* hp = (const float*)&hv[k];
#pragma unroll
      for (int i = 0; i < 4; ++i) {
        float cva = ((const float*)&cv[i])[k];
#pragma unroll
        for (int j = 0; j < 4; ++j)
          acc[i][j] = fmaf(cva, hp[j], acc[i][j]);
      }
    }
  }
  const float Dv = Dp[h];
#pragma unroll
  for (int i = 0; i < 4; ++i) {
    int l = t0 + ty * 4 + i;
    float gt = sGv[ty * 4 + i];
    size_t rowp = (size_t)(b * SEQ + l) * DPROJ;
    float4 xv = *(const float4*)&proj[rowp + OFF_X + h * 64 + tx * 4];
    float4 zv = *(const float4*)&proj[rowp + OFF_Z + h * 64 + tx * 4];
    size_t yo = (size_t)(b * SEQ + l) * DINNER + h * 64 + tx * 4;
    float4 y1 = *(const float4*)&Yacc[yo];
    float y[4];
    y[0] = y1.x + gt * acc[i][0] + Dv * xv.x;
    y[1] = y1.y + gt * acc[i][1] + Dv * xv.y;
    y[2] = y1.z + gt * acc[i][2] + Dv * xv.z;
    y[3] = y1.w + gt * acc[i][3] + Dv * xv.w;
    const float* zp = (const float*)&zv;
    float4 o;
    float* op = (float*)&o;
#pragma unroll
    for (int j = 0; j < 4; ++j) {
      float z = zp[j];
      float sg = 1.0f / (1.0f + expf(-z));
      op[j] = y[j] * z * sg;
    }
    *(float4*)&Yacc[yo] = o;
  }
}

extern "C" void kernel_launch(void* const* d_in, const int* in_sizes, int n_in,
                              void* d_out, int out_size, void* d_ws, size_t ws_size,
                              hipStream_t stream) {
  const float* u       = (const float*)d_in[0];
  const float* W_in    = (const float*)d_in[1];
  const float* W_out   = (const float*)d_in[2];
  const float* dt_bias = (const float*)d_in[3];
  const float* B_bias  = (const float*)d_in[4];
  const float* C_bias  = (const float*)d_in[5];
  const float* Bnw     = (const float*)d_in[6];
  const float* Cnw     = (const float*)d_in[7];
  const float* Dp      = (const float*)d_in[8];
  float* out = (float*)d_out;

  char* ws = (char*)d_ws;
  float*  proj  = (float*)(ws);                    // 36,700,160
  float4* sc4   = (float4*)(ws + 36700160);        //  1,048,576
  float*  theta = (float*)(ws + 37748736);         //  8,388,608
  u16*    Bh16  = (u16*)(ws + 46137344);           // 16,777,216
  u16*    Ch16  = (u16*)(ws + 62914560);           // 16,777,216
  float*  Y     = (float*)(ws + 79691776);         // 16,777,216
  float*  dHT   = (float*)(ws + 96468992);         // 33,554,432
  float*  Heff  = (float*)(ws + 130023424);        // 33,554,432
  float*  Gv    = (float*)(ws + 163577856);        //    262,144
  float2* deg   = (float2*)(ws + 163840000);       //      8,192
  // overlays: ub16/Wi16 live in Heff region (dead until carry);
  //           Y16/Wo16 live in dHT region (dead after carry).
  u16* ub16 = (u16*)(ws + 130023424);              //  4,194,304
  u16* Wi16 = (u16*)(ws + 134217728);              //  9,175,040
  u16* Y16  = (u16*)(ws + 96468992);               //  8,388,608
  u16* Wo16 = (u16*)(ws + 109051904);              //  4,194,304

  cvt_bf16<<<2048, 256, 0, stream>>>(u, ub16, 524288);
  cvt_bf16<<<4480, 256, 0, stream>>>(W_in, Wi16, 1146880);
  gemm_bf16<<<dim3(DPROJ / 128, (BATCH * SEQ) / 128), 256, 0, stream>>>(
      ub16, Wi16, proj, BATCH * SEQ, DPROJ, DMODEL);
  scalars_kernel<<<(BATCH * SEQ * NHEADS) / 256, 256, 0, stream>>>(proj, dt_bias, sc4);
  theta_kernel<<<BATCH * NHEADS, 1024, 0, stream>>>(proj, sc4, (float4*)theta);
  rope_kernel<<<BATCH * SEQ, 128, 0, stream>>>(proj, theta, B_bias, C_bias, Bnw, Cnw, Bh16, Ch16);
  chunk_kernel<<<BATCH * NHEADS * NCH, 256, 0, stream>>>(
      proj, sc4, Bh16, Ch16, Y, dHT, Gv, deg);
  carry_kernel<<<BATCH * NHEADS, 512, 0, stream>>>(proj, Bh16, dHT, deg, Heff);
  inter_kernel<<<BATCH * NHEADS * NCH, 256, 0, stream>>>(
      proj, Ch16, Heff, Gv, Dp, Y);
  cvt_bf16<<<4096, 256, 0, stream>>>(Y, Y16, 1048576);
  cvt_bf16<<<2048, 256, 0, stream>>>(W_out, Wo16, 524288);
  gemm_bf16<<<dim3(DMODEL / 128, (BATCH * SEQ) / 128), 256, 0, stream>>>(
      Y16, Wo16, out, BATCH * SEQ, DMODEL, DINNER);
}

// Round 7
// 292.376 us; speedup vs baseline: 8.3895x; 1.1412x over previous
//
#include <hip/hip_runtime.h>
#include <hip/hip_bf16.h>
#include <math.h>

#define BATCH 2
#define SEQ 1024
#define DMODEL 1024
#define DSTATE 128
#define HEADDIM 64
#define NHEADS 32
#define DINNER 2048
#define NUMANG 32
#define DPROJ 4480
#define CH 64
#define NCH 16
#define TAILSTART 4352
// proj row offsets (elements)
#define OFF_Z 0
#define OFF_X 2048
#define OFF_B 4096
#define OFF_C 4224
#define OFF_DT 4352
#define OFF_A 4384
#define OFF_TRAP 4416
#define OFF_ANG 4448

typedef __attribute__((ext_vector_type(8))) short bf16x8;
typedef __attribute__((ext_vector_type(4))) float f32x4;
typedef unsigned short u16;

__device__ __forceinline__ u16 f2bf(float f) {
  unsigned int u = __float_as_uint(f);
  u += 0x7FFFu + ((u >> 16) & 1u);
  return (u16)(u >> 16);
}
__device__ __forceinline__ float bf2f(u16 x) {
  return __uint_as_float(((unsigned int)x) << 16);
}

__global__ __launch_bounds__(256) void cvt_bf16(const float* __restrict__ in,
                                                u16* __restrict__ out, int n4) {
  int i = blockIdx.x * 256 + threadIdx.x;
  if (i >= n4) return;
  float4 v = ((const float4*)in)[i];
  ushort4 o;
  o.x = f2bf(v.x); o.y = f2bf(v.y); o.z = f2bf(v.z); o.w = f2bf(v.w);
  ((ushort4*)out)[i] = o;
}

__device__ __forceinline__ void gload_lds16(const void* g, void* l) {
  __builtin_amdgcn_global_load_lds(
      (const __attribute__((address_space(1))) unsigned int*)g,
      (__attribute__((address_space(3))) unsigned int*)l, 16, 0, 0);
}

// ============ 64x64-tile bf16 MFMA GEMM, C = A @ B^T ============
// variant 1: bf16 output + fp32 tail columns (>= TAILSTART)
__global__ __launch_bounds__(256) void gemm_proj64(const u16* __restrict__ A,
                                                   const u16* __restrict__ B,
                                                   u16* __restrict__ Cb,
                                                   float* __restrict__ tailF,
                                                   int M, int N, int K) {
  __shared__ u16 As[64 * 64];
  __shared__ u16 Bs[64 * 64];
  const int tid = threadIdx.x;
  const int lane = tid & 63, wave = tid >> 6;
  const int bm = blockIdx.y * 64, bn = blockIdx.x * 64;
  const int wm = (wave >> 1) * 32, wn = (wave & 1) * 32;
  const int srow = wave * 8 + (lane >> 3);
  const int scol = (((lane & 7) ^ ((lane >> 3) & 7)) * 8);
  const u16* Ab = A + (size_t)(bm + srow) * K + scol;
  const u16* Bb = B + (size_t)(bn + srow) * K + scol;
  u16* Asw = As + wave * 512;
  u16* Bsw = Bs + wave * 512;
  f32x4 acc[2][2];
#pragma unroll
  for (int i = 0; i < 2; ++i)
#pragma unroll
    for (int j = 0; j < 2; ++j) acc[i][j] = (f32x4){0.f, 0.f, 0.f, 0.f};
  const int fr = lane & 15, fq = lane >> 4, sw = fr & 7;

  for (int k0 = 0; k0 < K; k0 += 64) {
    __syncthreads();
#pragma unroll
    for (int it = 0; it < 2; ++it) {
      gload_lds16(Ab + (size_t)(it * 32) * K + k0, Asw + it * 2048);
      gload_lds16(Bb + (size_t)(it * 32) * K + k0, Bsw + it * 2048);
    }
    __syncthreads();
#pragma unroll
    for (int kh = 0; kh < 2; ++kh) {
      bf16x8 af[2], bfv[2];
#pragma unroll
      for (int i = 0; i < 2; ++i)
        af[i] = *(const bf16x8*)(As + (wm + i * 16 + fr) * 64 + (((kh * 4 + fq) ^ sw) * 8));
#pragma unroll
      for (int j = 0; j < 2; ++j)
        bfv[j] = *(const bf16x8*)(Bs + (wn + j * 16 + fr) * 64 + (((kh * 4 + fq) ^ sw) * 8));
#pragma unroll
      for (int i = 0; i < 2; ++i)
#pragma unroll
        for (int j = 0; j < 2; ++j)
          acc[i][j] = __builtin_amdgcn_mfma_f32_16x16x32_bf16(af[i], bfv[j], acc[i][j], 0, 0, 0);
    }
  }
  const int orow = bm + wm + fq * 4;
  const int ocol = bn + wn + fr;
  const bool tail = (bn >= TAILSTART);
#pragma unroll
  for (int i = 0; i < 2; ++i)
#pragma unroll
    for (int j = 0; j < 2; ++j)
#pragma unroll
      for (int r = 0; r < 4; ++r) {
        float v = acc[i][j][r];
        int row = orow + i * 16 + r, col = ocol + j * 16;
        Cb[(size_t)row * N + col] = f2bf(v);
        if (tail) tailF[(size_t)row * 128 + (col - TAILSTART)] = v;
      }
}

// variant 2: fp32 output
__global__ __launch_bounds__(256) void gemm_out64(const u16* __restrict__ A,
                                                  const u16* __restrict__ B,
                                                  float* __restrict__ C,
                                                  int M, int N, int K) {
  __shared__ u16 As[64 * 64];
  __shared__ u16 Bs[64 * 64];
  const int tid = threadIdx.x;
  const int lane = tid & 63, wave = tid >> 6;
  const int bm = blockIdx.y * 64, bn = blockIdx.x * 64;
  const int wm = (wave >> 1) * 32, wn = (wave & 1) * 32;
  const int srow = wave * 8 + (lane >> 3);
  const int scol = (((lane & 7) ^ ((lane >> 3) & 7)) * 8);
  const u16* Ab = A + (size_t)(bm + srow) * K + scol;
  const u16* Bb = B + (size_t)(bn + srow) * K + scol;
  u16* Asw = As + wave * 512;
  u16* Bsw = Bs + wave * 512;
  f32x4 acc[2][2];
#pragma unroll
  for (int i = 0; i < 2; ++i)
#pragma unroll
    for (int j = 0; j < 2; ++j) acc[i][j] = (f32x4){0.f, 0.f, 0.f, 0.f};
  const int fr = lane & 15, fq = lane >> 4, sw = fr & 7;

  for (int k0 = 0; k0 < K; k0 += 64) {
    __syncthreads();
#pragma unroll
    for (int it = 0; it < 2; ++it) {
      gload_lds16(Ab + (size_t)(it * 32) * K + k0, Asw + it * 2048);
      gload_lds16(Bb + (size_t)(it * 32) * K + k0, Bsw + it * 2048);
    }
    __syncthreads();
#pragma unroll
    for (int kh = 0; kh < 2; ++kh) {
      bf16x8 af[2], bfv[2];
#pragma unroll
      for (int i = 0; i < 2; ++i)
        af[i] = *(const bf16x8*)(As + (wm + i * 16 + fr) * 64 + (((kh * 4 + fq) ^ sw) * 8));
#pragma unroll
      for (int j = 0; j < 2; ++j)
        bfv[j] = *(const bf16x8*)(Bs + (wn + j * 16 + fr) * 64 + (((kh * 4 + fq) ^ sw) * 8));
#pragma unroll
      for (int i = 0; i < 2; ++i)
#pragma unroll
        for (int j = 0; j < 2; ++j)
          acc[i][j] = __builtin_amdgcn_mfma_f32_16x16x32_bf16(af[i], bfv[j], acc[i][j], 0, 0, 0);
    }
  }
  const int orow = bm + wm + fq * 4;
  const int ocol = bn + wn + fr;
#pragma unroll
  for (int i = 0; i < 2; ++i)
#pragma unroll
    for (int j = 0; j < 2; ++j)
#pragma unroll
      for (int r = 0; r < 4; ++r)
        C[(size_t)(orow + i * 16 + r) * N + ocol + j * 16] = acc[i][j][r];
}

// ---------------- scalars + theta cumsum fused, per (b,h) ----------------
__device__ __forceinline__ float softplusf(float x) {
  return fmaxf(x, 0.f) + log1pf(expf(-fabsf(x)));
}

__global__ __launch_bounds__(1024) void theta_kernel(const float* __restrict__ tailF,
                                                     const float* __restrict__ dt_bias,
                                                     float4* __restrict__ sc4,
                                                     float4* __restrict__ theta4) {
  __shared__ float4 part[16];
  __shared__ float4 part2[16];
  const int bh = blockIdx.x;
  const int b = bh >> 5, h = bh & 31;
  const int l = threadIdx.x;
  const int lane = l & 63, w = l >> 6;
  const float* trow = tailF + (size_t)(b * SEQ + l) * 128;
  float ddt = trow[h];
  float dda = trow[32 + h];
  float trp = trow[64 + h];
  float a = fminf(-softplusf(dda), -1e-4f);
  float dt = softplusf(ddt + dt_bias[h]);
  float adt = a * dt;
  float lam = 1.0f / (1.0f + expf(-trp));
  sc4[(size_t)bh * SEQ + l] = make_float4(dt, expf(adt), lam, adt);
  const float dtv = dt;
#pragma unroll
  for (int kc = 0; kc < 8; ++kc) {
    float4 v = *(const float4*)(trow + 96 + kc * 4);
    v.x *= dtv; v.y *= dtv; v.z *= dtv; v.w *= dtv;
#pragma unroll
    for (int off = 1; off < 64; off <<= 1) {
      float tx = __shfl_up(v.x, off, 64);
      float ty = __shfl_up(v.y, off, 64);
      float tz = __shfl_up(v.z, off, 64);
      float tw = __shfl_up(v.w, off, 64);
      if (lane >= off) { v.x += tx; v.y += ty; v.z += tz; v.w += tw; }
    }
    if (lane == 63) part[w] = v;
    __syncthreads();
    if (l < 16) {
      float4 p = part[l];
#pragma unroll
      for (int off = 1; off < 16; off <<= 1) {
        float tx = __shfl_up(p.x, off, 16);
        float ty = __shfl_up(p.y, off, 16);
        float tz = __shfl_up(p.z, off, 16);
        float tw = __shfl_up(p.w, off, 16);
        if (l >= off) { p.x += tx; p.y += ty; p.z += tz; p.w += tw; }
      }
      part2[l] = p;
    }
    __syncthreads();
    if (w > 0) {
      float4 o = part2[w - 1];
      v.x += o.x; v.y += o.y; v.z += o.z; v.w += o.w;
    }
    theta4[((size_t)(b * SEQ + l) * NHEADS + h) * 8 + kc] = v;
  }
}

// ---------------- RMSNorm + bias + RoPE -> Bh16, Ch16 (bf16) ----------
__global__ __launch_bounds__(128) void rope_kernel(const u16* __restrict__ proj16,
                                                   const float* __restrict__ theta,
                                                   const float* __restrict__ B_bias,
                                                   const float* __restrict__ C_bias,
                                                   const float* __restrict__ Bnw,
                                                   const float* __restrict__ Cnw,
                                                   u16* __restrict__ Bh,
                                                   u16* __restrict__ Ch) {
  const int bl = blockIdx.x;
  const int b = bl >> 10, l = bl & 1023;
  const int n = threadIdx.x;
  __shared__ float sB[128], sC[128], red[4];
  const size_t row = (size_t)bl * DPROJ;
  float bv = bf2f(proj16[row + OFF_B + n]);
  float cv = bf2f(proj16[row + OFF_C + n]);
  float sb = bv * bv, sc = cv * cv;
  for (int m = 32; m; m >>= 1) { sb += __shfl_xor(sb, m); sc += __shfl_xor(sc, m); }
  const int wave = n >> 6;
  if ((n & 63) == 0) { red[wave * 2] = sb; red[wave * 2 + 1] = sc; }
  __syncthreads();
  float rb = rsqrtf((red[0] + red[2]) / 128.0f + 1e-5f);
  float rc = rsqrtf((red[1] + red[3]) / 128.0f + 1e-5f);
  sB[n] = bv * rb * Bnw[n];
  sC[n] = cv * rc * Cnw[n];
  __syncthreads();
  for (int h = 0; h < 32; ++h) {
    float ob, oc;
    const size_t thbase = ((size_t)bl * NHEADS + h) * NUMANG;
    if (n < 64) {
      int k = n & 31;
      float th = theta[thbase + k];
      float cth = cosf(th), sth = sinf(th);
      float b1 = sB[k]      + B_bias[h * 128 + k];
      float b2 = sB[k + 32] + B_bias[h * 128 + k + 32];
      float c1 = sC[k]      + C_bias[h * 128 + k];
      float c2 = sC[k + 32] + C_bias[h * 128 + k + 32];
      if (n < 32) { ob = b1 * cth - b2 * sth; oc = c1 * cth - c2 * sth; }
      else        { ob = b1 * sth + b2 * cth; oc = c1 * sth + c2 * cth; }
    } else {
      ob = sB[n] + B_bias[h * 128 + n];
      oc = sC[n] + C_bias[h * 128 + n];
    }
    size_t o = (((size_t)(b * NHEADS + h)) * SEQ + l) * DSTATE + n;
    Bh[o] = f2bf(ob);
    Ch[o] = f2bf(oc);
  }
}

// ============ chunked scan, phase A: MFMA per-chunk GEMMs ==============
#define SWB 136
#define SWS 72

__global__ __launch_bounds__(256) void chunk_kernel(
    const u16* __restrict__ proj16,
    const float4* __restrict__ sc4,
    const u16* __restrict__ Bh16,
    const u16* __restrict__ Ch16,
    u16* __restrict__ Ybuf,
    float* __restrict__ dHT,
    float* __restrict__ Gv_g,
    float2* __restrict__ de_g) {
  __shared__ u16 sCb[64 * SWB];
  __shared__ u16 sBb[64 * SWB];
  __shared__ u16 sBt[128 * SWS];
  __shared__ u16 sXt[64 * SWS];
  __shared__ u16 sSw[64 * SWS];
  __shared__ float sA[64], sW[64], sDL[64], sCV[64];

  const int blk = blockIdx.x;
  const int bh = blk >> 4, ch = blk & 15;
  const int b = bh >> 5, h = bh & 31;
  const int t0 = ch * CH;
  const int tid = threadIdx.x;
  const int lane = tid & 63, wave = tid >> 6;

  {
    const int row = tid >> 5;
    const int c4 = tid & 31;
#pragma unroll
    for (int pass = 0; pass < 8; ++pass) {
      int ll = pass * 8 + row;
      int l = t0 + ll;
      ushort4 cv = *(const ushort4*)&Ch16[((size_t)bh * SEQ + l) * DSTATE + c4 * 4];
      ushort4 bv = *(const ushort4*)&Bh16[((size_t)bh * SEQ + l) * DSTATE + c4 * 4];
      *(ushort4*)&sCb[ll * SWB + c4 * 4] = cv;
      *(ushort4*)&sBb[ll * SWB + c4 * 4] = bv;
      sBt[(c4 * 4 + 0) * SWS + ll] = bv.x;
      sBt[(c4 * 4 + 1) * SWS + ll] = bv.y;
      sBt[(c4 * 4 + 2) * SWS + ll] = bv.z;
      sBt[(c4 * 4 + 3) * SWS + ll] = bv.w;
    }
    const int xr = tid >> 2, xc = tid & 3;
    const u16* xrow = &proj16[(size_t)(b * SEQ + t0 + xr) * DPROJ + OFF_X + h * 64];
#pragma unroll
    for (int j = 0; j < 4; ++j) {
      ushort4 xv = *(const ushort4*)(xrow + xc * 16 + j * 4);
      int p = xc * 16 + j * 4;
      sXt[(p + 0) * SWS + xr] = xv.x;
      sXt[(p + 1) * SWS + xr] = xv.y;
      sXt[(p + 2) * SWS + xr] = xv.z;
      sXt[(p + 3) * SWS + xr] = xv.w;
    }
  }
  if (tid < 64) {
    float4 s = sc4[(size_t)bh * SEQ + t0 + tid];
    float dt = s.x, lam = s.z, adt = s.w;
    float A = adt;
#pragma unroll
    for (int off = 1; off < 64; off <<= 1) {
      float t = __shfl_up(A, off, 64);
      if (tid >= off) A += t;
    }
    float dtn = __shfl_down(dt, 1, 64);
    float lamn = __shfl_down(lam, 1, 64);
    float dl = dt * lam;
    float w = dl + dtn * (1.0f - lamn);
    if (tid == 63) w = 0.0f;
    float A63 = __shfl(A, 63, 64);
    float cv = (tid < 63) ? expf(A63 - A) * w : dl;
    sA[tid] = A; sW[tid] = w; sCV[tid] = cv; sDL[tid] = dl;
    Gv_g[((size_t)bh * NCH + ch) * 64 + tid] = expf(A);
    if (tid == 0) de_g[(size_t)bh * NCH + ch] = make_float2(expf(A63), dt * (1.0f - lam));
  }
  __syncthreads();

  const int fr = lane & 15, fq = lane >> 4;

  // S^T then masked -> sSw[t][s] bf16
  {
    f32x4 acc[4];
#pragma unroll
    for (int j = 0; j < 4; ++j) acc[j] = (f32x4){0.f, 0.f, 0.f, 0.f};
#pragma unroll
    for (int kc = 0; kc < 4; ++kc) {
      bf16x8 af = *(const bf16x8*)&sBb[(wave * 16 + fr) * SWB + kc * 32 + fq * 8];
#pragma unroll
      for (int j = 0; j < 4; ++j) {
        bf16x8 bf = *(const bf16x8*)&sCb[(j * 16 + fr) * SWB + kc * 32 + fq * 8];
        acc[j] = __builtin_amdgcn_mfma_f32_16x16x32_bf16(af, bf, acc[j], 0, 0, 0);
      }
    }
    const int sbase = wave * 16 + fq * 4;
#pragma unroll
    for (int j = 0; j < 4; ++j) {
      int t = j * 16 + fr;
      float At = sA[t], dlt = sDL[t];
#pragma unroll
      for (int r = 0; r < 4; ++r) {
        int ss = sbase + r;
        float f = (ss < t) ? expf(At - sA[ss]) * sW[ss] : ((ss == t) ? dlt : 0.0f);
        sSw[t * SWS + ss] = f2bf(acc[j][r] * f);
      }
    }
  }
  __syncthreads();

  // Y1 = Sw @ X -> Ybuf (bf16)
  {
    f32x4 acc[4];
#pragma unroll
    for (int j = 0; j < 4; ++j) acc[j] = (f32x4){0.f, 0.f, 0.f, 0.f};
#pragma unroll
    for (int kc = 0; kc < 2; ++kc) {
      bf16x8 af = *(const bf16x8*)&sSw[(wave * 16 + fr) * SWS + kc * 32 + fq * 8];
#pragma unroll
      for (int j = 0; j < 4; ++j) {
        bf16x8 bf = *(const bf16x8*)&sXt[(j * 16 + fr) * SWS + kc * 32 + fq * 8];
        acc[j] = __builtin_amdgcn_mfma_f32_16x16x32_bf16(af, bf, acc[j], 0, 0, 0);
      }
    }
    const int tr = t0 + wave * 16 + fq * 4;
#pragma unroll
    for (int j = 0; j < 4; ++j) {
      int p = j * 16 + fr;
#pragma unroll
      for (int r = 0; r < 4; ++r)
        Ybuf[(size_t)(b * SEQ + tr + r) * DINNER + h * 64 + p] = f2bf(acc[j][r]);
    }
  }
  __syncthreads();

  // scale Xt columns by cv[s]
  {
    const int p = tid >> 2;
    const int s0 = (tid & 3) * 16;
#pragma unroll
    for (int k = 0; k < 16; ++k) {
      int s = s0 + k;
      sXt[p * SWS + s] = f2bf(bf2f(sXt[p * SWS + s]) * sCV[s]);
    }
  }
  __syncthreads();

  // dHT = Bt @ cvX
  {
#pragma unroll
    for (int mi = 0; mi < 2; ++mi) {
      f32x4 acc[4];
#pragma unroll
      for (int j = 0; j < 4; ++j) acc[j] = (f32x4){0.f, 0.f, 0.f, 0.f};
      const int nrow = wave * 32 + mi * 16;
#pragma unroll
      for (int kc = 0; kc < 2; ++kc) {
        bf16x8 af = *(const bf16x8*)&sBt[(nrow + fr) * SWS + kc * 32 + fq * 8];
#pragma unroll
        for (int j = 0; j < 4; ++j) {
          bf16x8 bf = *(const bf16x8*)&sXt[(j * 16 + fr) * SWS + kc * 32 + fq * 8];
          acc[j] = __builtin_amdgcn_mfma_f32_16x16x32_bf16(af, bf, acc[j], 0, 0, 0);
        }
      }
      const int nr = nrow + fq * 4;
#pragma unroll
      for (int j = 0; j < 4; ++j) {
        int p = j * 16 + fr;
#pragma unroll
        for (int r = 0; r < 4; ++r)
          dHT[(((size_t)bh * NCH + ch) * 128 + nr + r) * 64 + p] = acc[j][r];
      }
    }
  }
}

// ============ phase B: sequential 16-chunk state carry ==========
__global__ __launch_bounds__(512) void carry_kernel(
    const u16* __restrict__ proj16,
    const u16* __restrict__ Bh16,
    const float* __restrict__ dHT,
    const float2* __restrict__ de_g,
    float* __restrict__ Heff) {
  const int bh = blockIdx.x;
  const int b = bh >> 5, h = bh & 31;
  const int tid = threadIdx.x;
  const int n = tid >> 2;
  const int p0 = (tid & 3) * 16;
  float hreg[16] = {};
  for (int c = 0; c < NCH; ++c) {
    float2 de = de_g[bh * NCH + c];
    float heff[16];
    if (c == 0) {
#pragma unroll
      for (int j = 0; j < 16; ++j) heff[j] = 0.0f;
    } else {
      int lprev = c * CH - 1;
      float Bp = bf2f(Bh16[((size_t)bh * SEQ + lprev) * DSTATE + n]);
      const u16* xp = &proj16[(size_t)(b * SEQ + lprev) * DPROJ + OFF_X + h * 64 + p0];
      float eB = de.y * Bp;
#pragma unroll
      for (int j4 = 0; j4 < 4; ++j4) {
        ushort4 xv = *(const ushort4*)(xp + j4 * 4);
        heff[j4 * 4 + 0] = hreg[j4 * 4 + 0] + eB * bf2f(xv.x);
        heff[j4 * 4 + 1] = hreg[j4 * 4 + 1] + eB * bf2f(xv.y);
        heff[j4 * 4 + 2] = hreg[j4 * 4 + 2] + eB * bf2f(xv.z);
        heff[j4 * 4 + 3] = hreg[j4 * 4 + 3] + eB * bf2f(xv.w);
      }
    }
    size_t base = (((size_t)bh * NCH + c) * 128 + n) * 64 + p0;
#pragma unroll
    for (int j4 = 0; j4 < 4; ++j4)
      *(float4*)&Heff[base + j4 * 4] = *(const float4*)&heff[j4 * 4];
#pragma unroll
    for (int j4 = 0; j4 < 4; ++j4) {
      float4 dh = *(const float4*)&dHT[base + j4 * 4];
      hreg[j4 * 4 + 0] = de.x * heff[j4 * 4 + 0] + dh.x;
      hreg[j4 * 4 + 1] = de.x * heff[j4 * 4 + 1] + dh.y;
      hreg[j4 * 4 + 2] = de.x * heff[j4 * 4 + 2] + dh.z;
      hreg[j4 * 4 + 3] = de.x * heff[j4 * 4 + 3] + dh.w;
    }
  }
}

// ============ phase C: Y = gate(Y1 + G*(C@Heff) + D*x) -> bf16 in place ====
__global__ __launch_bounds__(256) void inter_kernel(
    const u16* __restrict__ proj16,
    const u16* __restrict__ Ch16,
    const float* __restrict__ Heff,
    const float* __restrict__ Gv_g,
    const float* __restrict__ Dp,
    u16* __restrict__ Ybuf) {
  __shared__ float sC[64][132];
  __shared__ float sH[128][68];
  __shared__ float sGv[64];
  const int blk = blockIdx.x;
  const int bh = blk >> 4, ch = blk & 15;
  const int b = bh >> 5, h = bh & 31;
  const int t0 = ch * CH;
  const int tid = threadIdx.x;
  {
    const int row = tid >> 5, c4 = tid & 31;
#pragma unroll
    for (int pass = 0; pass < 8; ++pass) {
      int l = t0 + pass * 8 + row;
      ushort4 cv = *(const ushort4*)&Ch16[((size_t)bh * SEQ + l) * DSTATE + c4 * 4];
      float4 cf = {bf2f(cv.x), bf2f(cv.y), bf2f(cv.z), bf2f(cv.w)};
      *(float4*)&sC[pass * 8 + row][c4 * 4] = cf;
    }
    const int hr = tid >> 4, hc = tid & 15;
#pragma unroll
    for (int pass = 0; pass < 8; ++pass) {
      int n = pass * 16 + hr;
      float4 hv = *(const float4*)&Heff[(((size_t)bh * NCH + ch) * 128 + n) * 64 + hc * 4];
      *(float4*)&sH[n][hc * 4] = hv;
    }
    if (tid < 64) sGv[tid] = Gv_g[((size_t)bh * NCH + ch) * 64 + tid];
  }
  __syncthreads();
  const int ty = tid >> 4, tx = tid & 15;
  float acc[4][4] = {};
  for (int n = 0; n < 128; n += 4) {
    float4 cv[4], hv[4];
#pragma unroll
    for (int i = 0; i < 4; ++i) cv[i] = *(const float4*)&sC[ty * 4 + i][n];
#pragma unroll
    for (int k = 0; k < 4; ++k) hv[k] = *(const float4*)&sH[n + k][tx * 4];
#pragma unroll
    for (int k = 0; k < 4; ++k) {
      const float* hp = (const float*)&hv[k];
#pragma unroll
      for (int i = 0; i < 4; ++i) {
        float cva = ((const float*)&cv[i])[k];
#pragma unroll
        for (int j = 0; j < 4; ++j)
          acc[i][j] = fmaf(cva, hp[j], acc[i][j]);
      }
    }
  }
  const float Dv = Dp[h];
#pragma unroll
  for (int i = 0; i < 4; ++i) {
    int l = t0 + ty * 4 + i;
    float gt = sGv[ty * 4 + i];
    size_t rowp = (size_t)(b * SEQ + l) * DPROJ;
    ushort4 xv = *(const ushort4*)&proj16[rowp + OFF_X + h * 64 + tx * 4];
    ushort4 zv = *(const ushort4*)&proj16[rowp + OFF_Z + h * 64 + tx * 4];
    size_t yo = (size_t)(b * SEQ + l) * DINNER + h * 64 + tx * 4;
    ushort4 y1 = *(const ushort4*)&Ybuf[yo];
    float x[4] = {bf2f(xv.x), bf2f(xv.y), bf2f(xv.z), bf2f(xv.w)};
    float z[4] = {bf2f(zv.x), bf2f(zv.y), bf2f(zv.z), bf2f(zv.w)};
    float y[4] = {bf2f(y1.x), bf2f(y1.y), bf2f(y1.z), bf2f(y1.w)};
    ushort4 o;
    u16* op = (u16*)&o;
#pragma unroll
    for (int j = 0; j < 4; ++j) {
      float yy = y[j] + gt * acc[i][j] + Dv * x[j];
      float sg = 1.0f / (1.0f + expf(-z[j]));
      op[j] = f2bf(yy * z[j] * sg);
    }
    *(ushort4*)&Ybuf[yo] = o;
  }
}

extern "C" void kernel_launch(void* const* d_in, const int* in_sizes, int n_in,
                              void* d_out, int out_size, void* d_ws, size_t ws_size,
                              hipStream_t stream) {
  const float* u       = (const float*)d_in[0];
  const float* W_in    = (const float*)d_in[1];
  const float* W_out   = (const float*)d_in[2];
  const float* dt_bias = (const float*)d_in[3];
  const float* B_bias  = (const float*)d_in[4];
  const float* C_bias  = (const float*)d_in[5];
  const float* Bnw     = (const float*)d_in[6];
  const float* Cnw     = (const float*)d_in[7];
  const float* Dp      = (const float*)d_in[8];
  float* out = (float*)d_out;

  char* ws = (char*)d_ws;
  u16*    proj16 = (u16*)(ws);                      // 18,350,080
  float*  tailF  = (float*)(ws + 18350080);         //  1,048,576
  float4* sc4    = (float4*)(ws + 19398656);        //  1,048,576
  float*  theta  = (float*)(ws + 20447232);         //  8,388,608
  u16*    Bh16   = (u16*)(ws + 28835840);           // 16,777,216
  u16*    Ch16   = (u16*)(ws + 45613056);           // 16,777,216
  u16*    Ybuf   = (u16*)(ws + 62390272);           //  8,388,608
  float*  dHT    = (float*)(ws + 70778880);         // 33,554,432
  float*  Heff   = (float*)(ws + 104333312);        // 33,554,432
  float*  Gv     = (float*)(ws + 137887744);        //    262,144
  float2* deg    = (float2*)(ws + 138149888);       //      8,192
  u16*    ub16   = (u16*)(ws + 138158080);          //  4,194,304
  u16*    Wi16   = (u16*)(ws + 142352384);          //  9,175,040
  u16*    Wo16   = (u16*)(ws + 151527424);          //  4,194,304

  cvt_bf16<<<2048, 256, 0, stream>>>(u, ub16, 524288);
  cvt_bf16<<<4480, 256, 0, stream>>>(W_in, Wi16, 1146880);
  gemm_proj64<<<dim3(DPROJ / 64, (BATCH * SEQ) / 64), 256, 0, stream>>>(
      ub16, Wi16, proj16, tailF, BATCH * SEQ, DPROJ, DMODEL);
  theta_kernel<<<BATCH * NHEADS, 1024, 0, stream>>>(tailF, dt_bias, sc4, (float4*)theta);
  rope_kernel<<<BATCH * SEQ, 128, 0, stream>>>(proj16, theta, B_bias, C_bias, Bnw, Cnw, Bh16, Ch16);
  chunk_kernel<<<BATCH * NHEADS * NCH, 256, 0, stream>>>(
      proj16, sc4, Bh16, Ch16, Ybuf, dHT, Gv, deg);
  carry_kernel<<<BATCH * NHEADS, 512, 0, stream>>>(proj16, Bh16, dHT, deg, Heff);
  inter_kernel<<<BATCH * NHEADS * NCH, 256, 0, stream>>>(
      proj16, Ch16, Heff, Gv, Dp, Ybuf);
  cvt_bf16<<<2048, 256, 0, stream>>>(W_out, Wo16, 524288);
  gemm_out64<<<dim3(DMODEL / 64, (BATCH * SEQ) / 64), 256, 0, stream>>>(
      Ybuf, Wo16, out, BATCH * SEQ, DMODEL, DINNER);
}

// Round 8
// 270.756 us; speedup vs baseline: 9.0594x; 1.0799x over previous
//
#include <hip/hip_runtime.h>
#include <hip/hip_bf16.h>
#include <math.h>

#define BATCH 2
#define SEQ 1024
#define DMODEL 1024
#define DSTATE 128
#define HEADDIM 64
#define NHEADS 32
#define DINNER 2048
#define NUMANG 32
#define DPROJ 4480
#define CH 64
#define NCH 16
#define TAILSTART 4352
// proj row offsets (elements)
#define OFF_Z 0
#define OFF_X 2048
#define OFF_B 4096
#define OFF_C 4224
#define OFF_DT 4352
#define OFF_A 4384
#define OFF_TRAP 4416
#define OFF_ANG 4448

typedef __attribute__((ext_vector_type(8))) short bf16x8;
typedef __attribute__((ext_vector_type(4))) float f32x4;
typedef unsigned short u16;

__device__ __forceinline__ u16 f2bf(float f) {
  unsigned int u = __float_as_uint(f);
  u += 0x7FFFu + ((u >> 16) & 1u);
  return (u16)(u >> 16);
}
__device__ __forceinline__ float bf2f(u16 x) {
  return __uint_as_float(((unsigned int)x) << 16);
}

__global__ __launch_bounds__(256) void cvt_bf16(const float* __restrict__ in,
                                                u16* __restrict__ out, int n4) {
  int i = blockIdx.x * 256 + threadIdx.x;
  if (i >= n4) return;
  float4 v = ((const float4*)in)[i];
  ushort4 o;
  o.x = f2bf(v.x); o.y = f2bf(v.y); o.z = f2bf(v.z); o.w = f2bf(v.w);
  ((ushort4*)out)[i] = o;
}

__device__ __forceinline__ void gload_lds16(const void* g, void* l) {
  __builtin_amdgcn_global_load_lds(
      (const __attribute__((address_space(1))) unsigned int*)g,
      (__attribute__((address_space(3))) unsigned int*)l, 16, 0, 0);
}

// ============ 64x64-tile bf16 MFMA GEMM, C = A @ B^T ============
__global__ __launch_bounds__(256) void gemm_proj64(const u16* __restrict__ A,
                                                   const u16* __restrict__ B,
                                                   u16* __restrict__ Cb,
                                                   float* __restrict__ tailF,
                                                   int M, int N, int K) {
  __shared__ u16 As[64 * 64];
  __shared__ u16 Bs[64 * 64];
  const int tid = threadIdx.x;
  const int lane = tid & 63, wave = tid >> 6;
  const int bm = blockIdx.y * 64, bn = blockIdx.x * 64;
  const int wm = (wave >> 1) * 32, wn = (wave & 1) * 32;
  const int srow = wave * 8 + (lane >> 3);
  const int scol = (((lane & 7) ^ ((lane >> 3) & 7)) * 8);
  const u16* Ab = A + (size_t)(bm + srow) * K + scol;
  const u16* Bb = B + (size_t)(bn + srow) * K + scol;
  u16* Asw = As + wave * 512;
  u16* Bsw = Bs + wave * 512;
  f32x4 acc[2][2];
#pragma unroll
  for (int i = 0; i < 2; ++i)
#pragma unroll
    for (int j = 0; j < 2; ++j) acc[i][j] = (f32x4){0.f, 0.f, 0.f, 0.f};
  const int fr = lane & 15, fq = lane >> 4, sw = fr & 7;

  for (int k0 = 0; k0 < K; k0 += 64) {
    __syncthreads();
#pragma unroll
    for (int it = 0; it < 2; ++it) {
      gload_lds16(Ab + (size_t)(it * 32) * K + k0, Asw + it * 2048);
      gload_lds16(Bb + (size_t)(it * 32) * K + k0, Bsw + it * 2048);
    }
    __syncthreads();
#pragma unroll
    for (int kh = 0; kh < 2; ++kh) {
      bf16x8 af[2], bfv[2];
#pragma unroll
      for (int i = 0; i < 2; ++i)
        af[i] = *(const bf16x8*)(As + (wm + i * 16 + fr) * 64 + (((kh * 4 + fq) ^ sw) * 8));
#pragma unroll
      for (int j = 0; j < 2; ++j)
        bfv[j] = *(const bf16x8*)(Bs + (wn + j * 16 + fr) * 64 + (((kh * 4 + fq) ^ sw) * 8));
#pragma unroll
      for (int i = 0; i < 2; ++i)
#pragma unroll
        for (int j = 0; j < 2; ++j)
          acc[i][j] = __builtin_amdgcn_mfma_f32_16x16x32_bf16(af[i], bfv[j], acc[i][j], 0, 0, 0);
    }
  }
  const int orow = bm + wm + fq * 4;
  const int ocol = bn + wn + fr;
  const bool tail = (bn >= TAILSTART);
#pragma unroll
  for (int i = 0; i < 2; ++i)
#pragma unroll
    for (int j = 0; j < 2; ++j)
#pragma unroll
      for (int r = 0; r < 4; ++r) {
        float v = acc[i][j][r];
        int row = orow + i * 16 + r, col = ocol + j * 16;
        Cb[(size_t)row * N + col] = f2bf(v);
        if (tail) tailF[(size_t)row * 128 + (col - TAILSTART)] = v;
      }
}

__global__ __launch_bounds__(256) void gemm_out64(const u16* __restrict__ A,
                                                  const u16* __restrict__ B,
                                                  float* __restrict__ C,
                                                  int M, int N, int K) {
  __shared__ u16 As[64 * 64];
  __shared__ u16 Bs[64 * 64];
  const int tid = threadIdx.x;
  const int lane = tid & 63, wave = tid >> 6;
  const int bm = blockIdx.y * 64, bn = blockIdx.x * 64;
  const int wm = (wave >> 1) * 32, wn = (wave & 1) * 32;
  const int srow = wave * 8 + (lane >> 3);
  const int scol = (((lane & 7) ^ ((lane >> 3) & 7)) * 8);
  const u16* Ab = A + (size_t)(bm + srow) * K + scol;
  const u16* Bb = B + (size_t)(bn + srow) * K + scol;
  u16* Asw = As + wave * 512;
  u16* Bsw = Bs + wave * 512;
  f32x4 acc[2][2];
#pragma unroll
  for (int i = 0; i < 2; ++i)
#pragma unroll
    for (int j = 0; j < 2; ++j) acc[i][j] = (f32x4){0.f, 0.f, 0.f, 0.f};
  const int fr = lane & 15, fq = lane >> 4, sw = fr & 7;

  for (int k0 = 0; k0 < K; k0 += 64) {
    __syncthreads();
#pragma unroll
    for (int it = 0; it < 2; ++it) {
      gload_lds16(Ab + (size_t)(it * 32) * K + k0, Asw + it * 2048);
      gload_lds16(Bb + (size_t)(it * 32) * K + k0, Bsw + it * 2048);
    }
    __syncthreads();
#pragma unroll
    for (int kh = 0; kh < 2; ++kh) {
      bf16x8 af[2], bfv[2];
#pragma unroll
      for (int i = 0; i < 2; ++i)
        af[i] = *(const bf16x8*)(As + (wm + i * 16 + fr) * 64 + (((kh * 4 + fq) ^ sw) * 8));
#pragma unroll
      for (int j = 0; j < 2; ++j)
        bfv[j] = *(const bf16x8*)(Bs + (wn + j * 16 + fr) * 64 + (((kh * 4 + fq) ^ sw) * 8));
#pragma unroll
      for (int i = 0; i < 2; ++i)
#pragma unroll
        for (int j = 0; j < 2; ++j)
          acc[i][j] = __builtin_amdgcn_mfma_f32_16x16x32_bf16(af[i], bfv[j], acc[i][j], 0, 0, 0);
    }
  }
  const int orow = bm + wm + fq * 4;
  const int ocol = bn + wn + fr;
#pragma unroll
  for (int i = 0; i < 2; ++i)
#pragma unroll
    for (int j = 0; j < 2; ++j)
#pragma unroll
      for (int r = 0; r < 4; ++r)
        C[(size_t)(orow + i * 16 + r) * N + ocol + j * 16] = acc[i][j][r];
}

// ---------------- scalars + theta cumsum, per (b,h,kc): 512 blocks ---------
__device__ __forceinline__ float softplusf(float x) {
  return fmaxf(x, 0.f) + log1pf(expf(-fabsf(x)));
}

__global__ __launch_bounds__(1024) void theta_kernel(const float* __restrict__ tailF,
                                                     const float* __restrict__ dt_bias,
                                                     float4* __restrict__ sc4,
                                                     float4* __restrict__ theta4) {
  __shared__ float4 part[16];
  __shared__ float4 part2[16];
  const int blk = blockIdx.x;
  const int bh = blk >> 3, kc = blk & 7;
  const int b = bh >> 5, h = bh & 31;
  const int l = threadIdx.x;
  const int lane = l & 63, w = l >> 6;
  const float* trow = tailF + (size_t)(b * SEQ + l) * 128;
  float ddt = trow[h];
  float dt = softplusf(ddt + dt_bias[h]);
  if (kc == 0) {
    float dda = trow[32 + h];
    float trp = trow[64 + h];
    float a = fminf(-softplusf(dda), -1e-4f);
    float adt = a * dt;
    float lam = 1.0f / (1.0f + expf(-trp));
    sc4[(size_t)bh * SEQ + l] = make_float4(dt, expf(adt), lam, adt);
  }
  float4 v = *(const float4*)(trow + 96 + kc * 4);
  v.x *= dt; v.y *= dt; v.z *= dt; v.w *= dt;
#pragma unroll
  for (int off = 1; off < 64; off <<= 1) {
    float tx = __shfl_up(v.x, off, 64);
    float ty = __shfl_up(v.y, off, 64);
    float tz = __shfl_up(v.z, off, 64);
    float tw = __shfl_up(v.w, off, 64);
    if (lane >= off) { v.x += tx; v.y += ty; v.z += tz; v.w += tw; }
  }
  if (lane == 63) part[w] = v;
  __syncthreads();
  if (l < 16) {
    float4 p = part[l];
#pragma unroll
    for (int off = 1; off < 16; off <<= 1) {
      float tx = __shfl_up(p.x, off, 16);
      float ty = __shfl_up(p.y, off, 16);
      float tz = __shfl_up(p.z, off, 16);
      float tw = __shfl_up(p.w, off, 16);
      if (l >= off) { p.x += tx; p.y += ty; p.z += tz; p.w += tw; }
    }
    part2[l] = p;
  }
  __syncthreads();
  if (w > 0) {
    float4 o = part2[w - 1];
    v.x += o.x; v.y += o.y; v.z += o.z; v.w += o.w;
  }
  theta4[((size_t)(b * SEQ + l) * NHEADS + h) * 8 + kc] = v;
}

// ------- RMSNorm + bias + RoPE, fully parallel over (h,n): 1024 thr -------
__global__ __launch_bounds__(1024) void rope_kernel(const u16* __restrict__ proj16,
                                                    const float* __restrict__ theta,
                                                    const float* __restrict__ B_bias,
                                                    const float* __restrict__ C_bias,
                                                    const float* __restrict__ Bnw,
                                                    const float* __restrict__ Cnw,
                                                    u16* __restrict__ Bh,
                                                    u16* __restrict__ Ch) {
  const int bl = blockIdx.x;
  const int b = bl >> 10, l = bl & 1023;
  const int tid = threadIdx.x;
  __shared__ float sB[128], sC[128], red[4];
  __shared__ float cth[1024], sth[1024];  // [h*32+k]
  float bv = 0.f, cv = 0.f;
  const size_t row = (size_t)bl * DPROJ;
  if (tid < 128) {
    bv = bf2f(proj16[row + OFF_B + tid]);
    cv = bf2f(proj16[row + OFF_C + tid]);
    float sb = bv * bv, sc = cv * cv;
    for (int m = 32; m; m >>= 1) { sb += __shfl_xor(sb, m); sc += __shfl_xor(sc, m); }
    const int wave = tid >> 6;
    if ((tid & 63) == 0) { red[wave * 2] = sb; red[wave * 2 + 1] = sc; }
  }
  // all threads: one cos/sin each for (h,k)
  {
    float th = theta[(size_t)bl * 1024 + tid];
    cth[tid] = cosf(th);
    sth[tid] = sinf(th);
  }
  __syncthreads();
  if (tid < 128) {
    float rb = rsqrtf((red[0] + red[2]) / 128.0f + 1e-5f);
    float rc = rsqrtf((red[1] + red[3]) / 128.0f + 1e-5f);
    sB[tid] = bv * rb * Bnw[tid];
    sC[tid] = cv * rc * Cnw[tid];
  }
  __syncthreads();
  const int h = tid >> 5;
  const int n0 = (tid & 31) * 4;
  float ob[4], oc[4];
  if (n0 < 32) {
#pragma unroll
    for (int j = 0; j < 4; ++j) {
      int n = n0 + j;
      float c = cth[h * 32 + n], s = sth[h * 32 + n];
      float b1 = sB[n] + B_bias[h * 128 + n];
      float b2 = sB[n + 32] + B_bias[h * 128 + n + 32];
      float c1 = sC[n] + C_bias[h * 128 + n];
      float c2 = sC[n + 32] + C_bias[h * 128 + n + 32];
      ob[j] = b1 * c - b2 * s;
      oc[j] = c1 * c - c2 * s;
    }
  } else if (n0 < 64) {
#pragma unroll
    for (int j = 0; j < 4; ++j) {
      int n = n0 + j, k = n - 32;
      float c = cth[h * 32 + k], s = sth[h * 32 + k];
      float b1 = sB[k] + B_bias[h * 128 + k];
      float b2 = sB[k + 32] + B_bias[h * 128 + k + 32];
      float c1 = sC[k] + C_bias[h * 128 + k];
      float c2 = sC[k + 32] + C_bias[h * 128 + k + 32];
      ob[j] = b1 * s + b2 * c;
      oc[j] = c1 * s + c2 * c;
    }
  } else {
#pragma unroll
    for (int j = 0; j < 4; ++j) {
      int n = n0 + j;
      ob[j] = sB[n] + B_bias[h * 128 + n];
      oc[j] = sC[n] + C_bias[h * 128 + n];
    }
  }
  size_t o = (((size_t)(b * NHEADS + h)) * SEQ + l) * DSTATE + n0;
  ushort4 vb = {f2bf(ob[0]), f2bf(ob[1]), f2bf(ob[2]), f2bf(ob[3])};
  ushort4 vc = {f2bf(oc[0]), f2bf(oc[1]), f2bf(oc[2]), f2bf(oc[3])};
  *(ushort4*)&Bh[o] = vb;
  *(ushort4*)&Ch[o] = vc;
}

// ============ chunked scan, phase A: MFMA per-chunk GEMMs ==============
#define SWB 136
#define SWS 72

__global__ __launch_bounds__(256) void chunk_kernel(
    const u16* __restrict__ proj16,
    const float4* __restrict__ sc4,
    const u16* __restrict__ Bh16,
    const u16* __restrict__ Ch16,
    u16* __restrict__ Ybuf,
    float* __restrict__ dHT,
    float* __restrict__ Gv_g,
    float2* __restrict__ de_g) {
  __shared__ u16 sCb[64 * SWB];
  __shared__ u16 sBb[64 * SWB];
  __shared__ u16 sBt[128 * SWS];
  __shared__ u16 sXt[64 * SWS];
  __shared__ u16 sSw[64 * SWS];
  __shared__ float sA[64], sW[64], sDL[64], sCV[64];

  const int blk = blockIdx.x;
  const int bh = blk >> 4, ch = blk & 15;
  const int b = bh >> 5, h = bh & 31;
  const int t0 = ch * CH;
  const int tid = threadIdx.x;
  const int lane = tid & 63, wave = tid >> 6;

  {
    const int row = tid >> 5;
    const int c4 = tid & 31;
#pragma unroll
    for (int pass = 0; pass < 8; ++pass) {
      int ll = pass * 8 + row;
      int l = t0 + ll;
      ushort4 cv = *(const ushort4*)&Ch16[((size_t)bh * SEQ + l) * DSTATE + c4 * 4];
      ushort4 bv = *(const ushort4*)&Bh16[((size_t)bh * SEQ + l) * DSTATE + c4 * 4];
      *(ushort4*)&sCb[ll * SWB + c4 * 4] = cv;
      *(ushort4*)&sBb[ll * SWB + c4 * 4] = bv;
      sBt[(c4 * 4 + 0) * SWS + ll] = bv.x;
      sBt[(c4 * 4 + 1) * SWS + ll] = bv.y;
      sBt[(c4 * 4 + 2) * SWS + ll] = bv.z;
      sBt[(c4 * 4 + 3) * SWS + ll] = bv.w;
    }
    const int xr = tid >> 2, xc = tid & 3;
    const u16* xrow = &proj16[(size_t)(b * SEQ + t0 + xr) * DPROJ + OFF_X + h * 64];
#pragma unroll
    for (int j = 0; j < 4; ++j) {
      ushort4 xv = *(const ushort4*)(xrow + xc * 16 + j * 4);
      int p = xc * 16 + j * 4;
      sXt[(p + 0) * SWS + xr] = xv.x;
      sXt[(p + 1) * SWS + xr] = xv.y;
      sXt[(p + 2) * SWS + xr] = xv.z;
      sXt[(p + 3) * SWS + xr] = xv.w;
    }
  }
  if (tid < 64) {
    float4 s = sc4[(size_t)bh * SEQ + t0 + tid];
    float dt = s.x, lam = s.z, adt = s.w;
    float A = adt;
#pragma unroll
    for (int off = 1; off < 64; off <<= 1) {
      float t = __shfl_up(A, off, 64);
      if (tid >= off) A += t;
    }
    float dtn = __shfl_down(dt, 1, 64);
    float lamn = __shfl_down(lam, 1, 64);
    float dl = dt * lam;
    float w = dl + dtn * (1.0f - lamn);
    if (tid == 63) w = 0.0f;
    float A63 = __shfl(A, 63, 64);
    float cv = (tid < 63) ? expf(A63 - A) * w : dl;
    sA[tid] = A; sW[tid] = w; sCV[tid] = cv; sDL[tid] = dl;
    Gv_g[((size_t)bh * NCH + ch) * 64 + tid] = expf(A);
    if (tid == 0) de_g[(size_t)bh * NCH + ch] = make_float2(expf(A63), dt * (1.0f - lam));
  }
  __syncthreads();

  const int fr = lane & 15, fq = lane >> 4;

  {
    f32x4 acc[4];
#pragma unroll
    for (int j = 0; j < 4; ++j) acc[j] = (f32x4){0.f, 0.f, 0.f, 0.f};
#pragma unroll
    for (int kc = 0; kc < 4; ++kc) {
      bf16x8 af = *(const bf16x8*)&sBb[(wave * 16 + fr) * SWB + kc * 32 + fq * 8];
#pragma unroll
      for (int j = 0; j < 4; ++j) {
        bf16x8 bf = *(const bf16x8*)&sCb[(j * 16 + fr) * SWB + kc * 32 + fq * 8];
        acc[j] = __builtin_amdgcn_mfma_f32_16x16x32_bf16(af, bf, acc[j], 0, 0, 0);
      }
    }
    const int sbase = wave * 16 + fq * 4;
#pragma unroll
    for (int j = 0; j < 4; ++j) {
      int t = j * 16 + fr;
      float At = sA[t], dlt = sDL[t];
#pragma unroll
      for (int r = 0; r < 4; ++r) {
        int ss = sbase + r;
        float f = (ss < t) ? expf(At - sA[ss]) * sW[ss] : ((ss == t) ? dlt : 0.0f);
        sSw[t * SWS + ss] = f2bf(acc[j][r] * f);
      }
    }
  }
  __syncthreads();

  {
    f32x4 acc[4];
#pragma unroll
    for (int j = 0; j < 4; ++j) acc[j] = (f32x4){0.f, 0.f, 0.f, 0.f};
#pragma unroll
    for (int kc = 0; kc < 2; ++kc) {
      bf16x8 af = *(const bf16x8*)&sSw[(wave * 16 + fr) * SWS + kc * 32 + fq * 8];
#pragma unroll
      for (int j = 0; j < 4; ++j) {
        bf16x8 bf = *(const bf16x8*)&sXt[(j * 16 + fr) * SWS + kc * 32 + fq * 8];
        acc[j] = __builtin_amdgcn_mfma_f32_16x16x32_bf16(af, bf, acc[j], 0, 0, 0);
      }
    }
    const int tr = t0 + wave * 16 + fq * 4;
#pragma unroll
    for (int j = 0; j < 4; ++j) {
      int p = j * 16 + fr;
#pragma unroll
      for (int r = 0; r < 4; ++r)
        Ybuf[(size_t)(b * SEQ + tr + r) * DINNER + h * 64 + p] = f2bf(acc[j][r]);
    }
  }
  __syncthreads();

  {
    const int p = tid >> 2;
    const int s0 = (tid & 3) * 16;
#pragma unroll
    for (int k = 0; k < 16; ++k) {
      int s = s0 + k;
      sXt[p * SWS + s] = f2bf(bf2f(sXt[p * SWS + s]) * sCV[s]);
    }
  }
  __syncthreads();

  {
#pragma unroll
    for (int mi = 0; mi < 2; ++mi) {
      f32x4 acc[4];
#pragma unroll
      for (int j = 0; j < 4; ++j) acc[j] = (f32x4){0.f, 0.f, 0.f, 0.f};
      const int nrow = wave * 32 + mi * 16;
#pragma unroll
      for (int kc = 0; kc < 2; ++kc) {
        bf16x8 af = *(const bf16x8*)&sBt[(nrow + fr) * SWS + kc * 32 + fq * 8];
#pragma unroll
        for (int j = 0; j < 4; ++j) {
          bf16x8 bf = *(const bf16x8*)&sXt[(j * 16 + fr) * SWS + kc * 32 + fq * 8];
          acc[j] = __builtin_amdgcn_mfma_f32_16x16x32_bf16(af, bf, acc[j], 0, 0, 0);
        }
      }
      const int nr = nrow + fq * 4;
#pragma unroll
      for (int j = 0; j < 4; ++j) {
        int p = j * 16 + fr;
#pragma unroll
        for (int r = 0; r < 4; ++r)
          dHT[(((size_t)bh * NCH + ch) * 128 + nr + r) * 64 + p] = acc[j][r];
      }
    }
  }
}

// ============ phase B: sequential 16-chunk state carry ==========
__global__ __launch_bounds__(512) void carry_kernel(
    const u16* __restrict__ proj16,
    const u16* __restrict__ Bh16,
    const float* __restrict__ dHT,
    const float2* __restrict__ de_g,
    float* __restrict__ Heff) {
  const int bh = blockIdx.x;
  const int b = bh >> 5, h = bh & 31;
  const int tid = threadIdx.x;
  const int n = tid >> 2;
  const int p0 = (tid & 3) * 16;
  float hreg[16] = {};
  for (int c = 0; c < NCH; ++c) {
    float2 de = de_g[bh * NCH + c];
    float heff[16];
    if (c == 0) {
#pragma unroll
      for (int j = 0; j < 16; ++j) heff[j] = 0.0f;
    } else {
      int lprev = c * CH - 1;
      float Bp = bf2f(Bh16[((size_t)bh * SEQ + lprev) * DSTATE + n]);
      const u16* xp = &proj16[(size_t)(b * SEQ + lprev) * DPROJ + OFF_X + h * 64 + p0];
      float eB = de.y * Bp;
#pragma unroll
      for (int j4 = 0; j4 < 4; ++j4) {
        ushort4 xv = *(const ushort4*)(xp + j4 * 4);
        heff[j4 * 4 + 0] = hreg[j4 * 4 + 0] + eB * bf2f(xv.x);
        heff[j4 * 4 + 1] = hreg[j4 * 4 + 1] + eB * bf2f(xv.y);
        heff[j4 * 4 + 2] = hreg[j4 * 4 + 2] + eB * bf2f(xv.z);
        heff[j4 * 4 + 3] = hreg[j4 * 4 + 3] + eB * bf2f(xv.w);
      }
    }
    size_t base = (((size_t)bh * NCH + c) * 128 + n) * 64 + p0;
#pragma unroll
    for (int j4 = 0; j4 < 4; ++j4)
      *(float4*)&Heff[base + j4 * 4] = *(const float4*)&heff[j4 * 4];
#pragma unroll
    for (int j4 = 0; j4 < 4; ++j4) {
      float4 dh = *(const float4*)&dHT[base + j4 * 4];
      hreg[j4 * 4 + 0] = de.x * heff[j4 * 4 + 0] + dh.x;
      hreg[j4 * 4 + 1] = de.x * heff[j4 * 4 + 1] + dh.y;
      hreg[j4 * 4 + 2] = de.x * heff[j4 * 4 + 2] + dh.z;
      hreg[j4 * 4 + 3] = de.x * heff[j4 * 4 + 3] + dh.w;
    }
  }
}

// ============ phase C: Y = gate(Y1 + G*(C@Heff) + D*x) -> bf16 in place ====
__global__ __launch_bounds__(256) void inter_kernel(
    const u16* __restrict__ proj16,
    const u16* __restrict__ Ch16,
    const float* __restrict__ Heff,
    const float* __restrict__ Gv_g,
    const float* __restrict__ Dp,
    u16* __restrict__ Ybuf) {
  __shared__ float sC[64][132];
  __shared__ float sH[128][68];
  __shared__ float sGv[64];
  const int blk = blockIdx.x;
  const int bh = blk >> 4, ch = blk & 15;
  const int b = bh >> 5, h = bh & 31;
  const int t0 = ch * CH;
  const int tid = threadIdx.x;
  {
    const int row = tid >> 5, c4 = tid & 31;
#pragma unroll
    for (int pass = 0; pass < 8; ++pass) {
      int l = t0 + pass * 8 + row;
      ushort4 cv = *(const ushort4*)&Ch16[((size_t)bh * SEQ + l) * DSTATE + c4 * 4];
      float4 cf = {bf2f(cv.x), bf2f(cv.y), bf2f(cv.z), bf2f(cv.w)};
      *(float4*)&sC[pass * 8 + row][c4 * 4] = cf;
    }
    const int hr = tid >> 4, hc = tid & 15;
#pragma unroll
    for (int pass = 0; pass < 8; ++pass) {
      int n = pass * 16 + hr;
      float4 hv = *(const float4*)&Heff[(((size_t)bh * NCH + ch) * 128 + n) * 64 + hc * 4];
      *(float4*)&sH[n][hc * 4] = hv;
    }
    if (tid < 64) sGv[tid] = Gv_g[((size_t)bh * NCH + ch) * 64 + tid];
  }
  __syncthreads();
  const int ty = tid >> 4, tx = tid & 15;
  float acc[4][4] = {};
  for (int n = 0; n < 128; n += 4) {
    float4 cv[4], hv[4];
#pragma unroll
    for (int i = 0; i < 4; ++i) cv[i] = *(const float4*)&sC[ty * 4 + i][n];
#pragma unroll
    for (int k = 0; k < 4; ++k) hv[k] = *(const float4*)&sH[n + k][tx * 4];
#pragma unroll
    for (int k = 0; k < 4; ++k) {
      const float* hp = (const float*)&hv[k];
#pragma unroll
      for (int i = 0; i < 4; ++i) {
        float cva = ((const float*)&cv[i])[k];
#pragma unroll
        for (int j = 0; j < 4; ++j)
          acc[i][j] = fmaf(cva, hp[j], acc[i][j]);
      }
    }
  }
  const float Dv = Dp[h];
#pragma unroll
  for (int i = 0; i < 4; ++i) {
    int l = t0 + ty * 4 + i;
    float gt = sGv[ty * 4 + i];
    size_t rowp = (size_t)(b * SEQ + l) * DPROJ;
    ushort4 xv = *(const ushort4*)&proj16[rowp + OFF_X + h * 64 + tx * 4];
    ushort4 zv = *(const ushort4*)&proj16[rowp + OFF_Z + h * 64 + tx * 4];
    size_t yo = (size_t)(b * SEQ + l) * DINNER + h * 64 + tx * 4;
    ushort4 y1 = *(const ushort4*)&Ybuf[yo];
    float x[4] = {bf2f(xv.x), bf2f(xv.y), bf2f(xv.z), bf2f(xv.w)};
    float z[4] = {bf2f(zv.x), bf2f(zv.y), bf2f(zv.z), bf2f(zv.w)};
    float y[4] = {bf2f(y1.x), bf2f(y1.y), bf2f(y1.z), bf2f(y1.w)};
    ushort4 o;
    u16* op = (u16*)&o;
#pragma unroll
    for (int j = 0; j < 4; ++j) {
      float yy = y[j] + gt * acc[i][j] + Dv * x[j];
      float sg = 1.0f / (1.0f + expf(-z[j]));
      op[j] = f2bf(yy * z[j] * sg);
    }
    *(ushort4*)&Ybuf[yo] = o;
  }
}

extern "C" void kernel_launch(void* const* d_in, const int* in_sizes, int n_in,
                              void* d_out, int out_size, void* d_ws, size_t ws_size,
                              hipStream_t stream) {
  const float* u       = (const float*)d_in[0];
  const float* W_in    = (const float*)d_in[1];
  const float* W_out   = (const float*)d_in[2];
  const float* dt_bias = (const float*)d_in[3];
  const float* B_bias  = (const float*)d_in[4];
  const float* C_bias  = (const float*)d_in[5];
  const float* Bnw     = (const float*)d_in[6];
  const float* Cnw     = (const float*)d_in[7];
  const float* Dp      = (const float*)d_in[8];
  float* out = (float*)d_out;

  char* ws = (char*)d_ws;
  u16*    proj16 = (u16*)(ws);                      // 18,350,080
  float*  tailF  = (float*)(ws + 18350080);         //  1,048,576
  float4* sc4    = (float4*)(ws + 19398656);        //  1,048,576
  float*  theta  = (float*)(ws + 20447232);         //  8,388,608
  u16*    Bh16   = (u16*)(ws + 28835840);           // 16,777,216
  u16*    Ch16   = (u16*)(ws + 45613056);           // 16,777,216
  u16*    Ybuf   = (u16*)(ws + 62390272);           //  8,388,608
  float*  dHT    = (float*)(ws + 70778880);         // 33,554,432
  float*  Heff   = (float*)(ws + 104333312);        // 33,554,432
  float*  Gv     = (float*)(ws + 137887744);        //    262,144
  float2* deg    = (float2*)(ws + 138149888);       //      8,192
  u16*    ub16   = (u16*)(ws + 138158080);          //  4,194,304
  u16*    Wi16   = (u16*)(ws + 142352384);          //  9,175,040
  u16*    Wo16   = (u16*)(ws + 151527424);          //  4,194,304

  cvt_bf16<<<2048, 256, 0, stream>>>(u, ub16, 524288);
  cvt_bf16<<<4480, 256, 0, stream>>>(W_in, Wi16, 1146880);
  gemm_proj64<<<dim3(DPROJ / 64, (BATCH * SEQ) / 64), 256, 0, stream>>>(
      ub16, Wi16, proj16, tailF, BATCH * SEQ, DPROJ, DMODEL);
  theta_kernel<<<BATCH * NHEADS * 8, 1024, 0, stream>>>(tailF, dt_bias, sc4, (float4*)theta);
  rope_kernel<<<BATCH * SEQ, 1024, 0, stream>>>(proj16, theta, B_bias, C_bias, Bnw, Cnw, Bh16, Ch16);
  chunk_kernel<<<BATCH * NHEADS * NCH, 256, 0, stream>>>(
      proj16, sc4, Bh16, Ch16, Ybuf, dHT, Gv, deg);
  carry_kernel<<<BATCH * NHEADS, 512, 0, stream>>>(proj16, Bh16, dHT, deg, Heff);
  inter_kernel<<<BATCH * NHEADS * NCH, 256, 0, stream>>>(
      proj16, Ch16, Heff, Gv, Dp, Ybuf);
  cvt_bf16<<<2048, 256, 0, stream>>>(W_out, Wo16, 524288);
  gemm_out64<<<dim3(DMODEL / 64, (BATCH * SEQ) / 64), 256, 0, stream>>>(
      Ybuf, Wo16, out, BATCH * SEQ, DMODEL, DINNER);
}

// Round 9
// 230.661 us; speedup vs baseline: 10.6342x; 1.1738x over previous
//
#include <hip/hip_runtime.h>
#include <hip/hip_bf16.h>
#include <math.h>

#define BATCH 2
#define SEQ 1024
#define DMODEL 1024
#define DSTATE 128
#define HEADDIM 64
#define NHEADS 32
#define DINNER 2048
#define NUMANG 32
#define DPROJ 4480
#define CH 64
#define NCH 16
#define TAILSTART 4352
// proj row offsets (elements)
#define OFF_Z 0
#define OFF_X 2048
#define OFF_B 4096
#define OFF_C 4224
#define OFF_DT 4352
#define OFF_A 4384
#define OFF_TRAP 4416
#define OFF_ANG 4448

typedef __attribute__((ext_vector_type(8))) short bf16x8;
typedef __attribute__((ext_vector_type(4))) float f32x4;
typedef unsigned short u16;

__device__ __forceinline__ u16 f2bf(float f) {
  unsigned int u = __float_as_uint(f);
  u += 0x7FFFu + ((u >> 16) & 1u);
  return (u16)(u >> 16);
}
__device__ __forceinline__ float bf2f(u16 x) {
  return __uint_as_float(((unsigned int)x) << 16);
}

#define N4_U 524288
#define N4_WI 1146880
#define N4_WO 524288

__global__ __launch_bounds__(256) void cvt_all(const float* __restrict__ u,
                                               const float* __restrict__ Wi,
                                               const float* __restrict__ Wo,
                                               u16* __restrict__ ub16,
                                               u16* __restrict__ Wi16,
                                               u16* __restrict__ Wo16) {
  int i = blockIdx.x * 256 + threadIdx.x;
  const float4* src;
  ushort4* dst;
  int idx;
  if (i < N4_U) { src = (const float4*)u; dst = (ushort4*)ub16; idx = i; }
  else if (i < N4_U + N4_WI) { src = (const float4*)Wi; dst = (ushort4*)Wi16; idx = i - N4_U; }
  else if (i < N4_U + N4_WI + N4_WO) { src = (const float4*)Wo; dst = (ushort4*)Wo16; idx = i - N4_U - N4_WI; }
  else return;
  float4 v = src[idx];
  ushort4 o;
  o.x = f2bf(v.x); o.y = f2bf(v.y); o.z = f2bf(v.z); o.w = f2bf(v.w);
  dst[idx] = o;
}

__device__ __forceinline__ void gload_lds16(const void* g, void* l) {
  __builtin_amdgcn_global_load_lds(
      (const __attribute__((address_space(1))) unsigned int*)g,
      (__attribute__((address_space(3))) unsigned int*)l, 16, 0, 0);
}

// ============ 64x64-tile bf16 MFMA GEMM, C = A @ B^T ============
__global__ __launch_bounds__(256) void gemm_proj64(const u16* __restrict__ A,
                                                   const u16* __restrict__ B,
                                                   u16* __restrict__ Cb,
                                                   float* __restrict__ tailF,
                                                   int M, int N, int K) {
  __shared__ u16 As[64 * 64];
  __shared__ u16 Bs[64 * 64];
  const int tid = threadIdx.x;
  const int lane = tid & 63, wave = tid >> 6;
  const int bm = blockIdx.y * 64, bn = blockIdx.x * 64;
  const int wm = (wave >> 1) * 32, wn = (wave & 1) * 32;
  const int srow = wave * 8 + (lane >> 3);
  const int scol = (((lane & 7) ^ ((lane >> 3) & 7)) * 8);
  const u16* Ab = A + (size_t)(bm + srow) * K + scol;
  const u16* Bb = B + (size_t)(bn + srow) * K + scol;
  u16* Asw = As + wave * 512;
  u16* Bsw = Bs + wave * 512;
  f32x4 acc[2][2];
#pragma unroll
  for (int i = 0; i < 2; ++i)
#pragma unroll
    for (int j = 0; j < 2; ++j) acc[i][j] = (f32x4){0.f, 0.f, 0.f, 0.f};
  const int fr = lane & 15, fq = lane >> 4, sw = fr & 7;

  for (int k0 = 0; k0 < K; k0 += 64) {
    __syncthreads();
#pragma unroll
    for (int it = 0; it < 2; ++it) {
      gload_lds16(Ab + (size_t)(it * 32) * K + k0, Asw + it * 2048);
      gload_lds16(Bb + (size_t)(it * 32) * K + k0, Bsw + it * 2048);
    }
    __syncthreads();
#pragma unroll
    for (int kh = 0; kh < 2; ++kh) {
      bf16x8 af[2], bfv[2];
#pragma unroll
      for (int i = 0; i < 2; ++i)
        af[i] = *(const bf16x8*)(As + (wm + i * 16 + fr) * 64 + (((kh * 4 + fq) ^ sw) * 8));
#pragma unroll
      for (int j = 0; j < 2; ++j)
        bfv[j] = *(const bf16x8*)(Bs + (wn + j * 16 + fr) * 64 + (((kh * 4 + fq) ^ sw) * 8));
#pragma unroll
      for (int i = 0; i < 2; ++i)
#pragma unroll
        for (int j = 0; j < 2; ++j)
          acc[i][j] = __builtin_amdgcn_mfma_f32_16x16x32_bf16(af[i], bfv[j], acc[i][j], 0, 0, 0);
    }
  }
  const int orow = bm + wm + fq * 4;
  const int ocol = bn + wn + fr;
  const bool tail = (bn >= TAILSTART);
#pragma unroll
  for (int i = 0; i < 2; ++i)
#pragma unroll
    for (int j = 0; j < 2; ++j)
#pragma unroll
      for (int r = 0; r < 4; ++r) {
        float v = acc[i][j][r];
        int row = orow + i * 16 + r, col = ocol + j * 16;
        Cb[(size_t)row * N + col] = f2bf(v);
        if (tail) tailF[(size_t)row * 128 + (col - TAILSTART)] = v;
      }
}

__global__ __launch_bounds__(256) void gemm_out64(const u16* __restrict__ A,
                                                  const u16* __restrict__ B,
                                                  float* __restrict__ C,
                                                  int M, int N, int K) {
  __shared__ u16 As[64 * 64];
  __shared__ u16 Bs[64 * 64];
  const int tid = threadIdx.x;
  const int lane = tid & 63, wave = tid >> 6;
  const int bm = blockIdx.y * 64, bn = blockIdx.x * 64;
  const int wm = (wave >> 1) * 32, wn = (wave & 1) * 32;
  const int srow = wave * 8 + (lane >> 3);
  const int scol = (((lane & 7) ^ ((lane >> 3) & 7)) * 8);
  const u16* Ab = A + (size_t)(bm + srow) * K + scol;
  const u16* Bb = B + (size_t)(bn + srow) * K + scol;
  u16* Asw = As + wave * 512;
  u16* Bsw = Bs + wave * 512;
  f32x4 acc[2][2];
#pragma unroll
  for (int i = 0; i < 2; ++i)
#pragma unroll
    for (int j = 0; j < 2; ++j) acc[i][j] = (f32x4){0.f, 0.f, 0.f, 0.f};
  const int fr = lane & 15, fq = lane >> 4, sw = fr & 7;

  for (int k0 = 0; k0 < K; k0 += 64) {
    __syncthreads();
#pragma unroll
    for (int it = 0; it < 2; ++it) {
      gload_lds16(Ab + (size_t)(it * 32) * K + k0, Asw + it * 2048);
      gload_lds16(Bb + (size_t)(it * 32) * K + k0, Bsw + it * 2048);
    }
    __syncthreads();
#pragma unroll
    for (int kh = 0; kh < 2; ++kh) {
      bf16x8 af[2], bfv[2];
#pragma unroll
      for (int i = 0; i < 2; ++i)
        af[i] = *(const bf16x8*)(As + (wm + i * 16 + fr) * 64 + (((kh * 4 + fq) ^ sw) * 8));
#pragma unroll
      for (int j = 0; j < 2; ++j)
        bfv[j] = *(const bf16x8*)(Bs + (wn + j * 16 + fr) * 64 + (((kh * 4 + fq) ^ sw) * 8));
#pragma unroll
      for (int i = 0; i < 2; ++i)
#pragma unroll
        for (int j = 0; j < 2; ++j)
          acc[i][j] = __builtin_amdgcn_mfma_f32_16x16x32_bf16(af[i], bfv[j], acc[i][j], 0, 0, 0);
    }
  }
  const int orow = bm + wm + fq * 4;
  const int ocol = bn + wn + fr;
#pragma unroll
  for (int i = 0; i < 2; ++i)
#pragma unroll
    for (int j = 0; j < 2; ++j)
#pragma unroll
      for (int r = 0; r < 4; ++r)
        C[(size_t)(orow + i * 16 + r) * N + ocol + j * 16] = acc[i][j][r];
}

// ---------------- scalars + theta cumsum, per (b,h,kc): 512 blocks ---------
__device__ __forceinline__ float softplusf(float x) {
  return fmaxf(x, 0.f) + log1pf(expf(-fabsf(x)));
}

__global__ __launch_bounds__(1024) void theta_kernel(const float* __restrict__ tailF,
                                                     const float* __restrict__ dt_bias,
                                                     float4* __restrict__ sc4,
                                                     float4* __restrict__ theta4) {
  __shared__ float4 part[16];
  __shared__ float4 part2[16];
  const int blk = blockIdx.x;
  const int bh = blk >> 3, kc = blk & 7;
  const int b = bh >> 5, h = bh & 31;
  const int l = threadIdx.x;
  const int lane = l & 63, w = l >> 6;
  const float* trow = tailF + (size_t)(b * SEQ + l) * 128;
  float ddt = trow[h];
  float dt = softplusf(ddt + dt_bias[h]);
  if (kc == 0) {
    float dda = trow[32 + h];
    float trp = trow[64 + h];
    float a = fminf(-softplusf(dda), -1e-4f);
    float adt = a * dt;
    float lam = 1.0f / (1.0f + expf(-trp));
    sc4[(size_t)bh * SEQ + l] = make_float4(dt, expf(adt), lam, adt);
  }
  float4 v = *(const float4*)(trow + 96 + kc * 4);
  v.x *= dt; v.y *= dt; v.z *= dt; v.w *= dt;
#pragma unroll
  for (int off = 1; off < 64; off <<= 1) {
    float tx = __shfl_up(v.x, off, 64);
    float ty = __shfl_up(v.y, off, 64);
    float tz = __shfl_up(v.z, off, 64);
    float tw = __shfl_up(v.w, off, 64);
    if (lane >= off) { v.x += tx; v.y += ty; v.z += tz; v.w += tw; }
  }
  if (lane == 63) part[w] = v;
  __syncthreads();
  if (l < 16) {
    float4 p = part[l];
#pragma unroll
    for (int off = 1; off < 16; off <<= 1) {
      float tx = __shfl_up(p.x, off, 16);
      float ty = __shfl_up(p.y, off, 16);
      float tz = __shfl_up(p.z, off, 16);
      float tw = __shfl_up(p.w, off, 16);
      if (l >= off) { p.x += tx; p.y += ty; p.z += tz; p.w += tw; }
    }
    part2[l] = p;
  }
  __syncthreads();
  if (w > 0) {
    float4 o = part2[w - 1];
    v.x += o.x; v.y += o.y; v.z += o.z; v.w += o.w;
  }
  theta4[((size_t)(b * SEQ + l) * NHEADS + h) * 8 + kc] = v;
}

// ------- RMSNorm + bias + RoPE, fully parallel over (h,n): 1024 thr -------
__global__ __launch_bounds__(1024) void rope_kernel(const u16* __restrict__ proj16,
                                                    const float* __restrict__ theta,
                                                    const float* __restrict__ B_bias,
                                                    const float* __restrict__ C_bias,
                                                    const float* __restrict__ Bnw,
                                                    const float* __restrict__ Cnw,
                                                    u16* __restrict__ Bh,
                                                    u16* __restrict__ Ch) {
  const int bl = blockIdx.x;
  const int b = bl >> 10, l = bl & 1023;
  const int tid = threadIdx.x;
  __shared__ float sB[128], sC[128], red[4];
  __shared__ float cth[1024], sth[1024];
  float bv = 0.f, cv = 0.f;
  const size_t row = (size_t)bl * DPROJ;
  if (tid < 128) {
    bv = bf2f(proj16[row + OFF_B + tid]);
    cv = bf2f(proj16[row + OFF_C + tid]);
    float sb = bv * bv, sc = cv * cv;
    for (int m = 32; m; m >>= 1) { sb += __shfl_xor(sb, m); sc += __shfl_xor(sc, m); }
    const int wave = tid >> 6;
    if ((tid & 63) == 0) { red[wave * 2] = sb; red[wave * 2 + 1] = sc; }
  }
  {
    float th = theta[(size_t)bl * 1024 + tid];
    cth[tid] = cosf(th);
    sth[tid] = sinf(th);
  }
  __syncthreads();
  if (tid < 128) {
    float rb = rsqrtf((red[0] + red[2]) / 128.0f + 1e-5f);
    float rc = rsqrtf((red[1] + red[3]) / 128.0f + 1e-5f);
    sB[tid] = bv * rb * Bnw[tid];
    sC[tid] = cv * rc * Cnw[tid];
  }
  __syncthreads();
  const int h = tid >> 5;
  const int n0 = (tid & 31) * 4;
  float ob[4], oc[4];
  if (n0 < 32) {
#pragma unroll
    for (int j = 0; j < 4; ++j) {
      int n = n0 + j;
      float c = cth[h * 32 + n], s = sth[h * 32 + n];
      float b1 = sB[n] + B_bias[h * 128 + n];
      float b2 = sB[n + 32] + B_bias[h * 128 + n + 32];
      float c1 = sC[n] + C_bias[h * 128 + n];
      float c2 = sC[n + 32] + C_bias[h * 128 + n + 32];
      ob[j] = b1 * c - b2 * s;
      oc[j] = c1 * c - c2 * s;
    }
  } else if (n0 < 64) {
#pragma unroll
    for (int j = 0; j < 4; ++j) {
      int n = n0 + j, k = n - 32;
      float c = cth[h * 32 + k], s = sth[h * 32 + k];
      float b1 = sB[k] + B_bias[h * 128 + k];
      float b2 = sB[k + 32] + B_bias[h * 128 + k + 32];
      float c1 = sC[k] + C_bias[h * 128 + k];
      float c2 = sC[k + 32] + C_bias[h * 128 + k + 32];
      ob[j] = b1 * s + b2 * c;
      oc[j] = c1 * s + c2 * c;
    }
  } else {
#pragma unroll
    for (int j = 0; j < 4; ++j) {
      int n = n0 + j;
      ob[j] = sB[n] + B_bias[h * 128 + n];
      oc[j] = sC[n] + C_bias[h * 128 + n];
    }
  }
  size_t o = (((size_t)(b * NHEADS + h)) * SEQ + l) * DSTATE + n0;
  ushort4 vb = {f2bf(ob[0]), f2bf(ob[1]), f2bf(ob[2]), f2bf(ob[3])};
  ushort4 vc = {f2bf(oc[0]), f2bf(oc[1]), f2bf(oc[2]), f2bf(oc[3])};
  *(ushort4*)&Bh[o] = vb;
  *(ushort4*)&Ch[o] = vc;
}

// ============ chunked scan, phase A: MFMA per-chunk GEMMs ==============
#define SWB 136
#define SWS 72

__global__ __launch_bounds__(256) void chunk_kernel(
    const u16* __restrict__ proj16,
    const float4* __restrict__ sc4,
    const u16* __restrict__ Bh16,
    const u16* __restrict__ Ch16,
    u16* __restrict__ Ybuf,
    u16* __restrict__ dHT16,      // [bh][ch][64 p][128 n] bf16
    float* __restrict__ Gv_g,
    float2* __restrict__ de_g) {
  __shared__ u16 sCb[64 * SWB];
  __shared__ u16 sBb[64 * SWB];
  __shared__ u16 sBt[128 * SWS];
  __shared__ u16 sXt[64 * SWS];
  __shared__ u16 sSw[64 * SWS];
  __shared__ float sA[64], sW[64], sDL[64], sCV[64];

  const int blk = blockIdx.x;
  const int bh = blk >> 4, ch = blk & 15;
  const int b = bh >> 5, h = bh & 31;
  const int t0 = ch * CH;
  const int tid = threadIdx.x;
  const int lane = tid & 63, wave = tid >> 6;

  {
    const int row = tid >> 5;
    const int c4 = tid & 31;
#pragma unroll
    for (int pass = 0; pass < 8; ++pass) {
      int ll = pass * 8 + row;
      int l = t0 + ll;
      ushort4 cv = *(const ushort4*)&Ch16[((size_t)bh * SEQ + l) * DSTATE + c4 * 4];
      ushort4 bv = *(const ushort4*)&Bh16[((size_t)bh * SEQ + l) * DSTATE + c4 * 4];
      *(ushort4*)&sCb[ll * SWB + c4 * 4] = cv;
      *(ushort4*)&sBb[ll * SWB + c4 * 4] = bv;
      sBt[(c4 * 4 + 0) * SWS + ll] = bv.x;
      sBt[(c4 * 4 + 1) * SWS + ll] = bv.y;
      sBt[(c4 * 4 + 2) * SWS + ll] = bv.z;
      sBt[(c4 * 4 + 3) * SWS + ll] = bv.w;
    }
    const int xr = tid >> 2, xc = tid & 3;
    const u16* xrow = &proj16[(size_t)(b * SEQ + t0 + xr) * DPROJ + OFF_X + h * 64];
#pragma unroll
    for (int j = 0; j < 4; ++j) {
      ushort4 xv = *(const ushort4*)(xrow + xc * 16 + j * 4);
      int p = xc * 16 + j * 4;
      sXt[(p + 0) * SWS + xr] = xv.x;
      sXt[(p + 1) * SWS + xr] = xv.y;
      sXt[(p + 2) * SWS + xr] = xv.z;
      sXt[(p + 3) * SWS + xr] = xv.w;
    }
  }
  if (tid < 64) {
    float4 s = sc4[(size_t)bh * SEQ + t0 + tid];
    float dt = s.x, lam = s.z, adt = s.w;
    float A = adt;
#pragma unroll
    for (int off = 1; off < 64; off <<= 1) {
      float t = __shfl_up(A, off, 64);
      if (tid >= off) A += t;
    }
    float dtn = __shfl_down(dt, 1, 64);
    float lamn = __shfl_down(lam, 1, 64);
    float dl = dt * lam;
    float w = dl + dtn * (1.0f - lamn);
    if (tid == 63) w = 0.0f;
    float A63 = __shfl(A, 63, 64);
    float cv = (tid < 63) ? expf(A63 - A) * w : dl;
    sA[tid] = A; sW[tid] = w; sCV[tid] = cv; sDL[tid] = dl;
    Gv_g[((size_t)bh * NCH + ch) * 64 + tid] = expf(A);
    if (tid == 0) de_g[(size_t)bh * NCH + ch] = make_float2(expf(A63), dt * (1.0f - lam));
  }
  __syncthreads();

  const int fr = lane & 15, fq = lane >> 4;

  // S^T masked -> sSw[t][s] bf16
  {
    f32x4 acc[4];
#pragma unroll
    for (int j = 0; j < 4; ++j) acc[j] = (f32x4){0.f, 0.f, 0.f, 0.f};
#pragma unroll
    for (int kc = 0; kc < 4; ++kc) {
      bf16x8 af = *(const bf16x8*)&sBb[(wave * 16 + fr) * SWB + kc * 32 + fq * 8];
#pragma unroll
      for (int j = 0; j < 4; ++j) {
        bf16x8 bf = *(const bf16x8*)&sCb[(j * 16 + fr) * SWB + kc * 32 + fq * 8];
        acc[j] = __builtin_amdgcn_mfma_f32_16x16x32_bf16(af, bf, acc[j], 0, 0, 0);
      }
    }
    const int sbase = wave * 16 + fq * 4;
#pragma unroll
    for (int j = 0; j < 4; ++j) {
      int t = j * 16 + fr;
      float At = sA[t], dlt = sDL[t];
#pragma unroll
      for (int r = 0; r < 4; ++r) {
        int ss = sbase + r;
        float f = (ss < t) ? expf(At - sA[ss]) * sW[ss] : ((ss == t) ? dlt : 0.0f);
        sSw[t * SWS + ss] = f2bf(acc[j][r] * f);
      }
    }
  }
  __syncthreads();

  // Y1 = Sw @ X -> Ybuf (bf16)
  {
    f32x4 acc[4];
#pragma unroll
    for (int j = 0; j < 4; ++j) acc[j] = (f32x4){0.f, 0.f, 0.f, 0.f};
#pragma unroll
    for (int kc = 0; kc < 2; ++kc) {
      bf16x8 af = *(const bf16x8*)&sSw[(wave * 16 + fr) * SWS + kc * 32 + fq * 8];
#pragma unroll
      for (int j = 0; j < 4; ++j) {
        bf16x8 bf = *(const bf16x8*)&sXt[(j * 16 + fr) * SWS + kc * 32 + fq * 8];
        acc[j] = __builtin_amdgcn_mfma_f32_16x16x32_bf16(af, bf, acc[j], 0, 0, 0);
      }
    }
    const int tr = t0 + wave * 16 + fq * 4;
#pragma unroll
    for (int j = 0; j < 4; ++j) {
      int p = j * 16 + fr;
#pragma unroll
      for (int r = 0; r < 4; ++r)
        Ybuf[(size_t)(b * SEQ + tr + r) * DINNER + h * 64 + p] = f2bf(acc[j][r]);
    }
  }
  __syncthreads();

  // scale Xt columns by cv[s]
  {
    const int p = tid >> 2;
    const int s0 = (tid & 3) * 16;
#pragma unroll
    for (int k = 0; k < 16; ++k) {
      int s = s0 + k;
      sXt[p * SWS + s] = f2bf(bf2f(sXt[p * SWS + s]) * sCV[s]);
    }
  }
  __syncthreads();

  // dHT[p][n] = sum_s Xt[p][s] * Bt[n][s]  (A = Xt rows p, B = Bt rows n)
  {
    f32x4 acc[8];
#pragma unroll
    for (int j = 0; j < 8; ++j) acc[j] = (f32x4){0.f, 0.f, 0.f, 0.f};
#pragma unroll
    for (int kc = 0; kc < 2; ++kc) {
      bf16x8 af = *(const bf16x8*)&sXt[(wave * 16 + fr) * SWS + kc * 32 + fq * 8];
#pragma unroll
      for (int j = 0; j < 8; ++j) {
        bf16x8 bf = *(const bf16x8*)&sBt[(j * 16 + fr) * SWS + kc * 32 + fq * 8];
        acc[j] = __builtin_amdgcn_mfma_f32_16x16x32_bf16(af, bf, acc[j], 0, 0, 0);
      }
    }
    const int pr = wave * 16 + fq * 4;
#pragma unroll
    for (int j = 0; j < 8; ++j) {
      int n = j * 16 + fr;
#pragma unroll
      for (int r = 0; r < 4; ++r)
        dHT16[(((size_t)bh * NCH + ch) * 64 + pr + r) * 128 + n] = f2bf(acc[j][r]);
    }
  }
}

// ============ phase B: carry, 256 blocks (bh x 4 p-groups) ==========
__global__ __launch_bounds__(128) void carry_kernel(
    const u16* __restrict__ proj16,
    const u16* __restrict__ Bh16,
    const u16* __restrict__ dHT16,
    const float2* __restrict__ de_g,
    u16* __restrict__ Heff16) {   // [bh][ch][64 p][128 n] bf16
  const int blk = blockIdx.x;
  const int bh = blk >> 2, pg = blk & 3;
  const int b = bh >> 5, h = bh & 31;
  const int tid = threadIdx.x;
  const int p = pg * 16 + (tid >> 3);
  const int n0 = (tid & 7) * 16;
  float hreg[16] = {};
  for (int c = 0; c < NCH; ++c) {
    float2 de = de_g[bh * NCH + c];
    float heff[16];
    if (c == 0) {
#pragma unroll
      for (int j = 0; j < 16; ++j) heff[j] = 0.0f;
    } else {
      int lprev = c * CH - 1;
      float xp = bf2f(proj16[(size_t)(b * SEQ + lprev) * DPROJ + OFF_X + h * 64 + p]);
      float eBx = de.y * xp;
      const u16* Bp = &Bh16[((size_t)bh * SEQ + lprev) * DSTATE + n0];
#pragma unroll
      for (int j4 = 0; j4 < 4; ++j4) {
        ushort4 bv = *(const ushort4*)(Bp + j4 * 4);
        heff[j4 * 4 + 0] = hreg[j4 * 4 + 0] + eBx * bf2f(bv.x);
        heff[j4 * 4 + 1] = hreg[j4 * 4 + 1] + eBx * bf2f(bv.y);
        heff[j4 * 4 + 2] = hreg[j4 * 4 + 2] + eBx * bf2f(bv.z);
        heff[j4 * 4 + 3] = hreg[j4 * 4 + 3] + eBx * bf2f(bv.w);
      }
    }
    size_t base = (((size_t)bh * NCH + c) * 64 + p) * 128 + n0;
#pragma unroll
    for (int j4 = 0; j4 < 4; ++j4) {
      ushort4 o = {f2bf(heff[j4 * 4 + 0]), f2bf(heff[j4 * 4 + 1]),
                   f2bf(heff[j4 * 4 + 2]), f2bf(heff[j4 * 4 + 3])};
      *(ushort4*)&Heff16[base + j4 * 4] = o;
    }
#pragma unroll
    for (int j4 = 0; j4 < 4; ++j4) {
      ushort4 dh = *(const ushort4*)&dHT16[base + j4 * 4];
      hreg[j4 * 4 + 0] = de.x * heff[j4 * 4 + 0] + bf2f(dh.x);
      hreg[j4 * 4 + 1] = de.x * heff[j4 * 4 + 1] + bf2f(dh.y);
      hreg[j4 * 4 + 2] = de.x * heff[j4 * 4 + 2] + bf2f(dh.z);
      hreg[j4 * 4 + 3] = de.x * heff[j4 * 4 + 3] + bf2f(dh.w);
    }
  }
}

// ============ phase C: MFMA  Y = gate(Y1 + G*(Ch@Heff^T) + D*x) ============
__global__ __launch_bounds__(256) void inter_kernel(
    const u16* __restrict__ proj16,
    const u16* __restrict__ Ch16,
    const u16* __restrict__ Heff16,
    const float* __restrict__ Gv_g,
    const float* __restrict__ Dp,
    u16* __restrict__ Ybuf) {
  __shared__ u16 sCt[64 * SWB];
  __shared__ u16 sHe[64 * SWB];
  __shared__ float sGv[64];
  const int blk = blockIdx.x;
  const int bh = blk >> 4, ch = blk & 15;
  const int b = bh >> 5, h = bh & 31;
  const int t0 = ch * CH;
  const int tid = threadIdx.x;
  const int lane = tid & 63, wave = tid >> 6;
  {
    const int row = tid >> 2, seg = tid & 3;  // 64 rows, 4 segs of 32 elems
    const u16* csrc = &Ch16[((size_t)bh * SEQ + t0 + row) * DSTATE + seg * 32];
    const u16* hsrc = &Heff16[(((size_t)bh * NCH + ch) * 64 + row) * 128 + seg * 32];
#pragma unroll
    for (int q = 0; q < 4; ++q) {
      *(ushort4*)&sCt[row * SWB + seg * 32 + q * 8]     = *(const ushort4*)(csrc + q * 8);
      *(ushort4*)&sCt[row * SWB + seg * 32 + q * 8 + 4] = *(const ushort4*)(csrc + q * 8 + 4);
      *(ushort4*)&sHe[row * SWB + seg * 32 + q * 8]     = *(const ushort4*)(hsrc + q * 8);
      *(ushort4*)&sHe[row * SWB + seg * 32 + q * 8 + 4] = *(const ushort4*)(hsrc + q * 8 + 4);
    }
    if (tid < 64) sGv[tid] = Gv_g[((size_t)bh * NCH + ch) * 64 + tid];
  }
  __syncthreads();
  const int fr = lane & 15, fq = lane >> 4;
  f32x4 acc[4];
#pragma unroll
  for (int j = 0; j < 4; ++j) acc[j] = (f32x4){0.f, 0.f, 0.f, 0.f};
#pragma unroll
  for (int kc = 0; kc < 4; ++kc) {
    bf16x8 af = *(const bf16x8*)&sCt[(wave * 16 + fr) * SWB + kc * 32 + fq * 8];
#pragma unroll
    for (int j = 0; j < 4; ++j) {
      bf16x8 bf = *(const bf16x8*)&sHe[(j * 16 + fr) * SWB + kc * 32 + fq * 8];
      acc[j] = __builtin_amdgcn_mfma_f32_16x16x32_bf16(af, bf, acc[j], 0, 0, 0);
    }
  }
  const float Dv = Dp[h];
#pragma unroll
  for (int r = 0; r < 4; ++r) {
    int tl = wave * 16 + fq * 4 + r;
    int l = t0 + tl;
    float gt = sGv[tl];
    size_t rowp = (size_t)(b * SEQ + l) * DPROJ;
    size_t yrow = (size_t)(b * SEQ + l) * DINNER + h * 64;
#pragma unroll
    for (int j = 0; j < 4; ++j) {
      int p = j * 16 + fr;
      float x = bf2f(proj16[rowp + OFF_X + h * 64 + p]);
      float z = bf2f(proj16[rowp + OFF_Z + h * 64 + p]);
      float y1 = bf2f(Ybuf[yrow + p]);
      float yy = y1 + gt * acc[j][r] + Dv * x;
      float sg = 1.0f / (1.0f + expf(-z));
      Ybuf[yrow + p] = f2bf(yy * z * sg);
    }
  }
}

extern "C" void kernel_launch(void* const* d_in, const int* in_sizes, int n_in,
                              void* d_out, int out_size, void* d_ws, size_t ws_size,
                              hipStream_t stream) {
  const float* u       = (const float*)d_in[0];
  const float* W_in    = (const float*)d_in[1];
  const float* W_out   = (const float*)d_in[2];
  const float* dt_bias = (const float*)d_in[3];
  const float* B_bias  = (const float*)d_in[4];
  const float* C_bias  = (const float*)d_in[5];
  const float* Bnw     = (const float*)d_in[6];
  const float* Cnw     = (const float*)d_in[7];
  const float* Dp      = (const float*)d_in[8];
  float* out = (float*)d_out;

  char* ws = (char*)d_ws;
  u16*    proj16 = (u16*)(ws);                      // 18,350,080
  float*  tailF  = (float*)(ws + 18350080);         //  1,048,576
  float4* sc4    = (float4*)(ws + 19398656);        //  1,048,576
  float*  theta  = (float*)(ws + 20447232);         //  8,388,608
  u16*    Bh16   = (u16*)(ws + 28835840);           // 16,777,216
  u16*    Ch16   = (u16*)(ws + 45613056);           // 16,777,216
  u16*    Ybuf   = (u16*)(ws + 62390272);           //  8,388,608
  u16*    dHT16  = (u16*)(ws + 70778880);           // 16,777,216
  u16*    Heff16 = (u16*)(ws + 87556096);           // 16,777,216
  float*  Gv     = (float*)(ws + 104333312);        //    262,144
  float2* deg    = (float2*)(ws + 104595456);       //      8,192
  u16*    ub16   = (u16*)(ws + 104603648);          //  4,194,304
  u16*    Wi16   = (u16*)(ws + 108797952);          //  9,175,040
  u16*    Wo16   = (u16*)(ws + 117972992);          //  4,194,304

  cvt_all<<<(N4_U + N4_WI + N4_WO + 255) / 256, 256, 0, stream>>>(
      u, W_in, W_out, ub16, Wi16, Wo16);
  gemm_proj64<<<dim3(DPROJ / 64, (BATCH * SEQ) / 64), 256, 0, stream>>>(
      ub16, Wi16, proj16, tailF, BATCH * SEQ, DPROJ, DMODEL);
  theta_kernel<<<BATCH * NHEADS * 8, 1024, 0, stream>>>(tailF, dt_bias, sc4, (float4*)theta);
  rope_kernel<<<BATCH * SEQ, 1024, 0, stream>>>(proj16, theta, B_bias, C_bias, Bnw, Cnw, Bh16, Ch16);
  chunk_kernel<<<BATCH * NHEADS * NCH, 256, 0, stream>>>(
      proj16, sc4, Bh16, Ch16, Ybuf, dHT16, Gv, deg);
  carry_kernel<<<BATCH * NHEADS * 4, 128, 0, stream>>>(proj16, Bh16, dHT16, deg, Heff16);
  inter_kernel<<<BATCH * NHEADS * NCH, 256, 0, stream>>>(
      proj16, Ch16, Heff16, Gv, Dp, Ybuf);
  gemm_out64<<<dim3(DMODEL / 64, (BATCH * SEQ) / 64), 256, 0, stream>>>(
      Ybuf, Wo16, out, BATCH * SEQ, DMODEL, DINNER);
}